// Round 1
// baseline (2071.483 us; speedup 1.0000x reference)
//
#include <hip/hip_runtime.h>
#include <math.h>

// Problem constants
#define BN     16384
#define INC    128
#define CH     512
#define ED     6240
#define KN     512      // NUM_EMB
#define DIN    64
#define DH     64
#define DY     32

// d_out layout (float32): dec[16384*32] | diff[1] | embed_ind[16384] | perplexity[1]
#define OUT_DEC   0
#define OUT_DIFF  (BN*DY)            // 524288
#define OUT_IND   (BN*DY + 1)        // 524289
#define OUT_PERP  (BN*DY + 1 + BN)   // 540673

// ---------------------------------------------------------------------------
// Transpose Wf2 [512][6240] -> Wf2T [6240][512]
// ---------------------------------------------------------------------------
__global__ __launch_bounds__(256) void transpose_kernel(const float* __restrict__ A,
                                                        float* __restrict__ At) {
    __shared__ float tile[32][33];
    int db = blockIdx.x * 32;           // d base (0..6239)
    int jb = blockIdx.y * 32;           // j base (0..511)
    int tx = threadIdx.x & 31, ty = threadIdx.x >> 5;   // ty 0..7
    #pragma unroll
    for (int r = ty; r < 32; r += 8)
        tile[r][tx] = A[(size_t)(jb + r) * ED + db + tx];
    __syncthreads();
    #pragma unroll
    for (int r = ty; r < 32; r += 8)
        At[(size_t)(db + r) * CH + jb + tx] = tile[tx][r];
}

// ---------------------------------------------------------------------------
// Small precomputes: s2[k]=||e_k||^2, be[k]=bf2.e_k, w0[j]=Wf2[j,:].bf2, bb=||bf2||^2
// s2/be/w0 accumulated with atomics into zeroed buffers (d-split for parallelism).
// ---------------------------------------------------------------------------
__global__ __launch_bounds__(256) void psmall_kernel(const float* __restrict__ embed,
                                                     const float* __restrict__ bf2,
                                                     const float* __restrict__ Wf2T,
                                                     float* __restrict__ s2,
                                                     float* __restrict__ be,
                                                     float* __restrict__ w0,
                                                     float* __restrict__ bbuf) {
    __shared__ float sf[256];
    int task = blockIdx.y;
    int t = threadIdx.x;
    if (task == 0) {
        int khalf = blockIdx.x & 1, chunk = blockIdx.x >> 1;   // 16 chunks of 390
        int k = khalf * 256 + t;
        float s = 0.f, b = 0.f;
        int d0 = chunk * 390, d1 = d0 + 390;
        for (int d = d0; d < d1; ++d) {
            float e = embed[(size_t)d * KN + k];
            s = fmaf(e, e, s);
            b = fmaf(bf2[d], e, b);
        }
        atomicAdd(&s2[k], s);
        atomicAdd(&be[k], b);
    } else if (task == 1) {
        int jhalf = blockIdx.x & 1, chunk = blockIdx.x >> 1;
        int j = jhalf * 256 + t;
        float w = 0.f;
        int d0 = chunk * 390, d1 = d0 + 390;
        for (int d = d0; d < d1; ++d)
            w = fmaf(bf2[d], Wf2T[(size_t)d * CH + j], w);
        atomicAdd(&w0[j], w);
    } else {
        if (blockIdx.x > 0) return;
        float s = 0.f;
        for (int d = t; d < ED; d += 256) { float v = bf2[d]; s = fmaf(v, v, s); }
        sf[t] = s; __syncthreads();
        for (int r = 128; r > 0; r >>= 1) { if (t < r) sf[t] += sf[t + r]; __syncthreads(); }
        if (t == 0) bbuf[0] = sf[0];
    }
}

// ---------------------------------------------------------------------------
// Tiled fp32 GEMM with K-split atomics: C[512x512] += A[512xK] @ Bm[Kx512]
// Used for We = Wf2 @ embed and G = Wf2 @ Wf2T. C must be pre-zeroed.
// block 256, tile M=32 N=128 Kc=32, grid (4, 16, KSPLIT)
// ---------------------------------------------------------------------------
__global__ __launch_bounds__(256) void pgemm_kernel(const float* __restrict__ A,
                                                    const float* __restrict__ Bm,
                                                    float* __restrict__ C,
                                                    int ksteps_per, int Ktot) {
    __shared__ float As[32][36];
    __shared__ float Bs[32][132];
    int n0 = blockIdx.x * 128;
    int m0 = blockIdx.y * 32;
    int t = threadIdx.x;
    int mt = (t >> 5) << 2;      // 0..28
    int nt = (t & 31) << 2;      // 0..124
    float acc[4][4] = {};
    int nk = Ktot / 32;          // 195
    int kbegin = blockIdx.z * ksteps_per;
    int kend = kbegin + ksteps_per; if (kend > nk) kend = nk;
    for (int ks = kbegin; ks < kend; ++ks) {
        int kk = ks * 32;
        {   // A tile -> As[kc][m] (transposed in LDS)
            int row = t >> 3;            // 0..31
            int c4  = (t & 7) << 2;      // 0..28
            float4 av = *(const float4*)&A[(size_t)(m0 + row) * Ktot + kk + c4];
            As[c4 + 0][row] = av.x; As[c4 + 1][row] = av.y;
            As[c4 + 2][row] = av.z; As[c4 + 3][row] = av.w;
        }
        {   // B tile -> Bs[kc][n]
            int rr = t >> 5;             // 0..7
            int c4 = (t & 31) << 2;      // 0..124
            #pragma unroll
            for (int p = 0; p < 4; ++p) {
                int r = rr + p * 8;
                *(float4*)&Bs[r][c4] = *(const float4*)&Bm[(size_t)(kk + r) * KN + n0 + c4];
            }
        }
        __syncthreads();
        #pragma unroll
        for (int kc = 0; kc < 32; ++kc) {
            float4 a = *(const float4*)&As[kc][mt];
            float4 b = *(const float4*)&Bs[kc][nt];
            acc[0][0] = fmaf(a.x, b.x, acc[0][0]); acc[0][1] = fmaf(a.x, b.y, acc[0][1]);
            acc[0][2] = fmaf(a.x, b.z, acc[0][2]); acc[0][3] = fmaf(a.x, b.w, acc[0][3]);
            acc[1][0] = fmaf(a.y, b.x, acc[1][0]); acc[1][1] = fmaf(a.y, b.y, acc[1][1]);
            acc[1][2] = fmaf(a.y, b.z, acc[1][2]); acc[1][3] = fmaf(a.y, b.w, acc[1][3]);
            acc[2][0] = fmaf(a.z, b.x, acc[2][0]); acc[2][1] = fmaf(a.z, b.y, acc[2][1]);
            acc[2][2] = fmaf(a.z, b.z, acc[2][2]); acc[2][3] = fmaf(a.z, b.w, acc[2][3]);
            acc[3][0] = fmaf(a.w, b.x, acc[3][0]); acc[3][1] = fmaf(a.w, b.y, acc[3][1]);
            acc[3][2] = fmaf(a.w, b.z, acc[3][2]); acc[3][3] = fmaf(a.w, b.w, acc[3][3]);
        }
        __syncthreads();
    }
    #pragma unroll
    for (int i = 0; i < 4; ++i)
        #pragma unroll
        for (int j = 0; j < 4; ++j)
            atomicAdd(&C[(size_t)(m0 + mt + i) * KN + n0 + nt + j], acc[i][j]);
}

// ---------------------------------------------------------------------------
// Layer-1 for both encoders: H = relu(x@Wf1+bf1), Hx = relu(x@Wx1+bx1)
// Also accumulates colsum[c] = sum_b H[b][c] (for diff's 2*h.w0 term).
// block 256, 16 samples/block; thread t owns cols {t,t+256} of each W.
// ---------------------------------------------------------------------------
__global__ __launch_bounds__(256) void enc1_kernel(const float* __restrict__ x,
                                                   const float* __restrict__ Wf1,
                                                   const float* __restrict__ bf1,
                                                   const float* __restrict__ Wx1,
                                                   const float* __restrict__ bx1,
                                                   float* __restrict__ H,
                                                   float* __restrict__ Hx,
                                                   float* __restrict__ colsum) {
    __shared__ float xs[16][INC];     // 8 KB
    int bbase = blockIdx.x * 16;
    int t = threadIdx.x;
    for (int i = t; i < 16 * (INC / 4); i += 256) {
        int m = i >> 5, c4 = i & 31;
        ((float4*)xs[m])[c4] = ((const float4*)(x + (size_t)(bbase + m) * INC))[c4];
    }
    __syncthreads();
    float acc[16][4] = {};
    for (int j = 0; j < INC; j += 4) {
        float w[4][4];
        #pragma unroll
        for (int dj = 0; dj < 4; ++dj) {
            w[dj][0] = Wf1[(size_t)(j + dj) * CH + t];
            w[dj][1] = Wf1[(size_t)(j + dj) * CH + t + 256];
            w[dj][2] = Wx1[(size_t)(j + dj) * CH + t];
            w[dj][3] = Wx1[(size_t)(j + dj) * CH + t + 256];
        }
        #pragma unroll
        for (int m = 0; m < 16; ++m) {
            float4 hv = *(const float4*)&xs[m][j];
            float xv;
            xv = hv.x;
            acc[m][0] = fmaf(xv, w[0][0], acc[m][0]); acc[m][1] = fmaf(xv, w[0][1], acc[m][1]);
            acc[m][2] = fmaf(xv, w[0][2], acc[m][2]); acc[m][3] = fmaf(xv, w[0][3], acc[m][3]);
            xv = hv.y;
            acc[m][0] = fmaf(xv, w[1][0], acc[m][0]); acc[m][1] = fmaf(xv, w[1][1], acc[m][1]);
            acc[m][2] = fmaf(xv, w[1][2], acc[m][2]); acc[m][3] = fmaf(xv, w[1][3], acc[m][3]);
            xv = hv.z;
            acc[m][0] = fmaf(xv, w[2][0], acc[m][0]); acc[m][1] = fmaf(xv, w[2][1], acc[m][1]);
            acc[m][2] = fmaf(xv, w[2][2], acc[m][2]); acc[m][3] = fmaf(xv, w[2][3], acc[m][3]);
            xv = hv.w;
            acc[m][0] = fmaf(xv, w[3][0], acc[m][0]); acc[m][1] = fmaf(xv, w[3][1], acc[m][1]);
            acc[m][2] = fmaf(xv, w[3][2], acc[m][2]); acc[m][3] = fmaf(xv, w[3][3], acc[m][3]);
        }
    }
    float bf0 = bf1[t], bf1v = bf1[t + 256], bx0 = bx1[t], bx1v = bx1[t + 256];
    float cs0 = 0.f, cs1 = 0.f;
    #pragma unroll
    for (int m = 0; m < 16; ++m) {
        float v0 = fmaxf(acc[m][0] + bf0, 0.f);
        float v1 = fmaxf(acc[m][1] + bf1v, 0.f);
        float v2 = fmaxf(acc[m][2] + bx0, 0.f);
        float v3 = fmaxf(acc[m][3] + bx1v, 0.f);
        size_t row = (size_t)(bbase + m) * CH;
        H[row + t] = v0; H[row + t + 256] = v1;
        Hx[row + t] = v2; Hx[row + t + 256] = v3;
        cs0 += v0; cs1 += v1;
    }
    atomicAdd(&colsum[t], cs0);
    atomicAdd(&colsum[t + 256], cs1);
}

// ---------------------------------------------------------------------------
// Scoring kernel (the hot one): per sample b,
//   g_k = 0.5*s2[k] - be[k] - h_b.We[:,k]   (argmin_k g_k == argmin_k dist)
//   hGh = sum_k (h_b.G[:,k]) * h_b[k]
// Emits ind[b], float(ind) to d_out, counts histogram, and
// diffsum += sum_b (2*g_min + hGh).
// block 256, 16 samples/block; thread t owns cols {t, t+256} of We and of G.
// ---------------------------------------------------------------------------
__global__ __launch_bounds__(256) void score_kernel(const float* __restrict__ H,
                                                    const float* __restrict__ We,
                                                    const float* __restrict__ G,
                                                    const float* __restrict__ s2,
                                                    const float* __restrict__ be,
                                                    int* __restrict__ ind,
                                                    int* __restrict__ counts,
                                                    float* __restrict__ diffsum,
                                                    float* __restrict__ out_ind) {
    __shared__ float hs[16][CH];      // 32 KB
    __shared__ float redv[256];
    __shared__ int   redi[256];
    __shared__ float redg[256];
    int bbase = blockIdx.x * 16;
    int t = threadIdx.x;
    for (int i = t; i < 16 * (CH / 4); i += 256) {
        int m = i >> 7, c4 = i & 127;
        ((float4*)hs[m])[c4] = ((const float4*)(H + (size_t)(bbase + m) * CH))[c4];
    }
    __syncthreads();
    const int kA = t, kB = t + 256;
    float sA[16] = {}, sB[16] = {}, gA[16] = {}, gB[16] = {};
    for (int j = 0; j < CH; j += 4) {
        float wA[4], wB[4], qA[4], qB[4];
        #pragma unroll
        for (int dj = 0; dj < 4; ++dj) {
            size_t ro = (size_t)(j + dj) * KN;
            wA[dj] = We[ro + kA]; wB[dj] = We[ro + kB];
            qA[dj] = G[ro + kA];  qB[dj] = G[ro + kB];
        }
        #pragma unroll
        for (int m = 0; m < 16; ++m) {
            float4 hv = *(const float4*)&hs[m][j];
            sA[m] = fmaf(hv.x, wA[0], sA[m]); sA[m] = fmaf(hv.y, wA[1], sA[m]);
            sA[m] = fmaf(hv.z, wA[2], sA[m]); sA[m] = fmaf(hv.w, wA[3], sA[m]);
            sB[m] = fmaf(hv.x, wB[0], sB[m]); sB[m] = fmaf(hv.y, wB[1], sB[m]);
            sB[m] = fmaf(hv.z, wB[2], sB[m]); sB[m] = fmaf(hv.w, wB[3], sB[m]);
            gA[m] = fmaf(hv.x, qA[0], gA[m]); gA[m] = fmaf(hv.y, qA[1], gA[m]);
            gA[m] = fmaf(hv.z, qA[2], gA[m]); gA[m] = fmaf(hv.w, qA[3], gA[m]);
            gB[m] = fmaf(hv.x, qB[0], gB[m]); gB[m] = fmaf(hv.y, qB[1], gB[m]);
            gB[m] = fmaf(hv.z, qB[2], gB[m]); gB[m] = fmaf(hv.w, qB[3], gB[m]);
        }
    }
    float ckA = 0.5f * s2[kA] - be[kA];
    float ckB = 0.5f * s2[kB] - be[kB];
    float blockdiff = 0.f;   // thread 0 only
    for (int m = 0; m < 16; ++m) {
        float vA = ckA - sA[m];
        float vB = ckB - sB[m];
        float mv; int mi;
        if (vB < vA) { mv = vB; mi = kB; } else { mv = vA; mi = kA; }
        float gc = gA[m] * hs[m][kA] + gB[m] * hs[m][kB];
        redv[t] = mv; redi[t] = mi; redg[t] = gc;
        __syncthreads();
        for (int s = 128; s > 0; s >>= 1) {
            if (t < s) {
                float ov = redv[t + s]; int oi = redi[t + s];
                if (ov < redv[t] || (ov == redv[t] && oi < redi[t])) {
                    redv[t] = ov; redi[t] = oi;
                }
                redg[t] += redg[t + s];
            }
            __syncthreads();
        }
        if (t == 0) {
            int kmin = redi[0];
            ind[bbase + m] = kmin;
            out_ind[bbase + m] = (float)kmin;
            atomicAdd(&counts[kmin], 1);
            blockdiff += 2.f * redv[0] + redg[0];
        }
        __syncthreads();
    }
    if (t == 0) atomicAdd(diffsum, blockdiff);
}

// ---------------------------------------------------------------------------
// embedded_x = Hx @ Wx2 + bx2   [16384 x 64]
// block 256, 32 samples/block
// ---------------------------------------------------------------------------
__global__ __launch_bounds__(256) void ex_kernel(const float* __restrict__ Hx,
                                                 const float* __restrict__ Wx2,
                                                 const float* __restrict__ bx2,
                                                 float* __restrict__ EX) {
    __shared__ float hs[32][CH];      // 64 KB
    int bbase = blockIdx.x * 32;
    int t = threadIdx.x;
    for (int i = t; i < 32 * (CH / 4); i += 256) {
        int m = i >> 7, c4 = i & 127;
        ((float4*)hs[m])[c4] = ((const float4*)(Hx + (size_t)(bbase + m) * CH))[c4];
    }
    __syncthreads();
    int c = t & 63;
    int mg = t >> 6;                  // 0..3
    float acc[8] = {};
    for (int j = 0; j < CH; j += 4) {
        float w[4];
        #pragma unroll
        for (int dj = 0; dj < 4; ++dj) w[dj] = Wx2[(size_t)(j + dj) * DIN + c];
        #pragma unroll
        for (int mm = 0; mm < 8; ++mm) {
            int m = mg * 8 + mm;
            float4 hv = *(const float4*)&hs[m][j];
            acc[mm] = fmaf(hv.x, w[0], acc[mm]);
            acc[mm] = fmaf(hv.y, w[1], acc[mm]);
            acc[mm] = fmaf(hv.z, w[2], acc[mm]);
            acc[mm] = fmaf(hv.w, w[3], acc[mm]);
        }
    }
    float bias = bx2[c];
    #pragma unroll
    for (int mm = 0; mm < 8; ++mm) {
        int m = mg * 8 + mm;
        EX[(size_t)(bbase + m) * DIN + c] = acc[mm] + bias;
    }
}

// ---------------------------------------------------------------------------
// Finalize: offsets = exclusive scan(counts); perplexity; diff.  One block, 512 thr.
// ---------------------------------------------------------------------------
__global__ __launch_bounds__(512) void finalize_kernel(const int* __restrict__ counts,
                                                       int* __restrict__ offsets,
                                                       const float* __restrict__ diffsum,
                                                       const float* __restrict__ colsum,
                                                       const float* __restrict__ w0,
                                                       const float* __restrict__ bbuf,
                                                       float* __restrict__ out_diff,
                                                       float* __restrict__ out_perp) {
    __shared__ int   sc[512];
    __shared__ float sf[512];
    int t = threadIdx.x;
    int c = counts[t];
    sc[t] = c;
    double p = (double)c / (double)BN;
    double term = -p * log(p + 1e-10);
    float dotp = colsum[t] * w0[t];
    __syncthreads();
    int off = 0;
    for (int k = 0; k < t; ++k) off += sc[k];
    offsets[t] = off;
    sf[t] = dotp; __syncthreads();
    for (int s = 256; s > 0; s >>= 1) { if (t < s) sf[t] += sf[t + s]; __syncthreads(); }
    float dot_all = sf[0];
    __syncthreads();
    sf[t] = (float)term; __syncthreads();
    for (int s = 256; s > 0; s >>= 1) { if (t < s) sf[t] += sf[t + s]; __syncthreads(); }
    if (t == 0) {
        *out_perp = expf(sf[0]);
        *out_diff = (diffsum[0] + 2.f * dot_all + (float)BN * bbuf[0]) /
                    ((float)BN * (float)ED);
    }
}

// ---------------------------------------------------------------------------
// Scatter: perm[] groups sample ids by expert. cursors must be pre-zeroed.
// ---------------------------------------------------------------------------
__global__ __launch_bounds__(256) void scatter_kernel(const int* __restrict__ ind,
                                                      const int* __restrict__ offsets,
                                                      int* __restrict__ cursors,
                                                      int* __restrict__ perm) {
    int b = blockIdx.x * 256 + threadIdx.x;
    int k = ind[b];
    int pos = offsets[k] + atomicAdd(&cursors[k], 1);
    perm[pos] = b;
}

// ---------------------------------------------------------------------------
// Decoder: one block per expert k; W1[k],W2[k],b1,b2 staged in LDS once;
// 4 samples per iteration (thread = (slot, lane)).
// ---------------------------------------------------------------------------
__global__ __launch_bounds__(256) void decode_kernel(const float* __restrict__ EX,
                                                     const int* __restrict__ perm,
                                                     const int* __restrict__ offsets,
                                                     const int* __restrict__ counts,
                                                     const float* __restrict__ W1,
                                                     const float* __restrict__ b1,
                                                     const float* __restrict__ W2,
                                                     const float* __restrict__ b2,
                                                     float* __restrict__ dec) {
    int k = blockIdx.x;
    int n = counts[k];
    if (n == 0) return;                       // block-uniform
    __shared__ float w1s[64][65];
    __shared__ float w2s[64][33];
    __shared__ float b1s[64];
    __shared__ float b2s[32];
    __shared__ float exs[4][64];
    __shared__ float h2s[4][64];
    int t = threadIdx.x;
    for (int i = t; i < 4096; i += 256) w1s[i >> 6][i & 63] = W1[(size_t)k * 4096 + i];
    for (int i = t; i < 2048; i += 256) w2s[i >> 5][i & 31] = W2[(size_t)k * 2048 + i];
    if (t < 64) b1s[t] = b1[(size_t)k * 64 + t];
    if (t < 32) b2s[t] = b2[(size_t)k * 32 + t];
    __syncthreads();
    int base = offsets[k];
    int slot = t >> 6, l = t & 63;
    for (int s0 = 0; s0 < n; s0 += 4) {
        int si = s0 + slot;
        bool valid = si < n;
        int b = valid ? perm[base + si] : 0;
        if (valid) exs[slot][l] = EX[(size_t)b * DIN + l];
        __syncthreads();
        if (valid) {
            float h = b1s[l];
            #pragma unroll
            for (int j = 0; j < 64; ++j) h = fmaf(exs[slot][j], w1s[j][l], h);
            h2s[slot][l] = fmaxf(h, 0.f);
        }
        __syncthreads();
        if (valid && l < 32) {
            float d = b2s[l];
            #pragma unroll
            for (int j = 0; j < 64; ++j) d = fmaf(h2s[slot][j], w2s[j][l], d);
            dec[(size_t)b * DY + l] = d;
        }
        __syncthreads();
    }
}

// ---------------------------------------------------------------------------
extern "C" void kernel_launch(void* const* d_in, const int* in_sizes, int n_in,
                              void* d_out, int out_size, void* d_ws, size_t ws_size,
                              hipStream_t stream) {
    const float* x     = (const float*)d_in[0];
    const float* Wf1   = (const float*)d_in[1];
    const float* bf1   = (const float*)d_in[2];
    const float* Wf2   = (const float*)d_in[3];
    const float* bf2   = (const float*)d_in[4];
    const float* Wx1   = (const float*)d_in[5];
    const float* bx1   = (const float*)d_in[6];
    const float* Wx2   = (const float*)d_in[7];
    const float* bx2   = (const float*)d_in[8];
    const float* embed = (const float*)d_in[9];
    const float* W1    = (const float*)d_in[10];
    const float* b1    = (const float*)d_in[11];
    const float* W2    = (const float*)d_in[12];
    const float* b2    = (const float*)d_in[13];
    float* out = (float*)d_out;

    char* ws = (char*)d_ws;
    size_t off = 0;
    auto carve = [&](size_t bytes) -> void* {
        void* p = ws + off;
        off += (bytes + 255) & ~(size_t)255;
        return p;
    };
    float* H     = (float*)carve((size_t)BN * CH * 4);      // 33.5 MB
    float* Hx    = (float*)carve((size_t)BN * CH * 4);      // 33.5 MB
    float* Wf2T  = (float*)carve((size_t)ED * CH * 4);      // 12.8 MB
    float* EX    = (float*)carve((size_t)BN * DIN * 4);     // 4.2 MB
    char*  zbase = ws + off;                                 // ---- zero region ----
    float* We    = (float*)carve((size_t)KN * KN * 4);      // 1 MB
    float* G     = (float*)carve((size_t)KN * KN * 4);      // 1 MB
    float* s2    = (float*)carve(KN * 4);
    float* be    = (float*)carve(KN * 4);
    float* w0    = (float*)carve(CH * 4);
    float* colsum= (float*)carve(CH * 4);
    int*   counts= (int*)carve(KN * 4);
    int*   cursors=(int*)carve(KN * 4);
    float* diffsum=(float*)carve(256);
    float* bbuf  = (float*)carve(256);
    size_t zbytes = (size_t)(ws + off - zbase);              // ---- end zero region ----
    int*   ind     = (int*)carve(BN * 4);
    int*   offsets = (int*)carve(KN * 4);
    int*   perm    = (int*)carve(BN * 4);
    (void)in_sizes; (void)n_in; (void)out_size; (void)ws_size;

    hipMemsetAsync(zbase, 0, zbytes, stream);
    transpose_kernel<<<dim3(ED / 32, CH / 32), 256, 0, stream>>>(Wf2, Wf2T);
    psmall_kernel<<<dim3(32, 3), 256, 0, stream>>>(embed, bf2, Wf2T, s2, be, w0, bbuf);
    pgemm_kernel<<<dim3(4, 16, 8), 256, 0, stream>>>(Wf2, embed, We, 25, ED);
    pgemm_kernel<<<dim3(4, 16, 8), 256, 0, stream>>>(Wf2, Wf2T, G, 25, ED);
    enc1_kernel<<<BN / 16, 256, 0, stream>>>(x, Wf1, bf1, Wx1, bx1, H, Hx, colsum);
    score_kernel<<<BN / 16, 256, 0, stream>>>(H, We, G, s2, be, ind, counts, diffsum,
                                              out + OUT_IND);
    ex_kernel<<<BN / 32, 256, 0, stream>>>(Hx, Wx2, bx2, EX);
    finalize_kernel<<<1, 512, 0, stream>>>(counts, offsets, diffsum, colsum, w0, bbuf,
                                           out + OUT_DIFF, out + OUT_PERP);
    scatter_kernel<<<BN / 256, 256, 0, stream>>>(ind, offsets, cursors, perm);
    decode_kernel<<<KN, 256, 0, stream>>>(EX, perm, offsets, counts, W1, b1, W2, b2,
                                          out + OUT_DEC);
}

// Round 2
// 694.864 us; speedup vs baseline: 2.9811x; 2.9811x over previous
//
#include <hip/hip_runtime.h>
#include <math.h>

// Problem constants
#define BN     16384
#define INC    128
#define CH     512
#define ED     6240
#define KN     512      // NUM_EMB
#define DIN    64
#define DH     64
#define DY     32

// d_out layout (float32): dec[16384*32] | diff[1] | embed_ind[16384] | perplexity[1]
#define OUT_DEC   0
#define OUT_DIFF  (BN*DY)            // 524288
#define OUT_IND   (BN*DY + 1)        // 524289
#define OUT_PERP  (BN*DY + 1 + BN)   // 540673

// ---------------------------------------------------------------------------
// Transpose Wf2 [512][6240] -> Wf2T [6240][512]
// ---------------------------------------------------------------------------
__global__ __launch_bounds__(256) void transpose_kernel(const float* __restrict__ A,
                                                        float* __restrict__ At) {
    __shared__ float tile[32][33];
    int db = blockIdx.x * 32;           // d base (0..6239)
    int jb = blockIdx.y * 32;           // j base (0..511)
    int tx = threadIdx.x & 31, ty = threadIdx.x >> 5;   // ty 0..7
    #pragma unroll
    for (int r = ty; r < 32; r += 8)
        tile[r][tx] = A[(size_t)(jb + r) * ED + db + tx];
    __syncthreads();
    #pragma unroll
    for (int r = ty; r < 32; r += 8)
        At[(size_t)(db + r) * CH + jb + tx] = tile[tx][r];
}

// ---------------------------------------------------------------------------
// Small precomputes: s2[k]=||e_k||^2, be[k]=bf2.e_k, w0[j]=Wf2[j,:].bf2, bb=||bf2||^2
// ---------------------------------------------------------------------------
__global__ __launch_bounds__(256) void psmall_kernel(const float* __restrict__ embed,
                                                     const float* __restrict__ bf2,
                                                     const float* __restrict__ Wf2T,
                                                     float* __restrict__ s2,
                                                     float* __restrict__ be,
                                                     float* __restrict__ w0,
                                                     float* __restrict__ bbuf) {
    __shared__ float sf[256];
    int task = blockIdx.y;
    int t = threadIdx.x;
    if (task == 0) {
        int khalf = blockIdx.x & 1, chunk = blockIdx.x >> 1;   // 16 chunks of 390
        int k = khalf * 256 + t;
        float s = 0.f, b = 0.f;
        int d0 = chunk * 390, d1 = d0 + 390;
        for (int d = d0; d < d1; ++d) {
            float e = embed[(size_t)d * KN + k];
            s = fmaf(e, e, s);
            b = fmaf(bf2[d], e, b);
        }
        atomicAdd(&s2[k], s);
        atomicAdd(&be[k], b);
    } else if (task == 1) {
        int jhalf = blockIdx.x & 1, chunk = blockIdx.x >> 1;
        int j = jhalf * 256 + t;
        float w = 0.f;
        int d0 = chunk * 390, d1 = d0 + 390;
        for (int d = d0; d < d1; ++d)
            w = fmaf(bf2[d], Wf2T[(size_t)d * CH + j], w);
        atomicAdd(&w0[j], w);
    } else {
        if (blockIdx.x > 0) return;
        float s = 0.f;
        for (int d = t; d < ED; d += 256) { float v = bf2[d]; s = fmaf(v, v, s); }
        sf[t] = s; __syncthreads();
        for (int r = 128; r > 0; r >>= 1) { if (t < r) sf[t] += sf[t + r]; __syncthreads(); }
        if (t == 0) bbuf[0] = sf[0];
    }
}

// ---------------------------------------------------------------------------
// Tiled fp32 GEMM with K-split atomics: C[512x512] += A[512xK] @ Bm[Kx512]
// Used for We = Wf2 @ embed and G = Wf2 @ Wf2T. C must be pre-zeroed.
// ---------------------------------------------------------------------------
__global__ __launch_bounds__(256) void pgemm_kernel(const float* __restrict__ A,
                                                    const float* __restrict__ Bm,
                                                    float* __restrict__ C,
                                                    int ksteps_per, int Ktot) {
    __shared__ float As[32][36];
    __shared__ float Bs[32][132];
    int n0 = blockIdx.x * 128;
    int m0 = blockIdx.y * 32;
    int t = threadIdx.x;
    int mt = (t >> 5) << 2;      // 0..28
    int nt = (t & 31) << 2;      // 0..124
    float acc[4][4] = {};
    int nk = Ktot / 32;          // 195
    int kbegin = blockIdx.z * ksteps_per;
    int kend = kbegin + ksteps_per; if (kend > nk) kend = nk;
    for (int ks = kbegin; ks < kend; ++ks) {
        int kk = ks * 32;
        {   // A tile -> As[kc][m] (transposed in LDS)
            int row = t >> 3;            // 0..31
            int c4  = (t & 7) << 2;      // 0..28
            float4 av = *(const float4*)&A[(size_t)(m0 + row) * Ktot + kk + c4];
            As[c4 + 0][row] = av.x; As[c4 + 1][row] = av.y;
            As[c4 + 2][row] = av.z; As[c4 + 3][row] = av.w;
        }
        {   // B tile -> Bs[kc][n]
            int rr = t >> 5;             // 0..7
            int c4 = (t & 31) << 2;      // 0..124
            #pragma unroll
            for (int p = 0; p < 4; ++p) {
                int r = rr + p * 8;
                *(float4*)&Bs[r][c4] = *(const float4*)&Bm[(size_t)(kk + r) * KN + n0 + c4];
            }
        }
        __syncthreads();
        #pragma unroll
        for (int kc = 0; kc < 32; ++kc) {
            float4 a = *(const float4*)&As[kc][mt];
            float4 b = *(const float4*)&Bs[kc][nt];
            acc[0][0] = fmaf(a.x, b.x, acc[0][0]); acc[0][1] = fmaf(a.x, b.y, acc[0][1]);
            acc[0][2] = fmaf(a.x, b.z, acc[0][2]); acc[0][3] = fmaf(a.x, b.w, acc[0][3]);
            acc[1][0] = fmaf(a.y, b.x, acc[1][0]); acc[1][1] = fmaf(a.y, b.y, acc[1][1]);
            acc[1][2] = fmaf(a.y, b.z, acc[1][2]); acc[1][3] = fmaf(a.y, b.w, acc[1][3]);
            acc[2][0] = fmaf(a.z, b.x, acc[2][0]); acc[2][1] = fmaf(a.z, b.y, acc[2][1]);
            acc[2][2] = fmaf(a.z, b.z, acc[2][2]); acc[2][3] = fmaf(a.z, b.w, acc[2][3]);
            acc[3][0] = fmaf(a.w, b.x, acc[3][0]); acc[3][1] = fmaf(a.w, b.y, acc[3][1]);
            acc[3][2] = fmaf(a.w, b.z, acc[3][2]); acc[3][3] = fmaf(a.w, b.w, acc[3][3]);
        }
        __syncthreads();
    }
    #pragma unroll
    for (int i = 0; i < 4; ++i)
        #pragma unroll
        for (int j = 0; j < 4; ++j)
            atomicAdd(&C[(size_t)(m0 + mt + i) * KN + n0 + nt + j], acc[i][j]);
}

// ---------------------------------------------------------------------------
// Layer-1 for both encoders: H = relu(x@Wf1+bf1), Hx = relu(x@Wx1+bx1)
// Also accumulates colsum[c] = sum_b H[b][c] (for diff's 2*h.w0 term).
// ---------------------------------------------------------------------------
__global__ __launch_bounds__(256) void enc1_kernel(const float* __restrict__ x,
                                                   const float* __restrict__ Wf1,
                                                   const float* __restrict__ bf1,
                                                   const float* __restrict__ Wx1,
                                                   const float* __restrict__ bx1,
                                                   float* __restrict__ H,
                                                   float* __restrict__ Hx,
                                                   float* __restrict__ colsum) {
    __shared__ float xs[16][INC];     // 8 KB
    int bbase = blockIdx.x * 16;
    int t = threadIdx.x;
    for (int i = t; i < 16 * (INC / 4); i += 256) {
        int m = i >> 5, c4 = i & 31;
        ((float4*)xs[m])[c4] = ((const float4*)(x + (size_t)(bbase + m) * INC))[c4];
    }
    __syncthreads();
    float acc[16][4] = {};
    for (int j = 0; j < INC; j += 4) {
        float w[4][4];
        #pragma unroll
        for (int dj = 0; dj < 4; ++dj) {
            w[dj][0] = Wf1[(size_t)(j + dj) * CH + t];
            w[dj][1] = Wf1[(size_t)(j + dj) * CH + t + 256];
            w[dj][2] = Wx1[(size_t)(j + dj) * CH + t];
            w[dj][3] = Wx1[(size_t)(j + dj) * CH + t + 256];
        }
        #pragma unroll
        for (int m = 0; m < 16; ++m) {
            float4 hv = *(const float4*)&xs[m][j];
            float xv;
            xv = hv.x;
            acc[m][0] = fmaf(xv, w[0][0], acc[m][0]); acc[m][1] = fmaf(xv, w[0][1], acc[m][1]);
            acc[m][2] = fmaf(xv, w[0][2], acc[m][2]); acc[m][3] = fmaf(xv, w[0][3], acc[m][3]);
            xv = hv.y;
            acc[m][0] = fmaf(xv, w[1][0], acc[m][0]); acc[m][1] = fmaf(xv, w[1][1], acc[m][1]);
            acc[m][2] = fmaf(xv, w[1][2], acc[m][2]); acc[m][3] = fmaf(xv, w[1][3], acc[m][3]);
            xv = hv.z;
            acc[m][0] = fmaf(xv, w[2][0], acc[m][0]); acc[m][1] = fmaf(xv, w[2][1], acc[m][1]);
            acc[m][2] = fmaf(xv, w[2][2], acc[m][2]); acc[m][3] = fmaf(xv, w[2][3], acc[m][3]);
            xv = hv.w;
            acc[m][0] = fmaf(xv, w[3][0], acc[m][0]); acc[m][1] = fmaf(xv, w[3][1], acc[m][1]);
            acc[m][2] = fmaf(xv, w[3][2], acc[m][2]); acc[m][3] = fmaf(xv, w[3][3], acc[m][3]);
        }
    }
    float bf0 = bf1[t], bf1v = bf1[t + 256], bx0 = bx1[t], bx1v = bx1[t + 256];
    float cs0 = 0.f, cs1 = 0.f;
    #pragma unroll
    for (int m = 0; m < 16; ++m) {
        float v0 = fmaxf(acc[m][0] + bf0, 0.f);
        float v1 = fmaxf(acc[m][1] + bf1v, 0.f);
        float v2 = fmaxf(acc[m][2] + bx0, 0.f);
        float v3 = fmaxf(acc[m][3] + bx1v, 0.f);
        size_t row = (size_t)(bbase + m) * CH;
        H[row + t] = v0; H[row + t + 256] = v1;
        Hx[row + t] = v2; Hx[row + t + 256] = v3;
        cs0 += v0; cs1 += v1;
    }
    atomicAdd(&colsum[t], cs0);
    atomicAdd(&colsum[t + 256], cs1);
}

// ---------------------------------------------------------------------------
// Scoring kernel: per sample b,
//   g_k = 0.5*s2[k] - be[k] - h_b.We[:,k]   (argmin_k g_k == argmin_k dist)
//   hGh = sum_k (h_b.G[:,k]) * h_b[k]
// ---------------------------------------------------------------------------
__global__ __launch_bounds__(256) void score_kernel(const float* __restrict__ H,
                                                    const float* __restrict__ We,
                                                    const float* __restrict__ G,
                                                    const float* __restrict__ s2,
                                                    const float* __restrict__ be,
                                                    int* __restrict__ ind,
                                                    int* __restrict__ counts,
                                                    float* __restrict__ diffsum,
                                                    float* __restrict__ out_ind) {
    __shared__ float hs[16][CH];      // 32 KB
    __shared__ float redv[256];
    __shared__ int   redi[256];
    __shared__ float redg[256];
    int bbase = blockIdx.x * 16;
    int t = threadIdx.x;
    for (int i = t; i < 16 * (CH / 4); i += 256) {
        int m = i >> 7, c4 = i & 127;
        ((float4*)hs[m])[c4] = ((const float4*)(H + (size_t)(bbase + m) * CH))[c4];
    }
    __syncthreads();
    const int kA = t, kB = t + 256;
    float sA[16] = {}, sB[16] = {}, gA[16] = {}, gB[16] = {};
    for (int j = 0; j < CH; j += 4) {
        float wA[4], wB[4], qA[4], qB[4];
        #pragma unroll
        for (int dj = 0; dj < 4; ++dj) {
            size_t ro = (size_t)(j + dj) * KN;
            wA[dj] = We[ro + kA]; wB[dj] = We[ro + kB];
            qA[dj] = G[ro + kA];  qB[dj] = G[ro + kB];
        }
        #pragma unroll
        for (int m = 0; m < 16; ++m) {
            float4 hv = *(const float4*)&hs[m][j];
            sA[m] = fmaf(hv.x, wA[0], sA[m]); sA[m] = fmaf(hv.y, wA[1], sA[m]);
            sA[m] = fmaf(hv.z, wA[2], sA[m]); sA[m] = fmaf(hv.w, wA[3], sA[m]);
            sB[m] = fmaf(hv.x, wB[0], sB[m]); sB[m] = fmaf(hv.y, wB[1], sB[m]);
            sB[m] = fmaf(hv.z, wB[2], sB[m]); sB[m] = fmaf(hv.w, wB[3], sB[m]);
            gA[m] = fmaf(hv.x, qA[0], gA[m]); gA[m] = fmaf(hv.y, qA[1], gA[m]);
            gA[m] = fmaf(hv.z, qA[2], gA[m]); gA[m] = fmaf(hv.w, qA[3], gA[m]);
            gB[m] = fmaf(hv.x, qB[0], gB[m]); gB[m] = fmaf(hv.y, qB[1], gB[m]);
            gB[m] = fmaf(hv.z, qB[2], gB[m]); gB[m] = fmaf(hv.w, qB[3], gB[m]);
        }
    }
    float ckA = 0.5f * s2[kA] - be[kA];
    float ckB = 0.5f * s2[kB] - be[kB];
    float blockdiff = 0.f;   // thread 0 only
    for (int m = 0; m < 16; ++m) {
        float vA = ckA - sA[m];
        float vB = ckB - sB[m];
        float mv; int mi;
        if (vB < vA) { mv = vB; mi = kB; } else { mv = vA; mi = kA; }
        float gc = gA[m] * hs[m][kA] + gB[m] * hs[m][kB];
        redv[t] = mv; redi[t] = mi; redg[t] = gc;
        __syncthreads();
        for (int s = 128; s > 0; s >>= 1) {
            if (t < s) {
                float ov = redv[t + s]; int oi = redi[t + s];
                if (ov < redv[t] || (ov == redv[t] && oi < redi[t])) {
                    redv[t] = ov; redi[t] = oi;
                }
                redg[t] += redg[t + s];
            }
            __syncthreads();
        }
        if (t == 0) {
            int kmin = redi[0];
            ind[bbase + m] = kmin;
            out_ind[bbase + m] = (float)kmin;
            atomicAdd(&counts[kmin], 1);
            blockdiff += 2.f * redv[0] + redg[0];
        }
        __syncthreads();
    }
    if (t == 0) atomicAdd(diffsum, blockdiff);
}

// ---------------------------------------------------------------------------
// embedded_x = Hx @ Wx2 + bx2   [16384 x 64]
// ---------------------------------------------------------------------------
__global__ __launch_bounds__(256) void ex_kernel(const float* __restrict__ Hx,
                                                 const float* __restrict__ Wx2,
                                                 const float* __restrict__ bx2,
                                                 float* __restrict__ EX) {
    __shared__ float hs[32][CH];      // 64 KB
    int bbase = blockIdx.x * 32;
    int t = threadIdx.x;
    for (int i = t; i < 32 * (CH / 4); i += 256) {
        int m = i >> 7, c4 = i & 127;
        ((float4*)hs[m])[c4] = ((const float4*)(Hx + (size_t)(bbase + m) * CH))[c4];
    }
    __syncthreads();
    int c = t & 63;
    int mg = t >> 6;                  // 0..3
    float acc[8] = {};
    for (int j = 0; j < CH; j += 4) {
        float w[4];
        #pragma unroll
        for (int dj = 0; dj < 4; ++dj) w[dj] = Wx2[(size_t)(j + dj) * DIN + c];
        #pragma unroll
        for (int mm = 0; mm < 8; ++mm) {
            int m = mg * 8 + mm;
            float4 hv = *(const float4*)&hs[m][j];
            acc[mm] = fmaf(hv.x, w[0], acc[mm]);
            acc[mm] = fmaf(hv.y, w[1], acc[mm]);
            acc[mm] = fmaf(hv.z, w[2], acc[mm]);
            acc[mm] = fmaf(hv.w, w[3], acc[mm]);
        }
    }
    float bias = bx2[c];
    #pragma unroll
    for (int mm = 0; mm < 8; ++mm) {
        int m = mg * 8 + mm;
        EX[(size_t)(bbase + m) * DIN + c] = acc[mm] + bias;
    }
}

// ---------------------------------------------------------------------------
// Finalize: offsets = exclusive scan(counts); perplexity; diff.  One block, 512 thr.
// ---------------------------------------------------------------------------
__global__ __launch_bounds__(512) void finalize_kernel(const int* __restrict__ counts,
                                                       int* __restrict__ offsets,
                                                       const float* __restrict__ diffsum,
                                                       const float* __restrict__ colsum,
                                                       const float* __restrict__ w0,
                                                       const float* __restrict__ bbuf,
                                                       float* __restrict__ out_diff,
                                                       float* __restrict__ out_perp) {
    __shared__ int   sc[512];
    __shared__ float sf[512];
    int t = threadIdx.x;
    int c = counts[t];
    sc[t] = c;
    double p = (double)c / (double)BN;
    double term = -p * log(p + 1e-10);
    float dotp = colsum[t] * w0[t];
    __syncthreads();
    int off = 0;
    for (int k = 0; k < t; ++k) off += sc[k];
    offsets[t] = off;
    sf[t] = dotp; __syncthreads();
    for (int s = 256; s > 0; s >>= 1) { if (t < s) sf[t] += sf[t + s]; __syncthreads(); }
    float dot_all = sf[0];
    __syncthreads();
    sf[t] = (float)term; __syncthreads();
    for (int s = 256; s > 0; s >>= 1) { if (t < s) sf[t] += sf[t + s]; __syncthreads(); }
    if (t == 0) {
        *out_perp = expf(sf[0]);
        *out_diff = (diffsum[0] + 2.f * dot_all + (float)BN * bbuf[0]) /
                    ((float)BN * (float)ED);
    }
}

// ---------------------------------------------------------------------------
// Scatter: perm[] groups sample ids by expert. cursors must be pre-zeroed.
// ---------------------------------------------------------------------------
__global__ __launch_bounds__(256) void scatter_kernel(const int* __restrict__ ind,
                                                      const int* __restrict__ offsets,
                                                      int* __restrict__ cursors,
                                                      int* __restrict__ perm) {
    int b = blockIdx.x * 256 + threadIdx.x;
    int k = ind[b];
    int pos = offsets[k] + atomicAdd(&cursors[k], 1);
    perm[pos] = b;
}

// ---------------------------------------------------------------------------
// Decoder v2: ONE WAVE PER SAMPLE (load-balanced under arbitrary histogram
// skew — R1's per-expert version hit a 1.4 ms serial tail at 0.28% occupancy).
// Wave w of block handles sample perm[blockIdx*4+w]; weights read from global
// (12.6 MB unique — L2/L3 resident; sorted perm gives temporal locality).
// Lane l: h_l = relu(b1[k][l] + sum_j ex[j]*W1[k][j][l])  (coalesced rows)
// then lanes 0..31: dec_o = b2[k][o] + sum_j h_j*W2[k][j][o] via LDS h.
// ---------------------------------------------------------------------------
__global__ __launch_bounds__(256) void decode_kernel(const float* __restrict__ EX,
                                                     const int* __restrict__ perm,
                                                     const int* __restrict__ ind,
                                                     const float* __restrict__ W1,
                                                     const float* __restrict__ b1,
                                                     const float* __restrict__ W2,
                                                     const float* __restrict__ b2,
                                                     float* __restrict__ dec) {
    __shared__ float exs[4][DIN];
    __shared__ float h2s[4][DH];
    int t = threadIdx.x;
    int w = t >> 6, l = t & 63;
    int s = blockIdx.x * 4 + w;
    int b = perm[s];
    int k = ind[b];
    exs[w][l] = EX[(size_t)b * DIN + l];
    __syncthreads();
    const float* w1 = W1 + (size_t)k * (DIN * DH);
    float h = b1[(size_t)k * DH + l];
    #pragma unroll
    for (int j = 0; j < DIN; ++j)
        h = fmaf(exs[w][j], w1[(size_t)j * DH + l], h);
    h2s[w][l] = fmaxf(h, 0.f);
    __syncthreads();
    if (l < DY) {
        const float* w2 = W2 + (size_t)k * (DH * DY);
        float d = b2[(size_t)k * DY + l];
        #pragma unroll
        for (int j = 0; j < DH; ++j)
            d = fmaf(h2s[w][j], w2[(size_t)j * DY + l], d);
        dec[(size_t)b * DY + l] = d;
    }
}

// ---------------------------------------------------------------------------
extern "C" void kernel_launch(void* const* d_in, const int* in_sizes, int n_in,
                              void* d_out, int out_size, void* d_ws, size_t ws_size,
                              hipStream_t stream) {
    const float* x     = (const float*)d_in[0];
    const float* Wf1   = (const float*)d_in[1];
    const float* bf1   = (const float*)d_in[2];
    const float* Wf2   = (const float*)d_in[3];
    const float* bf2   = (const float*)d_in[4];
    const float* Wx1   = (const float*)d_in[5];
    const float* bx1   = (const float*)d_in[6];
    const float* Wx2   = (const float*)d_in[7];
    const float* bx2   = (const float*)d_in[8];
    const float* embed = (const float*)d_in[9];
    const float* W1    = (const float*)d_in[10];
    const float* b1    = (const float*)d_in[11];
    const float* W2    = (const float*)d_in[12];
    const float* b2    = (const float*)d_in[13];
    float* out = (float*)d_out;

    char* ws = (char*)d_ws;
    size_t off = 0;
    auto carve = [&](size_t bytes) -> void* {
        void* p = ws + off;
        off += (bytes + 255) & ~(size_t)255;
        return p;
    };
    float* H     = (float*)carve((size_t)BN * CH * 4);      // 33.5 MB
    float* Hx    = (float*)carve((size_t)BN * CH * 4);      // 33.5 MB
    float* Wf2T  = (float*)carve((size_t)ED * CH * 4);      // 12.8 MB
    float* EX    = (float*)carve((size_t)BN * DIN * 4);     // 4.2 MB
    char*  zbase = ws + off;                                 // ---- zero region ----
    float* We    = (float*)carve((size_t)KN * KN * 4);      // 1 MB
    float* G     = (float*)carve((size_t)KN * KN * 4);      // 1 MB
    float* s2    = (float*)carve(KN * 4);
    float* be    = (float*)carve(KN * 4);
    float* w0    = (float*)carve(CH * 4);
    float* colsum= (float*)carve(CH * 4);
    int*   counts= (int*)carve(KN * 4);
    int*   cursors=(int*)carve(KN * 4);
    float* diffsum=(float*)carve(256);
    float* bbuf  = (float*)carve(256);
    size_t zbytes = (size_t)(ws + off - zbase);              // ---- end zero region ----
    int*   ind     = (int*)carve(BN * 4);
    int*   offsets = (int*)carve(KN * 4);
    int*   perm    = (int*)carve(BN * 4);
    (void)in_sizes; (void)n_in; (void)out_size; (void)ws_size;

    hipMemsetAsync(zbase, 0, zbytes, stream);
    transpose_kernel<<<dim3(ED / 32, CH / 32), 256, 0, stream>>>(Wf2, Wf2T);
    psmall_kernel<<<dim3(32, 3), 256, 0, stream>>>(embed, bf2, Wf2T, s2, be, w0, bbuf);
    pgemm_kernel<<<dim3(4, 16, 8), 256, 0, stream>>>(Wf2, embed, We, 25, ED);
    pgemm_kernel<<<dim3(4, 16, 8), 256, 0, stream>>>(Wf2, Wf2T, G, 25, ED);
    enc1_kernel<<<BN / 16, 256, 0, stream>>>(x, Wf1, bf1, Wx1, bx1, H, Hx, colsum);
    score_kernel<<<BN / 16, 256, 0, stream>>>(H, We, G, s2, be, ind, counts, diffsum,
                                              out + OUT_IND);
    ex_kernel<<<BN / 32, 256, 0, stream>>>(Hx, Wx2, bx2, EX);
    finalize_kernel<<<1, 512, 0, stream>>>(counts, offsets, diffsum, colsum, w0, bbuf,
                                           out + OUT_DIFF, out + OUT_PERP);
    scatter_kernel<<<BN / 256, 256, 0, stream>>>(ind, offsets, cursors, perm);
    decode_kernel<<<BN / 4, 256, 0, stream>>>(EX, perm, ind, W1, b1, W2, b2,
                                              out + OUT_DEC);
}

// Round 3
// 611.345 us; speedup vs baseline: 3.3884x; 1.1366x over previous
//
#include <hip/hip_runtime.h>
#include <math.h>

// Problem constants
#define BN     16384
#define INC    128
#define CH     512
#define ED     6240
#define KN     512      // NUM_EMB
#define DIN    64
#define DH     64
#define DY     32

// d_out layout (float32): dec[16384*32] | diff[1] | embed_ind[16384] | perplexity[1]
#define OUT_DEC   0
#define OUT_DIFF  (BN*DY)            // 524288
#define OUT_IND   (BN*DY + 1)        // 524289
#define OUT_PERP  (BN*DY + 1 + BN)   // 540673

typedef _Float16 half8 __attribute__((ext_vector_type(8)));
typedef float    f32x4 __attribute__((ext_vector_type(4)));
#define MFMA16(a, b, c) __builtin_amdgcn_mfma_f32_16x16x32_f16(a, b, c, 0, 0, 0)

// ---------------------------------------------------------------------------
// Transpose Wf2 [512][6240] -> Wf2T [6240][512]
// ---------------------------------------------------------------------------
__global__ __launch_bounds__(256) void transpose_kernel(const float* __restrict__ A,
                                                        float* __restrict__ At) {
    __shared__ float tile[32][33];
    int db = blockIdx.x * 32;           // d base (0..6239)
    int jb = blockIdx.y * 32;           // j base (0..511)
    int tx = threadIdx.x & 31, ty = threadIdx.x >> 5;   // ty 0..7
    #pragma unroll
    for (int r = ty; r < 32; r += 8)
        tile[r][tx] = A[(size_t)(jb + r) * ED + db + tx];
    __syncthreads();
    #pragma unroll
    for (int r = ty; r < 32; r += 8)
        At[(size_t)(db + r) * CH + jb + tx] = tile[tx][r];
}

// ---------------------------------------------------------------------------
// Small precomputes: s2[k]=||e_k||^2, be[k]=bf2.e_k, w0[j]=Wf2[j,:].bf2, bb=||bf2||^2
// ---------------------------------------------------------------------------
__global__ __launch_bounds__(256) void psmall_kernel(const float* __restrict__ embed,
                                                     const float* __restrict__ bf2,
                                                     const float* __restrict__ Wf2T,
                                                     float* __restrict__ s2,
                                                     float* __restrict__ be,
                                                     float* __restrict__ w0,
                                                     float* __restrict__ bbuf) {
    __shared__ float sf[256];
    int task = blockIdx.y;
    int t = threadIdx.x;
    if (task == 0) {
        int khalf = blockIdx.x & 1, chunk = blockIdx.x >> 1;   // 16 chunks of 390
        int k = khalf * 256 + t;
        float s = 0.f, b = 0.f;
        int d0 = chunk * 390, d1 = d0 + 390;
        for (int d = d0; d < d1; ++d) {
            float e = embed[(size_t)d * KN + k];
            s = fmaf(e, e, s);
            b = fmaf(bf2[d], e, b);
        }
        atomicAdd(&s2[k], s);
        atomicAdd(&be[k], b);
    } else if (task == 1) {
        int jhalf = blockIdx.x & 1, chunk = blockIdx.x >> 1;
        int j = jhalf * 256 + t;
        float w = 0.f;
        int d0 = chunk * 390, d1 = d0 + 390;
        for (int d = d0; d < d1; ++d)
            w = fmaf(bf2[d], Wf2T[(size_t)d * CH + j], w);
        atomicAdd(&w0[j], w);
    } else {
        if (blockIdx.x > 0) return;
        float s = 0.f;
        for (int d = t; d < ED; d += 256) { float v = bf2[d]; s = fmaf(v, v, s); }
        sf[t] = s; __syncthreads();
        for (int r = 128; r > 0; r >>= 1) { if (t < r) sf[t] += sf[t + r]; __syncthreads(); }
        if (t == 0) bbuf[0] = sf[0];
    }
}

// ---------------------------------------------------------------------------
// Tiled fp32 GEMM with K-split atomics: C[512x512] += A[512xK] @ Bm[Kx512]
// Used for We = Wf2 @ embed and G = Wf2 @ Wf2T. C must be pre-zeroed.
// ---------------------------------------------------------------------------
__global__ __launch_bounds__(256) void pgemm_kernel(const float* __restrict__ A,
                                                    const float* __restrict__ Bm,
                                                    float* __restrict__ C,
                                                    int ksteps_per, int Ktot) {
    __shared__ float As[32][36];
    __shared__ float Bs[32][132];
    int n0 = blockIdx.x * 128;
    int m0 = blockIdx.y * 32;
    int t = threadIdx.x;
    int mt = (t >> 5) << 2;      // 0..28
    int nt = (t & 31) << 2;      // 0..124
    float acc[4][4] = {};
    int nk = Ktot / 32;          // 195
    int kbegin = blockIdx.z * ksteps_per;
    int kend = kbegin + ksteps_per; if (kend > nk) kend = nk;
    for (int ks = kbegin; ks < kend; ++ks) {
        int kk = ks * 32;
        {   // A tile -> As[kc][m] (transposed in LDS)
            int row = t >> 3;            // 0..31
            int c4  = (t & 7) << 2;      // 0..28
            float4 av = *(const float4*)&A[(size_t)(m0 + row) * Ktot + kk + c4];
            As[c4 + 0][row] = av.x; As[c4 + 1][row] = av.y;
            As[c4 + 2][row] = av.z; As[c4 + 3][row] = av.w;
        }
        {   // B tile -> Bs[kc][n]
            int rr = t >> 5;             // 0..7
            int c4 = (t & 31) << 2;      // 0..124
            #pragma unroll
            for (int p = 0; p < 4; ++p) {
                int r = rr + p * 8;
                *(float4*)&Bs[r][c4] = *(const float4*)&Bm[(size_t)(kk + r) * KN + n0 + c4];
            }
        }
        __syncthreads();
        #pragma unroll
        for (int kc = 0; kc < 32; ++kc) {
            float4 a = *(const float4*)&As[kc][mt];
            float4 b = *(const float4*)&Bs[kc][nt];
            acc[0][0] = fmaf(a.x, b.x, acc[0][0]); acc[0][1] = fmaf(a.x, b.y, acc[0][1]);
            acc[0][2] = fmaf(a.x, b.z, acc[0][2]); acc[0][3] = fmaf(a.x, b.w, acc[0][3]);
            acc[1][0] = fmaf(a.y, b.x, acc[1][0]); acc[1][1] = fmaf(a.y, b.y, acc[1][1]);
            acc[1][2] = fmaf(a.y, b.z, acc[1][2]); acc[1][3] = fmaf(a.y, b.w, acc[1][3]);
            acc[2][0] = fmaf(a.z, b.x, acc[2][0]); acc[2][1] = fmaf(a.z, b.y, acc[2][1]);
            acc[2][2] = fmaf(a.z, b.z, acc[2][2]); acc[2][3] = fmaf(a.z, b.w, acc[2][3]);
            acc[3][0] = fmaf(a.w, b.x, acc[3][0]); acc[3][1] = fmaf(a.w, b.y, acc[3][1]);
            acc[3][2] = fmaf(a.w, b.z, acc[3][2]); acc[3][3] = fmaf(a.w, b.w, acc[3][3]);
        }
        __syncthreads();
    }
    #pragma unroll
    for (int i = 0; i < 4; ++i)
        #pragma unroll
        for (int j = 0; j < 4; ++j)
            atomicAdd(&C[(size_t)(m0 + mt + i) * KN + n0 + nt + j], acc[i][j]);
}

// ---------------------------------------------------------------------------
// Layer-1 for both encoders: h = relu(x@Wf1+bf1) -> SPLIT fp16 (Hs+Hl),
// Hx = relu(x@Wx1+bx1) -> fp32. colsum[c] = sum_b h[b][c].
// ---------------------------------------------------------------------------
__global__ __launch_bounds__(256) void enc1_kernel(const float* __restrict__ x,
                                                   const float* __restrict__ Wf1,
                                                   const float* __restrict__ bf1,
                                                   const float* __restrict__ Wx1,
                                                   const float* __restrict__ bx1,
                                                   _Float16* __restrict__ Hs,
                                                   _Float16* __restrict__ Hl,
                                                   float* __restrict__ Hx,
                                                   float* __restrict__ colsum) {
    __shared__ float xs[16][INC];     // 8 KB
    int bbase = blockIdx.x * 16;
    int t = threadIdx.x;
    for (int i = t; i < 16 * (INC / 4); i += 256) {
        int m = i >> 5, c4 = i & 31;
        ((float4*)xs[m])[c4] = ((const float4*)(x + (size_t)(bbase + m) * INC))[c4];
    }
    __syncthreads();
    float acc[16][4] = {};
    for (int j = 0; j < INC; j += 4) {
        float w[4][4];
        #pragma unroll
        for (int dj = 0; dj < 4; ++dj) {
            w[dj][0] = Wf1[(size_t)(j + dj) * CH + t];
            w[dj][1] = Wf1[(size_t)(j + dj) * CH + t + 256];
            w[dj][2] = Wx1[(size_t)(j + dj) * CH + t];
            w[dj][3] = Wx1[(size_t)(j + dj) * CH + t + 256];
        }
        #pragma unroll
        for (int m = 0; m < 16; ++m) {
            float4 hv = *(const float4*)&xs[m][j];
            float xv;
            xv = hv.x;
            acc[m][0] = fmaf(xv, w[0][0], acc[m][0]); acc[m][1] = fmaf(xv, w[0][1], acc[m][1]);
            acc[m][2] = fmaf(xv, w[0][2], acc[m][2]); acc[m][3] = fmaf(xv, w[0][3], acc[m][3]);
            xv = hv.y;
            acc[m][0] = fmaf(xv, w[1][0], acc[m][0]); acc[m][1] = fmaf(xv, w[1][1], acc[m][1]);
            acc[m][2] = fmaf(xv, w[1][2], acc[m][2]); acc[m][3] = fmaf(xv, w[1][3], acc[m][3]);
            xv = hv.z;
            acc[m][0] = fmaf(xv, w[2][0], acc[m][0]); acc[m][1] = fmaf(xv, w[2][1], acc[m][1]);
            acc[m][2] = fmaf(xv, w[2][2], acc[m][2]); acc[m][3] = fmaf(xv, w[2][3], acc[m][3]);
            xv = hv.w;
            acc[m][0] = fmaf(xv, w[3][0], acc[m][0]); acc[m][1] = fmaf(xv, w[3][1], acc[m][1]);
            acc[m][2] = fmaf(xv, w[3][2], acc[m][2]); acc[m][3] = fmaf(xv, w[3][3], acc[m][3]);
        }
    }
    float bf0 = bf1[t], bf1v = bf1[t + 256], bx0 = bx1[t], bx1v = bx1[t + 256];
    float cs0 = 0.f, cs1 = 0.f;
    #pragma unroll
    for (int m = 0; m < 16; ++m) {
        float v0 = fmaxf(acc[m][0] + bf0, 0.f);
        float v1 = fmaxf(acc[m][1] + bf1v, 0.f);
        float v2 = fmaxf(acc[m][2] + bx0, 0.f);
        float v3 = fmaxf(acc[m][3] + bx1v, 0.f);
        size_t row = (size_t)(bbase + m) * CH;
        _Float16 h0 = (_Float16)v0;
        _Float16 h1 = (_Float16)v1;
        Hs[row + t] = h0;        Hl[row + t] = (_Float16)(v0 - (float)h0);
        Hs[row + t + 256] = h1;  Hl[row + t + 256] = (_Float16)(v1 - (float)h1);
        Hx[row + t] = v2; Hx[row + t + 256] = v3;
        cs0 += v0; cs1 += v1;
    }
    atomicAdd(&colsum[t], cs0);
    atomicAdd(&colsum[t + 256], cs1);
}

// ---------------------------------------------------------------------------
// We fp32 [CH][KN] -> WeT hi/lo fp16 [KN][CH]   (transpose + split)
// ---------------------------------------------------------------------------
__global__ __launch_bounds__(256) void wesplit_kernel(const float* __restrict__ We,
                                                      _Float16* __restrict__ WeTs,
                                                      _Float16* __restrict__ WeTl) {
    __shared__ float tile[32][33];
    int kb = blockIdx.x * 32;          // KN dim
    int jb = blockIdx.y * 32;          // CH dim
    int tx = threadIdx.x & 31, ty = threadIdx.x >> 5;
    #pragma unroll
    for (int r = ty; r < 32; r += 8)
        tile[r][tx] = We[(size_t)(jb + r) * KN + kb + tx];
    __syncthreads();
    #pragma unroll
    for (int r = ty; r < 32; r += 8) {
        float v = tile[tx][r];
        _Float16 hi = (_Float16)v;
        size_t idx = (size_t)(kb + r) * CH + jb + tx;
        WeTs[idx] = hi;
        WeTl[idx] = (_Float16)(v - (float)hi);
    }
}

// ---------------------------------------------------------------------------
// G fp32 -> fp16 (straight; G symmetric so row-major == needed B layout)
// ---------------------------------------------------------------------------
__global__ __launch_bounds__(256) void gconv_kernel(const float* __restrict__ G,
                                                    _Float16* __restrict__ Ghi) {
    int i = (blockIdx.x * 256 + threadIdx.x) * 4;
    float4 v = *(const float4*)&G[i];
    Ghi[i + 0] = (_Float16)v.x;
    Ghi[i + 1] = (_Float16)v.y;
    Ghi[i + 2] = (_Float16)v.z;
    Ghi[i + 3] = (_Float16)v.w;
}

// ---------------------------------------------------------------------------
// MFMA scoring kernel. Block = 32 samples, 4 waves; wave w owns cols
// [128w,128w+128) of both We (split 3-pass) and G (1-pass).
// Layouts (verified, guide §3): A[m=lane&15][k=quad*8+j], B[n=lane&15][k=...],
// D: row=quad*4+reg, col=lane&15. WeT/G stored [col][CH] fp16.
//   g_k = 0.5*s2[k]-be[k]-h.We[:,k]; argmin_k; hGh = sum_k (h.G[:,k]) h[k]
// ---------------------------------------------------------------------------
__global__ __launch_bounds__(256) void score_mfma_kernel(
        const _Float16* __restrict__ Hs, const _Float16* __restrict__ Hl,
        const _Float16* __restrict__ WeTs, const _Float16* __restrict__ WeTl,
        const _Float16* __restrict__ Ghi,
        const float* __restrict__ s2, const float* __restrict__ be,
        int* __restrict__ ind, int* __restrict__ counts,
        float* __restrict__ diffsum, float* __restrict__ out_ind) {
    __shared__ float redv[4][32];
    __shared__ int   redi[4][32];
    __shared__ float redg[4][32];
    __shared__ float fin[32];
    int t = threadIdx.x;
    int w = t >> 6, L = t & 63;
    int lane16 = L & 15, quad = L >> 4;
    int m0 = blockIdx.x * 32;
    const _Float16* a0s = Hs + (size_t)(m0 + lane16) * CH + quad * 8;
    const _Float16* a0l = Hl + (size_t)(m0 + lane16) * CH + quad * 8;
    const _Float16* a1s = a0s + (size_t)16 * CH;
    const _Float16* a1l = a0l + (size_t)16 * CH;
    int col0 = w * 128 + lane16;
    const _Float16* bs = WeTs + (size_t)col0 * CH + quad * 8;
    const _Float16* bl = WeTl + (size_t)col0 * CH + quad * 8;
    f32x4 acc[2][8];
    #pragma unroll
    for (int rt = 0; rt < 2; ++rt)
        #pragma unroll
        for (int tt = 0; tt < 8; ++tt) acc[rt][tt] = (f32x4){0.f, 0.f, 0.f, 0.f};

    // ---- Phase 1: We scores, 3-pass fp16 split (fp32-equivalent accuracy) ----
    for (int ks = 0; ks < 16; ++ks) {
        int ko = ks * 32;
        half8 A0h = *(const half8*)(a0s + ko);
        half8 A0l = *(const half8*)(a0l + ko);
        half8 A1h = *(const half8*)(a1s + ko);
        half8 A1l = *(const half8*)(a1l + ko);
        #pragma unroll
        for (int tt = 0; tt < 8; ++tt) {
            half8 Bh = *(const half8*)(bs + (size_t)tt * 16 * CH + ko);
            half8 Bl = *(const half8*)(bl + (size_t)tt * 16 * CH + ko);
            acc[0][tt] = MFMA16(A0h, Bh, acc[0][tt]);
            acc[0][tt] = MFMA16(A0l, Bh, acc[0][tt]);
            acc[0][tt] = MFMA16(A0h, Bl, acc[0][tt]);
            acc[1][tt] = MFMA16(A1h, Bh, acc[1][tt]);
            acc[1][tt] = MFMA16(A1l, Bh, acc[1][tt]);
            acc[1][tt] = MFMA16(A1h, Bl, acc[1][tt]);
        }
    }
    // ck[col] for this lane's 8 tile-columns
    float cks[8];
    #pragma unroll
    for (int tt = 0; tt < 8; ++tt) {
        int c = w * 128 + tt * 16 + lane16;
        cks[tt] = 0.5f * s2[c] - be[c];
    }
    // per-(row-tile, reg) argmin over this wave's 128 cols, via quad shuffles
    #pragma unroll
    for (int rt = 0; rt < 2; ++rt) {
        #pragma unroll
        for (int r = 0; r < 4; ++r) {
            float mv = cks[0] - acc[rt][0][r];
            int   mi = w * 128 + lane16;
            #pragma unroll
            for (int tt = 1; tt < 8; ++tt) {
                float v = cks[tt] - acc[rt][tt][r];
                int   c = w * 128 + tt * 16 + lane16;
                if (v < mv) { mv = v; mi = c; }
            }
            #pragma unroll
            for (int d = 1; d < 16; d <<= 1) {
                float ov = __shfl_xor(mv, d);
                int   oi = __shfl_xor(mi, d);
                if (ov < mv || (ov == mv && oi < mi)) { mv = ov; mi = oi; }
            }
            if (lane16 == 0) {
                int row = rt * 16 + quad * 4 + r;
                redv[w][row] = mv; redi[w][row] = mi;
            }
        }
    }

    // ---- Phase 2: G scores (1-pass), hGh partials ----
    #pragma unroll
    for (int rt = 0; rt < 2; ++rt)
        #pragma unroll
        for (int tt = 0; tt < 8; ++tt) acc[rt][tt] = (f32x4){0.f, 0.f, 0.f, 0.f};
    const _Float16* bg = Ghi + (size_t)col0 * CH + quad * 8;
    for (int ks = 0; ks < 16; ++ks) {
        int ko = ks * 32;
        half8 A0h = *(const half8*)(a0s + ko);
        half8 A1h = *(const half8*)(a1s + ko);
        #pragma unroll
        for (int tt = 0; tt < 8; ++tt) {
            half8 Bg = *(const half8*)(bg + (size_t)tt * 16 * CH + ko);
            acc[0][tt] = MFMA16(A0h, Bg, acc[0][tt]);
            acc[1][tt] = MFMA16(A1h, Bg, acc[1][tt]);
        }
    }
    #pragma unroll
    for (int rt = 0; rt < 2; ++rt) {
        #pragma unroll
        for (int r = 0; r < 4; ++r) {
            int row = m0 + rt * 16 + quad * 4 + r;
            float s = 0.f;
            #pragma unroll
            for (int tt = 0; tt < 8; ++tt) {
                int c = w * 128 + tt * 16 + lane16;
                float h = (float)Hs[(size_t)row * CH + c] + (float)Hl[(size_t)row * CH + c];
                s += acc[rt][tt][r] * h;
            }
            #pragma unroll
            for (int d = 1; d < 16; d <<= 1) s += __shfl_xor(s, d);
            if (lane16 == 0) redg[w][rt * 16 + quad * 4 + r] = s;
        }
    }
    __syncthreads();

    // ---- finalize rows ----
    if (t < 32) {
        int row = t;
        float mv = redv[0][row]; int mi = redi[0][row];
        #pragma unroll
        for (int w2 = 1; w2 < 4; ++w2) {
            float ov = redv[w2][row]; int oi = redi[w2][row];
            if (ov < mv || (ov == mv && oi < mi)) { mv = ov; mi = oi; }
        }
        float hGh = redg[0][row] + redg[1][row] + redg[2][row] + redg[3][row];
        int b = m0 + row;
        ind[b] = mi;
        out_ind[b] = (float)mi;
        atomicAdd(&counts[mi], 1);
        fin[row] = 2.f * mv + hGh;
    }
    __syncthreads();
    if (t == 0) {
        float s = 0.f;
        #pragma unroll
        for (int i = 0; i < 32; ++i) s += fin[i];
        atomicAdd(diffsum, s);
    }
}

// ---------------------------------------------------------------------------
// embedded_x = Hx @ Wx2 + bx2   [16384 x 64]
// ---------------------------------------------------------------------------
__global__ __launch_bounds__(256) void ex_kernel(const float* __restrict__ Hx,
                                                 const float* __restrict__ Wx2,
                                                 const float* __restrict__ bx2,
                                                 float* __restrict__ EX) {
    __shared__ float hs[32][CH];      // 64 KB
    int bbase = blockIdx.x * 32;
    int t = threadIdx.x;
    for (int i = t; i < 32 * (CH / 4); i += 256) {
        int m = i >> 7, c4 = i & 127;
        ((float4*)hs[m])[c4] = ((const float4*)(Hx + (size_t)(bbase + m) * CH))[c4];
    }
    __syncthreads();
    int c = t & 63;
    int mg = t >> 6;                  // 0..3
    float acc[8] = {};
    for (int j = 0; j < CH; j += 4) {
        float w[4];
        #pragma unroll
        for (int dj = 0; dj < 4; ++dj) w[dj] = Wx2[(size_t)(j + dj) * DIN + c];
        #pragma unroll
        for (int mm = 0; mm < 8; ++mm) {
            int m = mg * 8 + mm;
            float4 hv = *(const float4*)&hs[m][j];
            acc[mm] = fmaf(hv.x, w[0], acc[mm]);
            acc[mm] = fmaf(hv.y, w[1], acc[mm]);
            acc[mm] = fmaf(hv.z, w[2], acc[mm]);
            acc[mm] = fmaf(hv.w, w[3], acc[mm]);
        }
    }
    float bias = bx2[c];
    #pragma unroll
    for (int mm = 0; mm < 8; ++mm) {
        int m = mg * 8 + mm;
        EX[(size_t)(bbase + m) * DIN + c] = acc[mm] + bias;
    }
}

// ---------------------------------------------------------------------------
// Finalize: offsets = exclusive scan(counts); perplexity; diff.  One block, 512 thr.
// ---------------------------------------------------------------------------
__global__ __launch_bounds__(512) void finalize_kernel(const int* __restrict__ counts,
                                                       int* __restrict__ offsets,
                                                       const float* __restrict__ diffsum,
                                                       const float* __restrict__ colsum,
                                                       const float* __restrict__ w0,
                                                       const float* __restrict__ bbuf,
                                                       float* __restrict__ out_diff,
                                                       float* __restrict__ out_perp) {
    __shared__ int   sc[512];
    __shared__ float sf[512];
    int t = threadIdx.x;
    int c = counts[t];
    sc[t] = c;
    double p = (double)c / (double)BN;
    double term = -p * log(p + 1e-10);
    float dotp = colsum[t] * w0[t];
    __syncthreads();
    int off = 0;
    for (int k = 0; k < t; ++k) off += sc[k];
    offsets[t] = off;
    sf[t] = dotp; __syncthreads();
    for (int s = 256; s > 0; s >>= 1) { if (t < s) sf[t] += sf[t + s]; __syncthreads(); }
    float dot_all = sf[0];
    __syncthreads();
    sf[t] = (float)term; __syncthreads();
    for (int s = 256; s > 0; s >>= 1) { if (t < s) sf[t] += sf[t + s]; __syncthreads(); }
    if (t == 0) {
        *out_perp = expf(sf[0]);
        *out_diff = (diffsum[0] + 2.f * dot_all + (float)BN * bbuf[0]) /
                    ((float)BN * (float)ED);
    }
}

// ---------------------------------------------------------------------------
// Scatter: perm[] groups sample ids by expert. cursors must be pre-zeroed.
// ---------------------------------------------------------------------------
__global__ __launch_bounds__(256) void scatter_kernel(const int* __restrict__ ind,
                                                      const int* __restrict__ offsets,
                                                      int* __restrict__ cursors,
                                                      int* __restrict__ perm) {
    int b = blockIdx.x * 256 + threadIdx.x;
    int k = ind[b];
    int pos = offsets[k] + atomicAdd(&cursors[k], 1);
    perm[pos] = b;
}

// ---------------------------------------------------------------------------
// Decoder: one wave per sample (load-balanced under histogram skew).
// ---------------------------------------------------------------------------
__global__ __launch_bounds__(256) void decode_kernel(const float* __restrict__ EX,
                                                     const int* __restrict__ perm,
                                                     const int* __restrict__ ind,
                                                     const float* __restrict__ W1,
                                                     const float* __restrict__ b1,
                                                     const float* __restrict__ W2,
                                                     const float* __restrict__ b2,
                                                     float* __restrict__ dec) {
    __shared__ float exs[4][DIN];
    __shared__ float h2s[4][DH];
    int t = threadIdx.x;
    int w = t >> 6, l = t & 63;
    int s = blockIdx.x * 4 + w;
    int b = perm[s];
    int k = ind[b];
    exs[w][l] = EX[(size_t)b * DIN + l];
    __syncthreads();
    const float* w1 = W1 + (size_t)k * (DIN * DH);
    float h = b1[(size_t)k * DH + l];
    #pragma unroll
    for (int j = 0; j < DIN; ++j)
        h = fmaf(exs[w][j], w1[(size_t)j * DH + l], h);
    h2s[w][l] = fmaxf(h, 0.f);
    __syncthreads();
    if (l < DY) {
        const float* w2 = W2 + (size_t)k * (DH * DY);
        float d = b2[(size_t)k * DY + l];
        #pragma unroll
        for (int j = 0; j < DH; ++j)
            d = fmaf(h2s[w][j], w2[(size_t)j * DY + l], d);
        dec[(size_t)b * DY + l] = d;
    }
}

// ---------------------------------------------------------------------------
extern "C" void kernel_launch(void* const* d_in, const int* in_sizes, int n_in,
                              void* d_out, int out_size, void* d_ws, size_t ws_size,
                              hipStream_t stream) {
    const float* x     = (const float*)d_in[0];
    const float* Wf1   = (const float*)d_in[1];
    const float* bf1   = (const float*)d_in[2];
    const float* Wf2   = (const float*)d_in[3];
    const float* bf2   = (const float*)d_in[4];
    const float* Wx1   = (const float*)d_in[5];
    const float* bx1   = (const float*)d_in[6];
    const float* Wx2   = (const float*)d_in[7];
    const float* bx2   = (const float*)d_in[8];
    const float* embed = (const float*)d_in[9];
    const float* W1    = (const float*)d_in[10];
    const float* b1    = (const float*)d_in[11];
    const float* W2    = (const float*)d_in[12];
    const float* b2    = (const float*)d_in[13];
    float* out = (float*)d_out;

    char* ws = (char*)d_ws;
    size_t off = 0;
    auto carve = [&](size_t bytes) -> void* {
        void* p = ws + off;
        off += (bytes + 255) & ~(size_t)255;
        return p;
    };
    _Float16* Hs   = (_Float16*)carve((size_t)BN * CH * 2);   // 16.8 MB
    _Float16* Hl   = (_Float16*)carve((size_t)BN * CH * 2);   // 16.8 MB
    float* Hx    = (float*)carve((size_t)BN * CH * 4);        // 33.5 MB
    float* Wf2T  = (float*)carve((size_t)ED * CH * 4);        // 12.8 MB
    float* EX    = (float*)carve((size_t)BN * DIN * 4);       // 4.2 MB
    _Float16* WeTs = (_Float16*)carve((size_t)KN * CH * 2);   // 0.5 MB
    _Float16* WeTl = (_Float16*)carve((size_t)KN * CH * 2);   // 0.5 MB
    _Float16* Ghi  = (_Float16*)carve((size_t)KN * KN * 2);   // 0.5 MB
    char*  zbase = ws + off;                                  // ---- zero region ----
    float* We    = (float*)carve((size_t)KN * KN * 4);        // 1 MB
    float* G     = (float*)carve((size_t)KN * KN * 4);        // 1 MB
    float* s2    = (float*)carve(KN * 4);
    float* be    = (float*)carve(KN * 4);
    float* w0    = (float*)carve(CH * 4);
    float* colsum= (float*)carve(CH * 4);
    int*   counts= (int*)carve(KN * 4);
    int*   cursors=(int*)carve(KN * 4);
    float* diffsum=(float*)carve(256);
    float* bbuf  = (float*)carve(256);
    size_t zbytes = (size_t)(ws + off - zbase);               // ---- end zero region ----
    int*   ind     = (int*)carve(BN * 4);
    int*   offsets = (int*)carve(KN * 4);
    int*   perm    = (int*)carve(BN * 4);
    (void)in_sizes; (void)n_in; (void)out_size; (void)ws_size;

    hipMemsetAsync(zbase, 0, zbytes, stream);
    transpose_kernel<<<dim3(ED / 32, CH / 32), 256, 0, stream>>>(Wf2, Wf2T);
    psmall_kernel<<<dim3(32, 3), 256, 0, stream>>>(embed, bf2, Wf2T, s2, be, w0, bbuf);
    pgemm_kernel<<<dim3(4, 16, 8), 256, 0, stream>>>(Wf2, embed, We, 25, ED);
    pgemm_kernel<<<dim3(4, 16, 8), 256, 0, stream>>>(Wf2, Wf2T, G, 25, ED);
    wesplit_kernel<<<dim3(16, 16), 256, 0, stream>>>(We, WeTs, WeTl);
    gconv_kernel<<<KN * KN / 1024, 256, 0, stream>>>(G, Ghi);
    enc1_kernel<<<BN / 16, 256, 0, stream>>>(x, Wf1, bf1, Wx1, bx1, Hs, Hl, Hx, colsum);
    score_mfma_kernel<<<BN / 32, 256, 0, stream>>>(Hs, Hl, WeTs, WeTl, Ghi, s2, be,
                                                   ind, counts, diffsum, out + OUT_IND);
    ex_kernel<<<BN / 32, 256, 0, stream>>>(Hx, Wx2, bx2, EX);
    finalize_kernel<<<1, 512, 0, stream>>>(counts, offsets, diffsum, colsum, w0, bbuf,
                                           out + OUT_DIFF, out + OUT_PERP);
    scatter_kernel<<<BN / 256, 256, 0, stream>>>(ind, offsets, cursors, perm);
    decode_kernel<<<BN / 4, 256, 0, stream>>>(EX, perm, ind, W1, b1, W2, b2,
                                              out + OUT_DEC);
}

// Round 4
// 598.977 us; speedup vs baseline: 3.4584x; 1.0206x over previous
//
#include <hip/hip_runtime.h>
#include <math.h>

// Problem constants
#define BN     16384
#define INC    128
#define CH     512
#define ED     6240
#define KN     512      // NUM_EMB
#define DIN    64
#define DH     64
#define DY     32
#define NCW    195      // ED/32 k-chunks for Wf2/embed packing

// d_out layout (float32): dec[16384*32] | diff[1] | embed_ind[16384] | perplexity[1]
#define OUT_DEC   0
#define OUT_DIFF  (BN*DY)
#define OUT_IND   (BN*DY + 1)
#define OUT_PERP  (BN*DY + 1 + BN)

typedef _Float16 half8 __attribute__((ext_vector_type(8)));
typedef float    f32x4 __attribute__((ext_vector_type(4)));
#define MFMA16(a, b, c) __builtin_amdgcn_mfma_f32_16x16x32_f16(a, b, c, 0, 0, 0)

// Packed fragment-tile layout: element (row r within 16-row tile `tile`,
// k-dim index d) lives at ((tile*NC + d/32)*64 + ((d%32)/8)*16 + (r%16))*8 + d%8.
// One wave-load of half8 at lane L = contiguous 1KB = one full MFMA fragment.
__device__ __forceinline__ size_t paddr(int tile, int NC, int c, int lane, int e) {
    return ((size_t)(tile * NC + c) * 64 + lane) * 8 + e;
}

// ---------------------------------------------------------------------------
// Split Wf2 [512][6240] fp32 -> packed fp16 hi/lo (frag layout, NC=195)
// ---------------------------------------------------------------------------
__global__ __launch_bounds__(256) void splitwf2_kernel(const float* __restrict__ Wf2,
                                                       _Float16* __restrict__ WfPs,
                                                       _Float16* __restrict__ WfPl) {
    int t = threadIdx.x;
    int d = blockIdx.x * 32 + (t & 31);
    int j = blockIdx.y * 8 + (t >> 5);
    float v = Wf2[(size_t)j * ED + d];
    _Float16 hi = (_Float16)v;
    size_t a = paddr(j >> 4, NCW, d >> 5, ((d & 31) >> 3) * 16 + (j & 15), d & 7);
    WfPs[a] = hi;
    WfPl[a] = (_Float16)(v - (float)hi);
}

// ---------------------------------------------------------------------------
// Transpose+split embed [6240][512] -> packed fp16 hi/lo (rows=codewords, NC=195)
// ---------------------------------------------------------------------------
__global__ __launch_bounds__(256) void embt_kernel(const float* __restrict__ embed,
                                                   _Float16* __restrict__ EmPs,
                                                   _Float16* __restrict__ EmPl) {
    __shared__ float tile[32][33];
    int t = threadIdx.x;
    int dl = t >> 5, kl = t & 31;
    #pragma unroll
    for (int r = 0; r < 4; ++r)
        tile[dl + 8 * r][kl] = embed[(size_t)(blockIdx.x * 32 + dl + 8 * r) * KN
                                     + blockIdx.y * 32 + kl];
    __syncthreads();
    int d = blockIdx.x * 32 + kl;
    #pragma unroll
    for (int r = 0; r < 4; ++r) {
        int k = blockIdx.y * 32 + dl + 8 * r;
        float v = tile[kl][dl + 8 * r];
        _Float16 hi = (_Float16)v;
        size_t a = paddr(k >> 4, NCW, d >> 5, ((d & 31) >> 3) * 16 + (k & 15), d & 7);
        EmPs[a] = hi;
        EmPl[a] = (_Float16)(v - (float)hi);
    }
}

// ---------------------------------------------------------------------------
// Small precomputes: s2[k]=||e_k||^2, be[k]=bf2.e_k, w0[j]=Wf2[j,:].bf2, bb=||bf2||^2
// ---------------------------------------------------------------------------
__global__ __launch_bounds__(256) void psmall_kernel(const float* __restrict__ embed,
                                                     const float* __restrict__ bf2,
                                                     const float* __restrict__ Wf2,
                                                     float* __restrict__ s2,
                                                     float* __restrict__ be,
                                                     float* __restrict__ w0,
                                                     float* __restrict__ bbuf) {
    __shared__ float sf[256];
    int task = blockIdx.y;
    int t = threadIdx.x;
    if (task == 0) {
        int khalf = blockIdx.x & 1, chunk = blockIdx.x >> 1;   // 16 chunks of 390
        int k = khalf * 256 + t;
        float s = 0.f, b = 0.f;
        int d0 = chunk * 390, d1 = d0 + 390;
        for (int d = d0; d < d1; ++d) {
            float e = embed[(size_t)d * KN + k];
            s = fmaf(e, e, s);
            b = fmaf(bf2[d], e, b);
        }
        atomicAdd(&s2[k], s);
        atomicAdd(&be[k], b);
    } else if (task == 1) {
        int w = t >> 6, lane = t & 63;
        #pragma unroll
        for (int jj = 0; jj < 4; ++jj) {
            int j = blockIdx.x * 16 + w * 4 + jj;
            float s = 0.f;
            for (int d = lane; d < ED; d += 64)
                s = fmaf(Wf2[(size_t)j * ED + d], bf2[d], s);
            #pragma unroll
            for (int dd = 1; dd < 64; dd <<= 1) s += __shfl_xor(s, dd);
            if (lane == 0) w0[j] = s;
        }
    } else {
        if (blockIdx.x > 0) return;
        float s = 0.f;
        for (int d = t; d < ED; d += 256) { float v = bf2[d]; s = fmaf(v, v, s); }
        sf[t] = s; __syncthreads();
        for (int r = 128; r > 0; r >>= 1) { if (t < r) sf[t] += sf[t + r]; __syncthreads(); }
        if (t == 0) bbuf[0] = sf[0];
    }
}

// ---------------------------------------------------------------------------
// 3-pass split-fp16 MFMA GEMM: C[512x512] += A'B' (fp32-equivalent).
// A,B packed frag layout, NC chunks. grid (16, 2, 16), block 256.
// Wave = 32 rows x 64 cols. K-split over blockIdx.z, fp32 atomics into C.
// ---------------------------------------------------------------------------
__global__ __launch_bounds__(256) void mfma3_kernel(const _Float16* __restrict__ As,
                                                    const _Float16* __restrict__ Al,
                                                    const _Float16* __restrict__ Bs,
                                                    const _Float16* __restrict__ Bl,
                                                    float* __restrict__ C, int NC) {
    int t = threadIdx.x;
    int w = t >> 6, L = t & 63;
    int lane16 = L & 15, quad = L >> 4;
    int m0 = blockIdx.x * 32;
    int n0 = blockIdx.y * 256 + w * 64;
    int ta = m0 >> 4, tb = n0 >> 4;
    int z = blockIdx.z;
    int base = NC / 16, rem = NC % 16;
    int c0 = z * base + (z < rem ? z : rem);
    int cnt = base + (z < rem ? 1 : 0);
    f32x4 acc[2][4];
    #pragma unroll
    for (int rt = 0; rt < 2; ++rt)
        #pragma unroll
        for (int tt = 0; tt < 4; ++tt) acc[rt][tt] = (f32x4){0.f, 0.f, 0.f, 0.f};
    for (int ci = 0; ci < cnt; ++ci) {
        int c = c0 + ci;
        size_t oa0 = paddr(ta, NC, c, L, 0), oa1 = paddr(ta + 1, NC, c, L, 0);
        half8 A0h = *(const half8*)(As + oa0);
        half8 A0l = *(const half8*)(Al + oa0);
        half8 A1h = *(const half8*)(As + oa1);
        half8 A1l = *(const half8*)(Al + oa1);
        #pragma unroll
        for (int tt = 0; tt < 4; ++tt) {
            size_t ob = paddr(tb + tt, NC, c, L, 0);
            half8 Bh = *(const half8*)(Bs + ob);
            half8 Bl8 = *(const half8*)(Bl + ob);
            acc[0][tt] = MFMA16(A0h, Bl8, MFMA16(A0l, Bh, MFMA16(A0h, Bh, acc[0][tt])));
            acc[1][tt] = MFMA16(A1h, Bl8, MFMA16(A1l, Bh, MFMA16(A1h, Bh, acc[1][tt])));
        }
    }
    #pragma unroll
    for (int rt = 0; rt < 2; ++rt)
        #pragma unroll
        for (int tt = 0; tt < 4; ++tt)
            #pragma unroll
            for (int r = 0; r < 4; ++r)
                atomicAdd(&C[(size_t)(m0 + rt * 16 + quad * 4 + r) * KN
                             + n0 + tt * 16 + lane16], acc[rt][tt][r]);
}

// 1-pass variant (for G = Wf2.Wf2^T and HtH = H^T.H; loose precision OK)
__global__ __launch_bounds__(256) void mfma1_kernel(const _Float16* __restrict__ As,
                                                    const _Float16* __restrict__ Bs,
                                                    float* __restrict__ C, int NC) {
    int t = threadIdx.x;
    int w = t >> 6, L = t & 63;
    int lane16 = L & 15, quad = L >> 4;
    int m0 = blockIdx.x * 32;
    int n0 = blockIdx.y * 256 + w * 64;
    int ta = m0 >> 4, tb = n0 >> 4;
    int z = blockIdx.z;
    int base = NC / 16, rem = NC % 16;
    int c0 = z * base + (z < rem ? z : rem);
    int cnt = base + (z < rem ? 1 : 0);
    f32x4 acc[2][4];
    #pragma unroll
    for (int rt = 0; rt < 2; ++rt)
        #pragma unroll
        for (int tt = 0; tt < 4; ++tt) acc[rt][tt] = (f32x4){0.f, 0.f, 0.f, 0.f};
    for (int ci = 0; ci < cnt; ++ci) {
        int c = c0 + ci;
        half8 A0h = *(const half8*)(As + paddr(ta, NC, c, L, 0));
        half8 A1h = *(const half8*)(As + paddr(ta + 1, NC, c, L, 0));
        #pragma unroll
        for (int tt = 0; tt < 4; ++tt) {
            half8 Bh = *(const half8*)(Bs + paddr(tb + tt, NC, c, L, 0));
            acc[0][tt] = MFMA16(A0h, Bh, acc[0][tt]);
            acc[1][tt] = MFMA16(A1h, Bh, acc[1][tt]);
        }
    }
    #pragma unroll
    for (int rt = 0; rt < 2; ++rt)
        #pragma unroll
        for (int tt = 0; tt < 4; ++tt)
            #pragma unroll
            for (int r = 0; r < 4; ++r)
                atomicAdd(&C[(size_t)(m0 + rt * 16 + quad * 4 + r) * KN
                             + n0 + tt * 16 + lane16], acc[rt][tt][r]);
}

// ---------------------------------------------------------------------------
// We fp32 [CH j][KN k] -> packed hi/lo fragments (B side: rows=codewords, NC=16)
// ---------------------------------------------------------------------------
__global__ __launch_bounds__(256) void wesplit_kernel(const float* __restrict__ We,
                                                      _Float16* __restrict__ WePs,
                                                      _Float16* __restrict__ WePl) {
    int gid = blockIdx.x * 256 + threadIdx.x;
    int j = gid >> 9, k = gid & 511;
    float v = We[gid];
    _Float16 hi = (_Float16)v;
    size_t a = paddr(k >> 4, 16, j >> 5, ((j & 31) >> 3) * 16 + (k & 15), j & 7);
    WePs[a] = hi;
    WePl[a] = (_Float16)(v - (float)hi);
}

// ---------------------------------------------------------------------------
// Fused encoder layer-1 (+EX): h = relu(x@Wf1+bf1) -> Hs/Hl (row-major) and
// HTP (packed, hi only, for HtH); hx = relu(x@Wx1+bx1) staged in LDS ->
// EX = hx@Wx2+bx2 directly. colsum[c] = sum_b h[b][c].
// ---------------------------------------------------------------------------
__global__ __launch_bounds__(256) void enc1_kernel(const float* __restrict__ x,
                                                   const float* __restrict__ Wf1,
                                                   const float* __restrict__ bf1,
                                                   const float* __restrict__ Wx1,
                                                   const float* __restrict__ bx1,
                                                   const float* __restrict__ Wx2,
                                                   const float* __restrict__ bx2,
                                                   _Float16* __restrict__ Hs,
                                                   _Float16* __restrict__ Hl,
                                                   _Float16* __restrict__ HTP,
                                                   float* __restrict__ colsum,
                                                   float* __restrict__ EX) {
    __shared__ float xs[16][INC];     // 8 KB
    __shared__ float hxs[16][CH];     // 32 KB
    int bbase = blockIdx.x * 16;
    int t = threadIdx.x;
    for (int i = t; i < 16 * (INC / 4); i += 256) {
        int m = i >> 5, c4 = i & 31;
        ((float4*)xs[m])[c4] = ((const float4*)(x + (size_t)(bbase + m) * INC))[c4];
    }
    __syncthreads();
    float acc[16][4] = {};
    for (int j = 0; j < INC; j += 4) {
        float wv[4][4];
        #pragma unroll
        for (int dj = 0; dj < 4; ++dj) {
            wv[dj][0] = Wf1[(size_t)(j + dj) * CH + t];
            wv[dj][1] = Wf1[(size_t)(j + dj) * CH + t + 256];
            wv[dj][2] = Wx1[(size_t)(j + dj) * CH + t];
            wv[dj][3] = Wx1[(size_t)(j + dj) * CH + t + 256];
        }
        #pragma unroll
        for (int m = 0; m < 16; ++m) {
            float4 hv = *(const float4*)&xs[m][j];
            float xv;
            xv = hv.x;
            acc[m][0] = fmaf(xv, wv[0][0], acc[m][0]); acc[m][1] = fmaf(xv, wv[0][1], acc[m][1]);
            acc[m][2] = fmaf(xv, wv[0][2], acc[m][2]); acc[m][3] = fmaf(xv, wv[0][3], acc[m][3]);
            xv = hv.y;
            acc[m][0] = fmaf(xv, wv[1][0], acc[m][0]); acc[m][1] = fmaf(xv, wv[1][1], acc[m][1]);
            acc[m][2] = fmaf(xv, wv[1][2], acc[m][2]); acc[m][3] = fmaf(xv, wv[1][3], acc[m][3]);
            xv = hv.z;
            acc[m][0] = fmaf(xv, wv[2][0], acc[m][0]); acc[m][1] = fmaf(xv, wv[2][1], acc[m][1]);
            acc[m][2] = fmaf(xv, wv[2][2], acc[m][2]); acc[m][3] = fmaf(xv, wv[2][3], acc[m][3]);
            xv = hv.w;
            acc[m][0] = fmaf(xv, wv[3][0], acc[m][0]); acc[m][1] = fmaf(xv, wv[3][1], acc[m][1]);
            acc[m][2] = fmaf(xv, wv[3][2], acc[m][2]); acc[m][3] = fmaf(xv, wv[3][3], acc[m][3]);
        }
    }
    float bf0 = bf1[t], bf1v = bf1[t + 256], bx0 = bx1[t], bx1v = bx1[t + 256];
    float cs0 = 0.f, cs1 = 0.f;
    int tm0 = t >> 4, tm1 = (t + 256) >> 4, l16 = t & 15;
    #pragma unroll
    for (int m = 0; m < 16; ++m) {
        float v0 = fmaxf(acc[m][0] + bf0, 0.f);
        float v1 = fmaxf(acc[m][1] + bf1v, 0.f);
        float v2 = fmaxf(acc[m][2] + bx0, 0.f);
        float v3 = fmaxf(acc[m][3] + bx1v, 0.f);
        int b = bbase + m;
        size_t row = (size_t)b * CH;
        _Float16 h0 = (_Float16)v0;
        _Float16 h1 = (_Float16)v1;
        Hs[row + t] = h0;        Hl[row + t] = (_Float16)(v0 - (float)h0);
        Hs[row + t + 256] = h1;  Hl[row + t + 256] = (_Float16)(v1 - (float)h1);
        int cb = b >> 5, qb = (b & 31) >> 3, eb = b & 7;
        HTP[paddr(tm0, 512, cb, qb * 16 + l16, eb)] = h0;
        HTP[paddr(tm1, 512, cb, qb * 16 + l16, eb)] = h1;
        hxs[m][t] = v2; hxs[m][t + 256] = v3;
        cs0 += v0; cs1 += v1;
    }
    atomicAdd(&colsum[t], cs0);
    atomicAdd(&colsum[t + 256], cs1);
    __syncthreads();
    // EX = hxs @ Wx2 + bx2 : wave w owns samples 4w..4w+4; lane = out col.
    int w = t >> 6, c = t & 63;
    float acce[4] = {0.f, 0.f, 0.f, 0.f};
    for (int j = 0; j < CH; ++j) {
        float wv = Wx2[(size_t)j * DIN + c];
        #pragma unroll
        for (int i = 0; i < 4; ++i)
            acce[i] = fmaf(hxs[w * 4 + i][j], wv, acce[i]);
    }
    float bias = bx2[c];
    #pragma unroll
    for (int i = 0; i < 4; ++i)
        EX[(size_t)(bbase + w * 4 + i) * DIN + c] = acce[i] + bias;
}

// ---------------------------------------------------------------------------
// Score/argmin kernel: g_k = 0.5*s2[k]-be[k]-h.We[:,k]; per-row argmin via
// order-encoded u64 atomicMin (tie -> lowest k, matches np.argmin).
// grid (BN/32, 2); wave = 32 rows x 64 cols; B from packed global (L2).
// ---------------------------------------------------------------------------
__global__ __launch_bounds__(256) void score_kernel(
        const _Float16* __restrict__ Hs, const _Float16* __restrict__ Hl,
        const _Float16* __restrict__ WePs, const _Float16* __restrict__ WePl,
        const float* __restrict__ s2, const float* __restrict__ be,
        unsigned long long* __restrict__ rowkey) {
    int t = threadIdx.x;
    int w = t >> 6, L = t & 63;
    int lane16 = L & 15, quad = L >> 4;
    int m0 = blockIdx.x * 32;
    int colbase = blockIdx.y * 256 + w * 64;
    int tb = colbase >> 4;
    const _Float16* a0s = Hs + (size_t)(m0 + lane16) * CH + quad * 8;
    const _Float16* a0l = Hl + (size_t)(m0 + lane16) * CH + quad * 8;
    const _Float16* a1s = a0s + (size_t)16 * CH;
    const _Float16* a1l = a0l + (size_t)16 * CH;
    float cks[4];
    #pragma unroll
    for (int tt = 0; tt < 4; ++tt) {
        int c = colbase + tt * 16 + lane16;
        cks[tt] = 0.5f * s2[c] - be[c];
    }
    f32x4 acc[2][4];
    #pragma unroll
    for (int rt = 0; rt < 2; ++rt)
        #pragma unroll
        for (int tt = 0; tt < 4; ++tt) acc[rt][tt] = (f32x4){0.f, 0.f, 0.f, 0.f};
    #pragma unroll
    for (int c = 0; c < 16; ++c) {
        int ko = c * 32;
        half8 A0h = *(const half8*)(a0s + ko);
        half8 A0l = *(const half8*)(a0l + ko);
        half8 A1h = *(const half8*)(a1s + ko);
        half8 A1l = *(const half8*)(a1l + ko);
        #pragma unroll
        for (int tt = 0; tt < 4; ++tt) {
            size_t ob = paddr(tb + tt, 16, c, L, 0);
            half8 Bh = *(const half8*)(WePs + ob);
            half8 Bl8 = *(const half8*)(WePl + ob);
            acc[0][tt] = MFMA16(A0h, Bl8, MFMA16(A0l, Bh, MFMA16(A0h, Bh, acc[0][tt])));
            acc[1][tt] = MFMA16(A1h, Bl8, MFMA16(A1l, Bh, MFMA16(A1h, Bh, acc[1][tt])));
        }
    }
    #pragma unroll
    for (int rt = 0; rt < 2; ++rt) {
        #pragma unroll
        for (int r = 0; r < 4; ++r) {
            float mv = cks[0] - acc[rt][0][r];
            int mi = colbase + lane16;
            #pragma unroll
            for (int tt = 1; tt < 4; ++tt) {
                float v = cks[tt] - acc[rt][tt][r];
                int c = colbase + tt * 16 + lane16;
                if (v < mv || (v == mv && c < mi)) { mv = v; mi = c; }
            }
            #pragma unroll
            for (int d = 1; d < 16; d <<= 1) {
                float ov = __shfl_xor(mv, d);
                int oi = __shfl_xor(mi, d);
                if (ov < mv || (ov == mv && oi < mi)) { mv = ov; mi = oi; }
            }
            if (lane16 == 0) {
                unsigned u = __float_as_uint(mv);
                unsigned ou = (u & 0x80000000u) ? ~u : (u | 0x80000000u);
                unsigned long long key = ((unsigned long long)ou << 32) | (unsigned)mi;
                atomicMin(&rowkey[m0 + rt * 16 + quad * 4 + r], key);
            }
        }
    }
}

// ---------------------------------------------------------------------------
// Postscore: decode rowkeys -> ind/out_ind/counts; accumulate sum(2*g_min).
// ---------------------------------------------------------------------------
__global__ __launch_bounds__(256) void postscore_kernel(
        const unsigned long long* __restrict__ rowkey,
        int* __restrict__ ind, float* __restrict__ out_ind,
        int* __restrict__ counts, float* __restrict__ diffsum) {
    __shared__ float sf[256];
    int t = threadIdx.x;
    int b = blockIdx.x * 256 + t;
    unsigned long long key = rowkey[b];
    int k = (int)(key & 0xFFFFFFFFull);
    unsigned ou = (unsigned)(key >> 32);
    unsigned u = (ou & 0x80000000u) ? (ou & 0x7FFFFFFFu) : ~ou;
    float gmin = __uint_as_float(u);
    ind[b] = k;
    out_ind[b] = (float)k;
    atomicAdd(&counts[k], 1);
    sf[t] = 2.f * gmin;
    __syncthreads();
    for (int s = 128; s > 0; s >>= 1) { if (t < s) sf[t] += sf[t + s]; __syncthreads(); }
    if (t == 0) atomicAdd(diffsum, sf[0]);
}

// ---------------------------------------------------------------------------
// diffsum += sum(HtH o G)   (= sum_b h^T G h)
// ---------------------------------------------------------------------------
__global__ __launch_bounds__(256) void diffdot_kernel(const float* __restrict__ HtH,
                                                      const float* __restrict__ G,
                                                      float* __restrict__ diffsum) {
    __shared__ float sf[256];
    int t = threadIdx.x;
    int i = (blockIdx.x * 256 + t) * 4;
    float4 a = *(const float4*)&HtH[i];
    float4 g = *(const float4*)&G[i];
    sf[t] = a.x * g.x + a.y * g.y + a.z * g.z + a.w * g.w;
    __syncthreads();
    for (int s = 128; s > 0; s >>= 1) { if (t < s) sf[t] += sf[t + s]; __syncthreads(); }
    if (t == 0) atomicAdd(diffsum, sf[0]);
}

// ---------------------------------------------------------------------------
// Finalize: offsets = exclusive scan(counts); perplexity; diff.
// ---------------------------------------------------------------------------
__global__ __launch_bounds__(512) void finalize_kernel(const int* __restrict__ counts,
                                                       int* __restrict__ offsets,
                                                       const float* __restrict__ diffsum,
                                                       const float* __restrict__ colsum,
                                                       const float* __restrict__ w0,
                                                       const float* __restrict__ bbuf,
                                                       float* __restrict__ out_diff,
                                                       float* __restrict__ out_perp) {
    __shared__ int   sc[512];
    __shared__ float sf[512];
    int t = threadIdx.x;
    int c = counts[t];
    sc[t] = c;
    double p = (double)c / (double)BN;
    double term = -p * log(p + 1e-10);
    float dotp = colsum[t] * w0[t];
    __syncthreads();
    int off = 0;
    for (int k = 0; k < t; ++k) off += sc[k];
    offsets[t] = off;
    sf[t] = dotp; __syncthreads();
    for (int s = 256; s > 0; s >>= 1) { if (t < s) sf[t] += sf[t + s]; __syncthreads(); }
    float dot_all = sf[0];
    __syncthreads();
    sf[t] = (float)term; __syncthreads();
    for (int s = 256; s > 0; s >>= 1) { if (t < s) sf[t] += sf[t + s]; __syncthreads(); }
    if (t == 0) {
        *out_perp = expf(sf[0]);
        *out_diff = (diffsum[0] + 2.f * dot_all + (float)BN * bbuf[0]) /
                    ((float)BN * (float)ED);
    }
}

// ---------------------------------------------------------------------------
// Scatter: perm[] groups sample ids by expert. cursors pre-zeroed.
// ---------------------------------------------------------------------------
__global__ __launch_bounds__(256) void scatter_kernel(const int* __restrict__ ind,
                                                      const int* __restrict__ offsets,
                                                      int* __restrict__ cursors,
                                                      int* __restrict__ perm) {
    int b = blockIdx.x * 256 + threadIdx.x;
    int k = ind[b];
    int pos = offsets[k] + atomicAdd(&cursors[k], 1);
    perm[pos] = b;
}

// ---------------------------------------------------------------------------
// Decoder: one wave per sample (load-balanced under histogram skew).
// ---------------------------------------------------------------------------
__global__ __launch_bounds__(256) void decode_kernel(const float* __restrict__ EX,
                                                     const int* __restrict__ perm,
                                                     const int* __restrict__ ind,
                                                     const float* __restrict__ W1,
                                                     const float* __restrict__ b1,
                                                     const float* __restrict__ W2,
                                                     const float* __restrict__ b2,
                                                     float* __restrict__ dec) {
    __shared__ float exs[4][DIN];
    __shared__ float h2s[4][DH];
    int t = threadIdx.x;
    int w = t >> 6, l = t & 63;
    int s = blockIdx.x * 4 + w;
    int b = perm[s];
    int k = ind[b];
    exs[w][l] = EX[(size_t)b * DIN + l];
    __syncthreads();
    const float* w1 = W1 + (size_t)k * (DIN * DH);
    float h = b1[(size_t)k * DH + l];
    #pragma unroll
    for (int j = 0; j < DIN; ++j)
        h = fmaf(exs[w][j], w1[(size_t)j * DH + l], h);
    h2s[w][l] = fmaxf(h, 0.f);
    __syncthreads();
    if (l < DY) {
        const float* w2 = W2 + (size_t)k * (DH * DY);
        float d = b2[(size_t)k * DY + l];
        #pragma unroll
        for (int j = 0; j < DH; ++j)
            d = fmaf(h2s[w][j], w2[(size_t)j * DY + l], d);
        dec[(size_t)b * DY + l] = d;
    }
}

// ---------------------------------------------------------------------------
extern "C" void kernel_launch(void* const* d_in, const int* in_sizes, int n_in,
                              void* d_out, int out_size, void* d_ws, size_t ws_size,
                              hipStream_t stream) {
    const float* x     = (const float*)d_in[0];
    const float* Wf1   = (const float*)d_in[1];
    const float* bf1   = (const float*)d_in[2];
    const float* Wf2   = (const float*)d_in[3];
    const float* bf2   = (const float*)d_in[4];
    const float* Wx1   = (const float*)d_in[5];
    const float* bx1   = (const float*)d_in[6];
    const float* Wx2   = (const float*)d_in[7];
    const float* bx2   = (const float*)d_in[8];
    const float* embed = (const float*)d_in[9];
    const float* W1    = (const float*)d_in[10];
    const float* b1    = (const float*)d_in[11];
    const float* W2    = (const float*)d_in[12];
    const float* b2    = (const float*)d_in[13];
    float* out = (float*)d_out;

    char* ws = (char*)d_ws;
    size_t off = 0;
    auto carve = [&](size_t bytes) -> void* {
        void* p = ws + off;
        off += (bytes + 255) & ~(size_t)255;
        return p;
    };
    _Float16* WfPs = (_Float16*)carve((size_t)CH * ED * 2);   // 6.4 MB
    _Float16* WfPl = (_Float16*)carve((size_t)CH * ED * 2);
    _Float16* EmPs = (_Float16*)carve((size_t)KN * ED * 2);
    _Float16* EmPl = (_Float16*)carve((size_t)KN * ED * 2);
    _Float16* Hs   = (_Float16*)carve((size_t)BN * CH * 2);   // 16.8 MB
    _Float16* Hl   = (_Float16*)carve((size_t)BN * CH * 2);
    _Float16* HTP  = (_Float16*)carve((size_t)CH * BN * 2);   // 16.8 MB
    float* EX      = (float*)carve((size_t)BN * DIN * 4);     // 4.2 MB
    _Float16* WePs = (_Float16*)carve((size_t)KN * CH * 2);
    _Float16* WePl = (_Float16*)carve((size_t)KN * CH * 2);
    char* zbase = ws + off;                                   // ---- zero region ----
    float* We    = (float*)carve((size_t)KN * KN * 4);
    float* G     = (float*)carve((size_t)KN * KN * 4);
    float* HtH   = (float*)carve((size_t)KN * KN * 4);
    float* s2    = (float*)carve(KN * 4);
    float* be    = (float*)carve(KN * 4);
    float* w0    = (float*)carve(CH * 4);
    float* colsum= (float*)carve(CH * 4);
    int*   counts= (int*)carve(KN * 4);
    int*   cursors=(int*)carve(KN * 4);
    float* diffsum=(float*)carve(256);
    float* bbuf  = (float*)carve(256);
    size_t zbytes = (size_t)(ws + off - zbase);               // ---- end zero region ----
    unsigned long long* rowkey = (unsigned long long*)carve(BN * 8);
    int*   ind     = (int*)carve(BN * 4);
    int*   offsets = (int*)carve(KN * 4);
    int*   perm    = (int*)carve(BN * 4);
    (void)in_sizes; (void)n_in; (void)out_size; (void)ws_size;

    hipMemsetAsync(zbase, 0, zbytes, stream);
    hipMemsetAsync(rowkey, 0xFF, (size_t)BN * 8, stream);
    splitwf2_kernel<<<dim3(NCW, 64), 256, 0, stream>>>(Wf2, WfPs, WfPl);
    embt_kernel<<<dim3(NCW, 16), 256, 0, stream>>>(embed, EmPs, EmPl);
    psmall_kernel<<<dim3(32, 3), 256, 0, stream>>>(embed, bf2, Wf2, s2, be, w0, bbuf);
    mfma3_kernel<<<dim3(16, 2, 16), 256, 0, stream>>>(WfPs, WfPl, EmPs, EmPl, We, NCW);
    mfma1_kernel<<<dim3(16, 2, 16), 256, 0, stream>>>(WfPs, WfPs, G, NCW);
    wesplit_kernel<<<KN * KN / 256, 256, 0, stream>>>(We, WePs, WePl);
    enc1_kernel<<<BN / 16, 256, 0, stream>>>(x, Wf1, bf1, Wx1, bx1, Wx2, bx2,
                                             Hs, Hl, HTP, colsum, EX);
    score_kernel<<<dim3(BN / 32, 2), 256, 0, stream>>>(Hs, Hl, WePs, WePl, s2, be,
                                                       rowkey);
    mfma1_kernel<<<dim3(16, 2, 16), 256, 0, stream>>>(HTP, HTP, HtH, BN / 32);
    postscore_kernel<<<BN / 256, 256, 0, stream>>>(rowkey, ind, out + OUT_IND,
                                                   counts, diffsum);
    diffdot_kernel<<<KN * KN / 1024, 256, 0, stream>>>(HtH, G, diffsum);
    finalize_kernel<<<1, 512, 0, stream>>>(counts, offsets, diffsum, colsum, w0, bbuf,
                                           out + OUT_DIFF, out + OUT_PERP);
    scatter_kernel<<<BN / 256, 256, 0, stream>>>(ind, offsets, cursors, perm);
    decode_kernel<<<BN / 4, 256, 0, stream>>>(EX, perm, ind, W1, b1, W2, b2,
                                              out + OUT_DEC);
}

// Round 5
// 487.650 us; speedup vs baseline: 4.2479x; 1.2283x over previous
//
#include <hip/hip_runtime.h>
#include <math.h>

// Problem constants
#define BN     16384
#define INC    128
#define CH     512
#define ED     6240
#define KN     512      // NUM_EMB
#define DIN    64
#define DH     64
#define DY     32
#define NCW    195      // ED/32 k-chunks for Wf2/embed packing

// d_out layout (float32): dec[16384*32] | diff[1] | embed_ind[16384] | perplexity[1]
#define OUT_DEC   0
#define OUT_DIFF  (BN*DY)
#define OUT_IND   (BN*DY + 1)
#define OUT_PERP  (BN*DY + 1 + BN)

typedef _Float16 half8 __attribute__((ext_vector_type(8)));
typedef float    f32x4 __attribute__((ext_vector_type(4)));
#define MFMA16(a, b, c) __builtin_amdgcn_mfma_f32_16x16x32_f16(a, b, c, 0, 0, 0)

// Packed fragment-tile layout: element (row r within 16-row tile `tile`,
// k-dim index d) lives at ((tile*NC + d/32)*64 + ((d%32)/8)*16 + (r%16))*8 + d%8.
// One wave-load of half8 at lane L = contiguous 1KB = one full MFMA fragment.
__device__ __forceinline__ size_t paddr(int tile, int NC, int c, int lane, int e) {
    return ((size_t)(tile * NC + c) * 64 + lane) * 8 + e;
}

// ---------------------------------------------------------------------------
// Pack x [BN][128] fp32 -> XPs/XPl packed hi/lo (A-side, NC=4)
// ---------------------------------------------------------------------------
__global__ __launch_bounds__(256) void xpack_kernel(const float* __restrict__ x,
                                                    _Float16* __restrict__ XPs,
                                                    _Float16* __restrict__ XPl) {
    __shared__ float xt[32][INC];
    int t = threadIdx.x;
    int m0 = blockIdx.x * 32;
    for (int i = t; i < 32 * (INC / 4); i += 256) {
        int row = i >> 5, c4 = (i & 31) << 2;
        *(float4*)&xt[row][c4] = *(const float4*)&x[(size_t)(m0 + row) * INC + c4];
    }
    __syncthreads();
    int ta = m0 >> 4;
    #pragma unroll
    for (int i = 0; i < 2; ++i) {
        int idx = t + 256 * i;              // 0..511
        int tile2 = idx >> 8;               // 0..1
        int c = (idx >> 6) & 3;
        int lane = idx & 63;
        int m = tile2 * 16 + (lane & 15);
        int d0 = c * 32 + ((lane >> 4) << 3);
        half8 hh, ll;
        #pragma unroll
        for (int e = 0; e < 8; ++e) {
            float v = xt[m][d0 + e];
            _Float16 hi = (_Float16)v;
            hh[e] = hi;
            ll[e] = (_Float16)(v - (float)hi);
        }
        *(half8*)(XPs + paddr(ta + tile2, 4, c, lane, 0)) = hh;
        *(half8*)(XPl + paddr(ta + tile2, 4, c, lane, 0)) = ll;
    }
}

// ---------------------------------------------------------------------------
// Pack fused Wf1|Wx1 cols (n<512 -> Wf1 col n; else Wx1 col n-512) to B-side
// frag layout (NC=4). Also bfx = concat(bf1, bx1).
// ---------------------------------------------------------------------------
__global__ __launch_bounds__(256) void wfxpack_kernel(const float* __restrict__ Wf1,
                                                      const float* __restrict__ Wx1,
                                                      const float* __restrict__ bf1,
                                                      const float* __restrict__ bx1,
                                                      _Float16* __restrict__ WfxPs,
                                                      _Float16* __restrict__ WfxPl,
                                                      float* __restrict__ bfx) {
    int t = threadIdx.x;
    int tile = blockIdx.x;                  // 0..63
    for (int i = t; i < 2048; i += 256) {
        int c = i >> 9, lane = (i >> 3) & 63, e = i & 7;
        int n = tile * 16 + (lane & 15);
        int d = c * 32 + ((lane >> 4) << 3) + e;
        float v = (n < 512) ? Wf1[(size_t)d * CH + n] : Wx1[(size_t)d * CH + n - 512];
        _Float16 hi = (_Float16)v;
        size_t a = paddr(tile, 4, c, lane, e);
        WfxPs[a] = hi;
        WfxPl[a] = (_Float16)(v - (float)hi);
    }
    if (blockIdx.x == 0)
        for (int j = t; j < 512; j += 256) { bfx[j] = bf1[j]; bfx[512 + j] = bx1[j]; }
}

// ---------------------------------------------------------------------------
// Pack Wx2 [512][64] -> B-side frag layout (4 tiles, NC=16), hi/lo
// ---------------------------------------------------------------------------
__global__ __launch_bounds__(256) void wx2pack_kernel(const float* __restrict__ Wx2,
                                                      _Float16* __restrict__ Ps,
                                                      _Float16* __restrict__ Pl) {
    int t = threadIdx.x;
    int tile = blockIdx.x;                  // 0..3
    for (int i = t; i < 8192; i += 256) {
        int c = i >> 9, lane = (i >> 3) & 63, e = i & 7;
        int n = tile * 16 + (lane & 15);
        int d = c * 32 + ((lane >> 4) << 3) + e;
        float v = Wx2[(size_t)d * DIN + n];
        _Float16 hi = (_Float16)v;
        size_t a = paddr(tile, 16, c, lane, e);
        Ps[a] = hi;
        Pl[a] = (_Float16)(v - (float)hi);
    }
}

// ---------------------------------------------------------------------------
// Split Wf2 [512][6240] fp32 -> packed fp16 hi/lo (frag layout, NC=195)
// ---------------------------------------------------------------------------
__global__ __launch_bounds__(256) void splitwf2_kernel(const float* __restrict__ Wf2,
                                                       _Float16* __restrict__ WfPs,
                                                       _Float16* __restrict__ WfPl) {
    int t = threadIdx.x;
    int d = blockIdx.x * 32 + (t & 31);
    int j = blockIdx.y * 8 + (t >> 5);
    float v = Wf2[(size_t)j * ED + d];
    _Float16 hi = (_Float16)v;
    size_t a = paddr(j >> 4, NCW, d >> 5, ((d & 31) >> 3) * 16 + (j & 15), d & 7);
    WfPs[a] = hi;
    WfPl[a] = (_Float16)(v - (float)hi);
}

// ---------------------------------------------------------------------------
// Transpose+split embed [6240][512] -> packed fp16 hi/lo (rows=codewords)
// ---------------------------------------------------------------------------
__global__ __launch_bounds__(256) void embt_kernel(const float* __restrict__ embed,
                                                   _Float16* __restrict__ EmPs,
                                                   _Float16* __restrict__ EmPl) {
    __shared__ float tile[32][33];
    int t = threadIdx.x;
    int dl = t >> 5, kl = t & 31;
    #pragma unroll
    for (int r = 0; r < 4; ++r)
        tile[dl + 8 * r][kl] = embed[(size_t)(blockIdx.x * 32 + dl + 8 * r) * KN
                                     + blockIdx.y * 32 + kl];
    __syncthreads();
    int d = blockIdx.x * 32 + kl;
    #pragma unroll
    for (int r = 0; r < 4; ++r) {
        int k = blockIdx.y * 32 + dl + 8 * r;
        float v = tile[kl][dl + 8 * r];
        _Float16 hi = (_Float16)v;
        size_t a = paddr(k >> 4, NCW, d >> 5, ((d & 31) >> 3) * 16 + (k & 15), d & 7);
        EmPs[a] = hi;
        EmPl[a] = (_Float16)(v - (float)hi);
    }
}

// ---------------------------------------------------------------------------
// Small precomputes: s2[k]=||e_k||^2, be[k]=bf2.e_k, w0[j]=Wf2[j,:].bf2, bb=||bf2||^2
// ---------------------------------------------------------------------------
__global__ __launch_bounds__(256) void psmall_kernel(const float* __restrict__ embed,
                                                     const float* __restrict__ bf2,
                                                     const float* __restrict__ Wf2,
                                                     float* __restrict__ s2,
                                                     float* __restrict__ be,
                                                     float* __restrict__ w0,
                                                     float* __restrict__ bbuf) {
    __shared__ float sf[256];
    int task = blockIdx.y;
    int t = threadIdx.x;
    if (task == 0) {
        int khalf = blockIdx.x & 1, chunk = blockIdx.x >> 1;   // 16 chunks of 390
        int k = khalf * 256 + t;
        float s = 0.f, b = 0.f;
        int d0 = chunk * 390, d1 = d0 + 390;
        for (int d = d0; d < d1; ++d) {
            float e = embed[(size_t)d * KN + k];
            s = fmaf(e, e, s);
            b = fmaf(bf2[d], e, b);
        }
        atomicAdd(&s2[k], s);
        atomicAdd(&be[k], b);
    } else if (task == 1) {
        int w = t >> 6, lane = t & 63;
        #pragma unroll
        for (int jj = 0; jj < 4; ++jj) {
            int j = blockIdx.x * 16 + w * 4 + jj;
            float s = 0.f;
            for (int d = lane; d < ED; d += 64)
                s = fmaf(Wf2[(size_t)j * ED + d], bf2[d], s);
            #pragma unroll
            for (int dd = 1; dd < 64; dd <<= 1) s += __shfl_xor(s, dd);
            if (lane == 0) w0[j] = s;
        }
    } else {
        if (blockIdx.x > 0) return;
        float s = 0.f;
        for (int d = t; d < ED; d += 256) { float v = bf2[d]; s = fmaf(v, v, s); }
        sf[t] = s; __syncthreads();
        for (int r = 128; r > 0; r >>= 1) { if (t < r) sf[t] += sf[t + r]; __syncthreads(); }
        if (t == 0) bbuf[0] = sf[0];
    }
}

// ---------------------------------------------------------------------------
// 3-pass split-fp16 MFMA GEMM -> per-z partial C. grid (4,4,16), block 512.
// Block tile 128x128; wave (mi=w&3, ni=w>>2) covers 32 rows x 64 cols.
// ---------------------------------------------------------------------------
__global__ __launch_bounds__(512) void mfma3_kernel(const _Float16* __restrict__ As,
                                                    const _Float16* __restrict__ Al,
                                                    const _Float16* __restrict__ Bs,
                                                    const _Float16* __restrict__ Bl,
                                                    float* __restrict__ Cp, int NC) {
    int t = threadIdx.x;
    int w = t >> 6, L = t & 63;
    int lane16 = L & 15, quad = L >> 4;
    int m0 = blockIdx.x * 128 + (w & 3) * 32;
    int n0 = blockIdx.y * 128 + (w >> 2) * 64;
    int ta = m0 >> 4, tb = n0 >> 4;
    int z = blockIdx.z;
    int base = NC / 16, rem = NC % 16;
    int c0 = z * base + (z < rem ? z : rem);
    int cnt = base + (z < rem ? 1 : 0);
    f32x4 acc[2][4];
    #pragma unroll
    for (int rt = 0; rt < 2; ++rt)
        #pragma unroll
        for (int tt = 0; tt < 4; ++tt) acc[rt][tt] = (f32x4){0.f, 0.f, 0.f, 0.f};
    for (int ci = 0; ci < cnt; ++ci) {
        int c = c0 + ci;
        size_t oa0 = paddr(ta, NC, c, L, 0), oa1 = paddr(ta + 1, NC, c, L, 0);
        half8 A0h = *(const half8*)(As + oa0);
        half8 A0l = *(const half8*)(Al + oa0);
        half8 A1h = *(const half8*)(As + oa1);
        half8 A1l = *(const half8*)(Al + oa1);
        #pragma unroll
        for (int tt = 0; tt < 4; ++tt) {
            size_t ob = paddr(tb + tt, NC, c, L, 0);
            half8 Bh = *(const half8*)(Bs + ob);
            half8 Bl8 = *(const half8*)(Bl + ob);
            acc[0][tt] = MFMA16(A0h, Bl8, MFMA16(A0l, Bh, MFMA16(A0h, Bh, acc[0][tt])));
            acc[1][tt] = MFMA16(A1h, Bl8, MFMA16(A1l, Bh, MFMA16(A1h, Bh, acc[1][tt])));
        }
    }
    float* C = Cp + (size_t)z * KN * KN;
    #pragma unroll
    for (int rt = 0; rt < 2; ++rt)
        #pragma unroll
        for (int tt = 0; tt < 4; ++tt)
            #pragma unroll
            for (int r = 0; r < 4; ++r)
                C[(size_t)(m0 + rt * 16 + quad * 4 + r) * KN
                  + n0 + tt * 16 + lane16] = acc[rt][tt][r];
}

// 1-pass variant -> per-z partial C (for G)
__global__ __launch_bounds__(512) void mfma1_kernel(const _Float16* __restrict__ As,
                                                    const _Float16* __restrict__ Bs,
                                                    float* __restrict__ Cp, int NC) {
    int t = threadIdx.x;
    int w = t >> 6, L = t & 63;
    int lane16 = L & 15, quad = L >> 4;
    int m0 = blockIdx.x * 128 + (w & 3) * 32;
    int n0 = blockIdx.y * 128 + (w >> 2) * 64;
    int ta = m0 >> 4, tb = n0 >> 4;
    int z = blockIdx.z;
    int base = NC / 16, rem = NC % 16;
    int c0 = z * base + (z < rem ? z : rem);
    int cnt = base + (z < rem ? 1 : 0);
    f32x4 acc[2][4];
    #pragma unroll
    for (int rt = 0; rt < 2; ++rt)
        #pragma unroll
        for (int tt = 0; tt < 4; ++tt) acc[rt][tt] = (f32x4){0.f, 0.f, 0.f, 0.f};
    for (int ci = 0; ci < cnt; ++ci) {
        int c = c0 + ci;
        half8 A0h = *(const half8*)(As + paddr(ta, NC, c, L, 0));
        half8 A1h = *(const half8*)(As + paddr(ta + 1, NC, c, L, 0));
        #pragma unroll
        for (int tt = 0; tt < 4; ++tt) {
            half8 Bh = *(const half8*)(Bs + paddr(tb + tt, NC, c, L, 0));
            acc[0][tt] = MFMA16(A0h, Bh, acc[0][tt]);
            acc[1][tt] = MFMA16(A1h, Bh, acc[1][tt]);
        }
    }
    float* C = Cp + (size_t)z * KN * KN;
    #pragma unroll
    for (int rt = 0; rt < 2; ++rt)
        #pragma unroll
        for (int tt = 0; tt < 4; ++tt)
            #pragma unroll
            for (int r = 0; r < 4; ++r)
                C[(size_t)(m0 + rt * 16 + quad * 4 + r) * KN
                  + n0 + tt * 16 + lane16] = acc[rt][tt][r];
}

// ---------------------------------------------------------------------------
// Reduce 16 We partials + transpose-pack to B-side hi/lo frags (NC=16)
// ---------------------------------------------------------------------------
__global__ __launch_bounds__(256) void wepack_kernel(const float* __restrict__ WeP,
                                                     _Float16* __restrict__ WePs,
                                                     _Float16* __restrict__ WePl) {
    int g = blockIdx.x * 256 + threadIdx.x;      // j*512 + k
    int j = g >> 9, k = g & 511;
    float v = 0.f;
    #pragma unroll
    for (int z = 0; z < 16; ++z) v += WeP[(size_t)z * KN * KN + g];
    _Float16 hi = (_Float16)v;
    size_t a = paddr(k >> 4, 16, j >> 5, ((j & 31) >> 3) * 16 + (k & 15), j & 7);
    WePs[a] = hi;
    WePl[a] = (_Float16)(v - (float)hi);
}

// Reduce 16 G partials -> G fp32
__global__ __launch_bounds__(256) void gred_kernel(const float* __restrict__ GP,
                                                   float* __restrict__ G) {
    int g = blockIdx.x * 256 + threadIdx.x;
    float v = 0.f;
    #pragma unroll
    for (int z = 0; z < 16; ++z) v += GP[(size_t)z * KN * KN + g];
    G[g] = v;
}

// ---------------------------------------------------------------------------
// Fused MFMA encoder: grid (BN/32, 2), block 512 (8 waves x 64 cols = 512 cols).
// y=0: h=relu(x@Wf1+bf1) -> packed HPs/HPl (A-side), HTP (hi), colsum.
// y=1: hx=relu(x@Wx1+bx1) staged in LDS -> EX = hx@Wx2+bx2 via 2nd MFMA stage.
// ---------------------------------------------------------------------------
__global__ __launch_bounds__(512) void enc1_kernel(
        const _Float16* __restrict__ XPs, const _Float16* __restrict__ XPl,
        const _Float16* __restrict__ WfxPs, const _Float16* __restrict__ WfxPl,
        const float* __restrict__ bfx,
        const _Float16* __restrict__ Wx2Ps, const _Float16* __restrict__ Wx2Pl,
        const float* __restrict__ bx2,
        _Float16* __restrict__ HPs, _Float16* __restrict__ HPl,
        _Float16* __restrict__ HTP,
        float* __restrict__ colsum, float* __restrict__ EX) {
    __shared__ _Float16 hhi[32][CH];   // 32 KB
    __shared__ _Float16 hlo[32][CH];   // 32 KB
    int t = threadIdx.x;
    int w = t >> 6, L = t & 63;
    int l16 = L & 15, quad = L >> 4;
    int m0 = blockIdx.x * 32;
    int ta = m0 >> 4;
    int enc = blockIdx.y;
    int n0 = enc * 512 + w * 64;
    int tb = n0 >> 4;
    f32x4 acc[2][4];
    #pragma unroll
    for (int rt = 0; rt < 2; ++rt)
        #pragma unroll
        for (int tt = 0; tt < 4; ++tt) acc[rt][tt] = (f32x4){0.f, 0.f, 0.f, 0.f};
    #pragma unroll
    for (int c = 0; c < 4; ++c) {
        size_t oa0 = paddr(ta, 4, c, L, 0), oa1 = paddr(ta + 1, 4, c, L, 0);
        half8 A0h = *(const half8*)(XPs + oa0);
        half8 A0l = *(const half8*)(XPl + oa0);
        half8 A1h = *(const half8*)(XPs + oa1);
        half8 A1l = *(const half8*)(XPl + oa1);
        #pragma unroll
        for (int tt = 0; tt < 4; ++tt) {
            size_t ob = paddr(tb + tt, 4, c, L, 0);
            half8 Bh = *(const half8*)(WfxPs + ob);
            half8 Bl8 = *(const half8*)(WfxPl + ob);
            acc[0][tt] = MFMA16(A0h, Bl8, MFMA16(A0l, Bh, MFMA16(A0h, Bh, acc[0][tt])));
            acc[1][tt] = MFMA16(A1h, Bl8, MFMA16(A1l, Bh, MFMA16(A1h, Bh, acc[1][tt])));
        }
    }
    #pragma unroll
    for (int rt = 0; rt < 2; ++rt)
        #pragma unroll
        for (int tt = 0; tt < 4; ++tt) {
            int col = w * 64 + tt * 16 + l16;
            float bias = bfx[enc * 512 + col];
            #pragma unroll
            for (int r = 0; r < 4; ++r) {
                int row = rt * 16 + quad * 4 + r;
                float v = fmaxf(acc[rt][tt][r] + bias, 0.f);
                _Float16 hi = (_Float16)v;
                hhi[row][col] = hi;
                hlo[row][col] = (_Float16)(v - (float)hi);
            }
        }
    __syncthreads();
    if (enc == 0) {
        float s = 0.f;
        #pragma unroll
        for (int r = 0; r < 32; ++r) s += (float)hhi[r][t] + (float)hlo[r][t];
        atomicAdd(&colsum[t], s);
        #pragma unroll
        for (int i = 0; i < 4; ++i) {
            int idx = t + 512 * i;                // 0..2047
            int tile2 = idx >> 10;
            int c = (idx >> 6) & 15;
            int lane = idx & 63;
            int m = tile2 * 16 + (lane & 15);
            int d0 = c * 32 + ((lane >> 4) << 3);
            *(half8*)(HPs + paddr(ta + tile2, 16, c, lane, 0)) = *(half8*)(&hhi[m][d0]);
            *(half8*)(HPl + paddr(ta + tile2, 16, c, lane, 0)) = *(half8*)(&hlo[m][d0]);
        }
        int cb = blockIdx.x;                      // sample chunk for HTP
        #pragma unroll
        for (int i = 0; i < 4; ++i) {
            int idx = t + 512 * i;
            int chtile = idx >> 6;
            int lane = idx & 63;
            int ch = chtile * 16 + (lane & 15);
            int b0 = (lane >> 4) << 3;
            half8 hh;
            #pragma unroll
            for (int e = 0; e < 8; ++e) hh[e] = hhi[b0 + e][ch];
            *(half8*)(HTP + paddr(chtile, 512, cb, lane, 0)) = hh;
        }
    } else {
        int rt = w & 1, ct = w >> 1;
        f32x4 eacc = (f32x4){0.f, 0.f, 0.f, 0.f};
        for (int c = 0; c < 16; ++c) {
            int d0 = c * 32 + (quad << 3);
            int m = rt * 16 + l16;
            half8 Ah = *(half8*)(&hhi[m][d0]);
            half8 Al = *(half8*)(&hlo[m][d0]);
            size_t ob = paddr(ct, 16, c, L, 0);
            half8 Bh = *(const half8*)(Wx2Ps + ob);
            half8 Bl8 = *(const half8*)(Wx2Pl + ob);
            eacc = MFMA16(Ah, Bl8, MFMA16(Al, Bh, MFMA16(Ah, Bh, eacc)));
        }
        int col = ct * 16 + l16;
        float bias = bx2[col];
        #pragma unroll
        for (int r = 0; r < 4; ++r) {
            int row = m0 + rt * 16 + quad * 4 + r;
            EX[(size_t)row * DIN + col] = eacc[r] + bias;
        }
    }
}

// ---------------------------------------------------------------------------
// Score/argmin: one block (512 thr, 8 waves) covers 32 samples x ALL 512 cols.
// g_k = 0.5*s2[k]-be[k]-h.We[:,k]; 3-pass split; argmin finalized in-block
// (tie -> lowest k, matching np.argmin). Also accumulates sum(2*g_min).
// ---------------------------------------------------------------------------
__global__ __launch_bounds__(512) void score_kernel(
        const _Float16* __restrict__ HPs, const _Float16* __restrict__ HPl,
        const _Float16* __restrict__ WePs, const _Float16* __restrict__ WePl,
        const float* __restrict__ s2, const float* __restrict__ be,
        int* __restrict__ ind, float* __restrict__ out_ind,
        int* __restrict__ counts, float* __restrict__ diffsum) {
    __shared__ float redv[8][32];
    __shared__ int   redi[8][32];
    __shared__ float fin[32];
    int t = threadIdx.x;
    int w = t >> 6, L = t & 63;
    int l16 = L & 15, quad = L >> 4;
    int m0 = blockIdx.x * 32;
    int ta = m0 >> 4;
    int colbase = w * 64;
    int tb = w * 4;
    float cks[4];
    #pragma unroll
    for (int tt = 0; tt < 4; ++tt) {
        int c = colbase + tt * 16 + l16;
        cks[tt] = 0.5f * s2[c] - be[c];
    }
    f32x4 acc[2][4];
    #pragma unroll
    for (int rt = 0; rt < 2; ++rt)
        #pragma unroll
        for (int tt = 0; tt < 4; ++tt) acc[rt][tt] = (f32x4){0.f, 0.f, 0.f, 0.f};
    #pragma unroll
    for (int c = 0; c < 16; ++c) {
        size_t oa0 = paddr(ta, 16, c, L, 0), oa1 = paddr(ta + 1, 16, c, L, 0);
        half8 A0h = *(const half8*)(HPs + oa0);
        half8 A0l = *(const half8*)(HPl + oa0);
        half8 A1h = *(const half8*)(HPs + oa1);
        half8 A1l = *(const half8*)(HPl + oa1);
        #pragma unroll
        for (int tt = 0; tt < 4; ++tt) {
            size_t ob = paddr(tb + tt, 16, c, L, 0);
            half8 Bh = *(const half8*)(WePs + ob);
            half8 Bl8 = *(const half8*)(WePl + ob);
            acc[0][tt] = MFMA16(A0h, Bl8, MFMA16(A0l, Bh, MFMA16(A0h, Bh, acc[0][tt])));
            acc[1][tt] = MFMA16(A1h, Bl8, MFMA16(A1l, Bh, MFMA16(A1h, Bh, acc[1][tt])));
        }
    }
    #pragma unroll
    for (int rt = 0; rt < 2; ++rt) {
        #pragma unroll
        for (int r = 0; r < 4; ++r) {
            float mv = cks[0] - acc[rt][0][r];
            int mi = colbase + l16;
            #pragma unroll
            for (int tt = 1; tt < 4; ++tt) {
                float v = cks[tt] - acc[rt][tt][r];
                int c = colbase + tt * 16 + l16;
                if (v < mv || (v == mv && c < mi)) { mv = v; mi = c; }
            }
            #pragma unroll
            for (int d = 1; d < 16; d <<= 1) {
                float ov = __shfl_xor(mv, d);
                int oi = __shfl_xor(mi, d);
                if (ov < mv || (ov == mv && oi < mi)) { mv = ov; mi = oi; }
            }
            if (l16 == 0) {
                int row = rt * 16 + quad * 4 + r;
                redv[w][row] = mv; redi[w][row] = mi;
            }
        }
    }
    __syncthreads();
    if (t < 32) {
        float mv = redv[0][t]; int mi = redi[0][t];
        #pragma unroll
        for (int w2 = 1; w2 < 8; ++w2) {
            float ov = redv[w2][t]; int oi = redi[w2][t];
            if (ov < mv || (ov == mv && oi < mi)) { mv = ov; mi = oi; }
        }
        int b = m0 + t;
        ind[b] = mi;
        out_ind[b] = (float)mi;
        atomicAdd(&counts[mi], 1);
        fin[t] = 2.f * mv;
    }
    __syncthreads();
    if (t == 0) {
        float s = 0.f;
        #pragma unroll
        for (int i = 0; i < 32; ++i) s += fin[i];
        atomicAdd(diffsum, s);
    }
}

// ---------------------------------------------------------------------------
// diffsum += sum(H^T H o G), tile-wise, no HtH materialization.
// grid (4,4,16), block 512; wave covers 32x64 of the 128x128 tile.
// ---------------------------------------------------------------------------
__global__ __launch_bounds__(512) void hth_kernel(const _Float16* __restrict__ HTP,
                                                  const float* __restrict__ G,
                                                  float* __restrict__ diffsum) {
    __shared__ float sf[512];
    int t = threadIdx.x;
    int w = t >> 6, L = t & 63;
    int lane16 = L & 15, quad = L >> 4;
    int m0 = blockIdx.x * 128 + (w & 3) * 32;
    int n0 = blockIdx.y * 128 + (w >> 2) * 64;
    int ta = m0 >> 4, tb = n0 >> 4;
    int c0 = blockIdx.z * 32;
    f32x4 acc[2][4];
    #pragma unroll
    for (int rt = 0; rt < 2; ++rt)
        #pragma unroll
        for (int tt = 0; tt < 4; ++tt) acc[rt][tt] = (f32x4){0.f, 0.f, 0.f, 0.f};
    for (int ci = 0; ci < 32; ++ci) {
        int c = c0 + ci;
        half8 A0h = *(const half8*)(HTP + paddr(ta, 512, c, L, 0));
        half8 A1h = *(const half8*)(HTP + paddr(ta + 1, 512, c, L, 0));
        #pragma unroll
        for (int tt = 0; tt < 4; ++tt) {
            half8 Bh = *(const half8*)(HTP + paddr(tb + tt, 512, c, L, 0));
            acc[0][tt] = MFMA16(A0h, Bh, acc[0][tt]);
            acc[1][tt] = MFMA16(A1h, Bh, acc[1][tt]);
        }
    }
    float s = 0.f;
    #pragma unroll
    for (int rt = 0; rt < 2; ++rt)
        #pragma unroll
        for (int tt = 0; tt < 4; ++tt)
            #pragma unroll
            for (int r = 0; r < 4; ++r)
                s += acc[rt][tt][r] * G[(size_t)(m0 + rt * 16 + quad * 4 + r) * KN
                                        + n0 + tt * 16 + lane16];
    sf[t] = s;
    __syncthreads();
    for (int st = 256; st > 0; st >>= 1) {
        if (t < st) sf[t] += sf[t + st];
        __syncthreads();
    }
    if (t == 0) atomicAdd(diffsum, sf[0]);
}

// ---------------------------------------------------------------------------
// Finalize: offsets = exclusive scan(counts); perplexity; diff.
// ---------------------------------------------------------------------------
__global__ __launch_bounds__(512) void finalize_kernel(const int* __restrict__ counts,
                                                       int* __restrict__ offsets,
                                                       const float* __restrict__ diffsum,
                                                       const float* __restrict__ colsum,
                                                       const float* __restrict__ w0,
                                                       const float* __restrict__ bbuf,
                                                       float* __restrict__ out_diff,
                                                       float* __restrict__ out_perp) {
    __shared__ int   sc[512];
    __shared__ float sf[512];
    int t = threadIdx.x;
    int c = counts[t];
    sc[t] = c;
    double p = (double)c / (double)BN;
    double term = -p * log(p + 1e-10);
    float dotp = colsum[t] * w0[t];
    __syncthreads();
    int off = 0;
    for (int k = 0; k < t; ++k) off += sc[k];
    offsets[t] = off;
    sf[t] = dotp; __syncthreads();
    for (int s = 256; s > 0; s >>= 1) { if (t < s) sf[t] += sf[t + s]; __syncthreads(); }
    float dot_all = sf[0];
    __syncthreads();
    sf[t] = (float)term; __syncthreads();
    for (int s = 256; s > 0; s >>= 1) { if (t < s) sf[t] += sf[t + s]; __syncthreads(); }
    if (t == 0) {
        *out_perp = expf(sf[0]);
        *out_diff = (diffsum[0] + 2.f * dot_all + (float)BN * bbuf[0]) /
                    ((float)BN * (float)ED);
    }
}

// ---------------------------------------------------------------------------
// Scatter, block-aggregated: one global atomic per (block, expert) instead of
// per sample (hot-expert serialization fix).
// ---------------------------------------------------------------------------
__global__ __launch_bounds__(256) void scatter_kernel(const int* __restrict__ ind,
                                                      const int* __restrict__ offsets,
                                                      int* __restrict__ cursors,
                                                      int* __restrict__ perm) {
    __shared__ int lcount[KN], lbase[KN], lcur[KN];
    int t = threadIdx.x;
    for (int i = t; i < KN; i += 256) { lcount[i] = 0; lcur[i] = 0; }
    __syncthreads();
    int b = blockIdx.x * 256 + t;
    int k = ind[b];
    atomicAdd(&lcount[k], 1);
    __syncthreads();
    for (int i = t; i < KN; i += 256) {
        int c = lcount[i];
        if (c > 0) lbase[i] = atomicAdd(&cursors[i], c);
    }
    __syncthreads();
    int pos = offsets[k] + lbase[k] + atomicAdd(&lcur[k], 1);
    perm[pos] = b;
}

// ---------------------------------------------------------------------------
// Decoder: one wave per sample (load-balanced under histogram skew).
// ---------------------------------------------------------------------------
__global__ __launch_bounds__(256) void decode_kernel(const float* __restrict__ EX,
                                                     const int* __restrict__ perm,
                                                     const int* __restrict__ ind,
                                                     const float* __restrict__ W1,
                                                     const float* __restrict__ b1,
                                                     const float* __restrict__ W2,
                                                     const float* __restrict__ b2,
                                                     float* __restrict__ dec) {
    __shared__ float exs[4][DIN];
    __shared__ float h2s[4][DH];
    int t = threadIdx.x;
    int w = t >> 6, l = t & 63;
    int s = blockIdx.x * 4 + w;
    int b = perm[s];
    int k = ind[b];
    exs[w][l] = EX[(size_t)b * DIN + l];
    __syncthreads();
    const float* w1 = W1 + (size_t)k * (DIN * DH);
    float h = b1[(size_t)k * DH + l];
    #pragma unroll
    for (int j = 0; j < DIN; ++j)
        h = fmaf(exs[w][j], w1[(size_t)j * DH + l], h);
    h2s[w][l] = fmaxf(h, 0.f);
    __syncthreads();
    if (l < DY) {
        const float* w2 = W2 + (size_t)k * (DH * DY);
        float d = b2[(size_t)k * DY + l];
        #pragma unroll
        for (int j = 0; j < DH; ++j)
            d = fmaf(h2s[w][j], w2[(size_t)j * DY + l], d);
        dec[(size_t)b * DY + l] = d;
    }
}

// ---------------------------------------------------------------------------
extern "C" void kernel_launch(void* const* d_in, const int* in_sizes, int n_in,
                              void* d_out, int out_size, void* d_ws, size_t ws_size,
                              hipStream_t stream) {
    const float* x     = (const float*)d_in[0];
    const float* Wf1   = (const float*)d_in[1];
    const float* bf1   = (const float*)d_in[2];
    const float* Wf2   = (const float*)d_in[3];
    const float* bf2   = (const float*)d_in[4];
    const float* Wx1   = (const float*)d_in[5];
    const float* bx1   = (const float*)d_in[6];
    const float* Wx2   = (const float*)d_in[7];
    const float* bx2   = (const float*)d_in[8];
    const float* embed = (const float*)d_in[9];
    const float* W1    = (const float*)d_in[10];
    const float* b1    = (const float*)d_in[11];
    const float* W2    = (const float*)d_in[12];
    const float* b2    = (const float*)d_in[13];
    float* out = (float*)d_out;

    char* ws = (char*)d_ws;
    size_t off = 0;
    auto carve = [&](size_t bytes) -> void* {
        void* p = ws + off;
        off += (bytes + 255) & ~(size_t)255;
        return p;
    };
    _Float16* XPs   = (_Float16*)carve((size_t)BN * INC * 2);    // 4.2 MB
    _Float16* XPl   = (_Float16*)carve((size_t)BN * INC * 2);
    _Float16* WfxPs = (_Float16*)carve((size_t)1024 * INC * 2);
    _Float16* WfxPl = (_Float16*)carve((size_t)1024 * INC * 2);
    float*    bfx   = (float*)carve(1024 * 4);
    _Float16* Wx2Ps = (_Float16*)carve((size_t)DIN * CH * 2);
    _Float16* Wx2Pl = (_Float16*)carve((size_t)DIN * CH * 2);
    _Float16* WfPs  = (_Float16*)carve((size_t)CH * ED * 2);     // 6.4 MB
    _Float16* WfPl  = (_Float16*)carve((size_t)CH * ED * 2);
    _Float16* EmPs  = (_Float16*)carve((size_t)KN * ED * 2);
    _Float16* EmPl  = (_Float16*)carve((size_t)KN * ED * 2);
    // Union region: {WeP[16] + GP[16]} (33.6 MB, dead after gred) overlaps
    // {HPs + HPl + HTP} (50.4 MB, written later by enc1).
    char* un = (char*)carve((size_t)3 * BN * CH * 2);            // 50.4 MB
    float*    WeP = (float*)un;
    float*    GP  = (float*)(un + (size_t)16 * KN * KN * 4);
    _Float16* HPs = (_Float16*)un;
    _Float16* HPl = (_Float16*)(un + (size_t)BN * CH * 2);
    _Float16* HTP = (_Float16*)(un + (size_t)BN * CH * 4);
    _Float16* WePs = (_Float16*)carve((size_t)KN * CH * 2);
    _Float16* WePl = (_Float16*)carve((size_t)KN * CH * 2);
    float*    G    = (float*)carve((size_t)KN * KN * 4);
    float*    EX   = (float*)carve((size_t)BN * DIN * 4);        // 4.2 MB
    char* zbase = ws + off;                                      // ---- zero region ----
    float* s2    = (float*)carve(KN * 4);
    float* be    = (float*)carve(KN * 4);
    float* w0    = (float*)carve(CH * 4);
    float* colsum= (float*)carve(CH * 4);
    int*   counts= (int*)carve(KN * 4);
    int*   cursors=(int*)carve(KN * 4);
    float* diffsum=(float*)carve(256);
    float* bbuf  = (float*)carve(256);
    size_t zbytes = (size_t)(ws + off - zbase);                  // ---- end zero region ----
    int*   ind     = (int*)carve(BN * 4);
    int*   offsets = (int*)carve(KN * 4);
    int*   perm    = (int*)carve(BN * 4);
    (void)in_sizes; (void)n_in; (void)out_size; (void)ws_size;

    hipMemsetAsync(zbase, 0, zbytes, stream);
    xpack_kernel<<<BN / 32, 256, 0, stream>>>(x, XPs, XPl);
    wfxpack_kernel<<<64, 256, 0, stream>>>(Wf1, Wx1, bf1, bx1, WfxPs, WfxPl, bfx);
    wx2pack_kernel<<<4, 256, 0, stream>>>(Wx2, Wx2Ps, Wx2Pl);
    splitwf2_kernel<<<dim3(NCW, 64), 256, 0, stream>>>(Wf2, WfPs, WfPl);
    embt_kernel<<<dim3(NCW, 16), 256, 0, stream>>>(embed, EmPs, EmPl);
    psmall_kernel<<<dim3(32, 3), 256, 0, stream>>>(embed, bf2, Wf2, s2, be, w0, bbuf);
    mfma3_kernel<<<dim3(4, 4, 16), 512, 0, stream>>>(WfPs, WfPl, EmPs, EmPl, WeP, NCW);
    mfma1_kernel<<<dim3(4, 4, 16), 512, 0, stream>>>(WfPs, WfPs, GP, NCW);
    wepack_kernel<<<KN * KN / 256, 256, 0, stream>>>(WeP, WePs, WePl);
    gred_kernel<<<KN * KN / 256, 256, 0, stream>>>(GP, G);
    enc1_kernel<<<dim3(BN / 32, 2), 512, 0, stream>>>(XPs, XPl, WfxPs, WfxPl, bfx,
                                                      Wx2Ps, Wx2Pl, bx2,
                                                      HPs, HPl, HTP, colsum, EX);
    score_kernel<<<BN / 32, 512, 0, stream>>>(HPs, HPl, WePs, WePl, s2, be,
                                              ind, out + OUT_IND, counts, diffsum);
    hth_kernel<<<dim3(4, 4, 16), 512, 0, stream>>>(HTP, G, diffsum);
    finalize_kernel<<<1, 512, 0, stream>>>(counts, offsets, diffsum, colsum, w0, bbuf,
                                           out + OUT_DIFF, out + OUT_PERP);
    scatter_kernel<<<BN / 256, 256, 0, stream>>>(ind, offsets, cursors, perm);
    decode_kernel<<<BN / 4, 256, 0, stream>>>(EX, perm, ind, W1, b1, W2, b2,
                                              out + OUT_DEC);
}

// Round 7
// 431.973 us; speedup vs baseline: 4.7954x; 1.1289x over previous
//
#include <hip/hip_runtime.h>
#include <math.h>

// Problem constants
#define BN     16384
#define INC    128
#define CH     512
#define ED     6240
#define KN     512      // NUM_EMB
#define DIN    64
#define DH     64
#define DY     32
#define NCW    195      // ED/32 k-chunks for Wf2/embed packing

// d_out layout (float32): dec[16384*32] | diff[1] | embed_ind[16384] | perplexity[1]
#define OUT_DEC   0
#define OUT_DIFF  (BN*DY)
#define OUT_IND   (BN*DY + 1)
#define OUT_PERP  (BN*DY + 1 + BN)

typedef _Float16 half8 __attribute__((ext_vector_type(8)));
typedef float    f32x4 __attribute__((ext_vector_type(4)));
#define MFMA16(a, b, c) __builtin_amdgcn_mfma_f32_16x16x32_f16(a, b, c, 0, 0, 0)

// Packed fragment-tile layout: element (row r within 16-row tile `tile`,
// k-dim index d) lives at ((tile*NC + d/32)*64 + ((d%32)/8)*16 + (r%16))*8 + d%8.
// One wave-load of half8 at lane L = contiguous 1KB = one full MFMA fragment.
__device__ __forceinline__ size_t paddr(int tile, int NC, int c, int lane, int e) {
    return ((size_t)(tile * NC + c) * 64 + lane) * 8 + e;
}

// ---------------------------------------------------------------------------
// Pack x [BN][128] fp32 -> XPs/XPl packed hi/lo (A-side, NC=4)
// ---------------------------------------------------------------------------
__global__ __launch_bounds__(256) void xpack_kernel(const float* __restrict__ x,
                                                    _Float16* __restrict__ XPs,
                                                    _Float16* __restrict__ XPl) {
    __shared__ float xt[32][INC];
    int t = threadIdx.x;
    int m0 = blockIdx.x * 32;
    for (int i = t; i < 32 * (INC / 4); i += 256) {
        int row = i >> 5, c4 = (i & 31) << 2;
        *(float4*)&xt[row][c4] = *(const float4*)&x[(size_t)(m0 + row) * INC + c4];
    }
    __syncthreads();
    int ta = m0 >> 4;
    #pragma unroll
    for (int i = 0; i < 2; ++i) {
        int idx = t + 256 * i;              // 0..511
        int tile2 = idx >> 8;               // 0..1
        int c = (idx >> 6) & 3;
        int lane = idx & 63;
        int m = tile2 * 16 + (lane & 15);
        int d0 = c * 32 + ((lane >> 4) << 3);
        half8 hh, ll;
        #pragma unroll
        for (int e = 0; e < 8; ++e) {
            float v = xt[m][d0 + e];
            _Float16 hi = (_Float16)v;
            hh[e] = hi;
            ll[e] = (_Float16)(v - (float)hi);
        }
        *(half8*)(XPs + paddr(ta + tile2, 4, c, lane, 0)) = hh;
        *(half8*)(XPl + paddr(ta + tile2, 4, c, lane, 0)) = ll;
    }
}

// ---------------------------------------------------------------------------
// Pack fused Wf1|Wx1 cols (n<512 -> Wf1 col n; else Wx1 col n-512) to B-side
// frag layout (NC=4). Also bfx = concat(bf1, bx1).
// ---------------------------------------------------------------------------
__global__ __launch_bounds__(256) void wfxpack_kernel(const float* __restrict__ Wf1,
                                                      const float* __restrict__ Wx1,
                                                      const float* __restrict__ bf1,
                                                      const float* __restrict__ bx1,
                                                      _Float16* __restrict__ WfxPs,
                                                      _Float16* __restrict__ WfxPl,
                                                      float* __restrict__ bfx) {
    int t = threadIdx.x;
    int tile = blockIdx.x;                  // 0..63
    for (int i = t; i < 2048; i += 256) {
        int c = i >> 9, lane = (i >> 3) & 63, e = i & 7;
        int n = tile * 16 + (lane & 15);
        int d = c * 32 + ((lane >> 4) << 3) + e;
        float v = (n < 512) ? Wf1[(size_t)d * CH + n] : Wx1[(size_t)d * CH + n - 512];
        _Float16 hi = (_Float16)v;
        size_t a = paddr(tile, 4, c, lane, e);
        WfxPs[a] = hi;
        WfxPl[a] = (_Float16)(v - (float)hi);
    }
    if (blockIdx.x == 0)
        for (int j = t; j < 512; j += 256) { bfx[j] = bf1[j]; bfx[512 + j] = bx1[j]; }
}

// ---------------------------------------------------------------------------
// Pack Wx2 [512][64] -> B-side frag layout (4 tiles, NC=16), hi/lo
// ---------------------------------------------------------------------------
__global__ __launch_bounds__(256) void wx2pack_kernel(const float* __restrict__ Wx2,
                                                      _Float16* __restrict__ Ps,
                                                      _Float16* __restrict__ Pl) {
    int t = threadIdx.x;
    int tile = blockIdx.x;                  // 0..3
    for (int i = t; i < 8192; i += 256) {
        int c = i >> 9, lane = (i >> 3) & 63, e = i & 7;
        int n = tile * 16 + (lane & 15);
        int d = c * 32 + ((lane >> 4) << 3) + e;
        float v = Wx2[(size_t)d * DIN + n];
        _Float16 hi = (_Float16)v;
        size_t a = paddr(tile, 16, c, lane, e);
        Ps[a] = hi;
        Pl[a] = (_Float16)(v - (float)hi);
    }
}

// ---------------------------------------------------------------------------
// Split Wf2 [512][6240] fp32 -> packed fp16 hi/lo (frag layout, NC=195).
// Folded: w0[j] += Wf2[j,:].bf2 partials (atomic — feeds only loose-tol diff).
// ---------------------------------------------------------------------------
__global__ __launch_bounds__(256) void splitwf2_kernel(const float* __restrict__ Wf2,
                                                       const float* __restrict__ bf2,
                                                       _Float16* __restrict__ WfPs,
                                                       _Float16* __restrict__ WfPl,
                                                       float* __restrict__ w0) {
    __shared__ float red[8][33];
    int t = threadIdx.x;
    int d = blockIdx.x * 32 + (t & 31);
    int j = blockIdx.y * 8 + (t >> 5);
    float v = Wf2[(size_t)j * ED + d];
    _Float16 hi = (_Float16)v;
    size_t a = paddr(j >> 4, NCW, d >> 5, ((d & 31) >> 3) * 16 + (j & 15), d & 7);
    WfPs[a] = hi;
    WfPl[a] = (_Float16)(v - (float)hi);
    red[t >> 5][t & 31] = v * bf2[d];
    __syncthreads();
    if (t < 8) {
        float s = 0.f;
        #pragma unroll
        for (int i = 0; i < 32; ++i) s += red[t][i];
        atomicAdd(&w0[blockIdx.y * 8 + t], s);
    }
}

// ---------------------------------------------------------------------------
// Transpose+split embed [6240][512] -> packed fp16 hi/lo (rows=codewords).
// (R7: pure pack — s2/be moved to deterministic s2bep/sbered; R6's atomic
// fold here made argmin inputs nondeterministic and tripped the harness.)
// ---------------------------------------------------------------------------
__global__ __launch_bounds__(256) void embt_kernel(const float* __restrict__ embed,
                                                   _Float16* __restrict__ EmPs,
                                                   _Float16* __restrict__ EmPl) {
    __shared__ float tile[32][33];
    int t = threadIdx.x;
    int dl = t >> 5, kl = t & 31;
    #pragma unroll
    for (int r = 0; r < 4; ++r)
        tile[dl + 8 * r][kl] = embed[(size_t)(blockIdx.x * 32 + dl + 8 * r) * KN
                                     + blockIdx.y * 32 + kl];
    __syncthreads();
    int d = blockIdx.x * 32 + kl;
    #pragma unroll
    for (int r = 0; r < 4; ++r) {
        int k = blockIdx.y * 32 + dl + 8 * r;
        float v = tile[kl][dl + 8 * r];
        _Float16 hi = (_Float16)v;
        size_t a = paddr(k >> 4, NCW, d >> 5, ((d & 31) >> 3) * 16 + (k & 15), d & 7);
        EmPs[a] = hi;
        EmPl[a] = (_Float16)(v - (float)hi);
    }
}

// ---------------------------------------------------------------------------
// DETERMINISTIC s2/be partials: grid (16,8). Block = 32 k's x 780 d's.
// Fixed-order in-block reduction, plain stores (no atomics).
// ---------------------------------------------------------------------------
__global__ __launch_bounds__(256) void s2bep_kernel(const float* __restrict__ embed,
                                                    const float* __restrict__ bf2,
                                                    float* __restrict__ s2p,
                                                    float* __restrict__ bep) {
    __shared__ float rs[8][33], rb[8][33];
    int t = threadIdx.x;
    int kl = t & 31, dl = t >> 5;
    int kb = blockIdx.x * 32;
    int d0 = blockIdx.y * 780;
    float s = 0.f, b = 0.f;
    for (int d = d0 + dl; d < d0 + 780; d += 8) {
        float e = embed[(size_t)d * KN + kb + kl];
        s = fmaf(e, e, s);
        b = fmaf(bf2[d], e, b);
    }
    rs[dl][kl] = s; rb[dl][kl] = b;
    __syncthreads();
    if (t < 32) {
        float ss = 0.f, bb = 0.f;
        #pragma unroll
        for (int i = 0; i < 8; ++i) { ss += rs[i][t]; bb += rb[i][t]; }
        s2p[blockIdx.y * KN + kb + t] = ss;
        bep[blockIdx.y * KN + kb + t] = bb;
    }
}

// Deterministic final reduce: s2[k], be[k] from 8 partials in fixed order.
__global__ __launch_bounds__(512) void sbered_kernel(const float* __restrict__ s2p,
                                                     const float* __restrict__ bep,
                                                     float* __restrict__ s2,
                                                     float* __restrict__ be) {
    int k = threadIdx.x;
    float s = 0.f, b = 0.f;
    #pragma unroll
    for (int y = 0; y < 8; ++y) {
        s += s2p[y * KN + k];
        b += bep[y * KN + k];
    }
    s2[k] = s;
    be[k] = b;
}

// ---------------------------------------------------------------------------
// 3-pass split-fp16 MFMA GEMM -> per-z partial C. grid (4,4,16), block 512.
// Block tile 128x128; wave (mi=w&3, ni=w>>2) covers 32 rows x 64 cols.
// ---------------------------------------------------------------------------
__global__ __launch_bounds__(512) void mfma3_kernel(const _Float16* __restrict__ As,
                                                    const _Float16* __restrict__ Al,
                                                    const _Float16* __restrict__ Bs,
                                                    const _Float16* __restrict__ Bl,
                                                    float* __restrict__ Cp, int NC) {
    int t = threadIdx.x;
    int w = t >> 6, L = t & 63;
    int lane16 = L & 15, quad = L >> 4;
    int m0 = blockIdx.x * 128 + (w & 3) * 32;
    int n0 = blockIdx.y * 128 + (w >> 2) * 64;
    int ta = m0 >> 4, tb = n0 >> 4;
    int z = blockIdx.z;
    int base = NC / 16, rem = NC % 16;
    int c0 = z * base + (z < rem ? z : rem);
    int cnt = base + (z < rem ? 1 : 0);
    f32x4 acc[2][4];
    #pragma unroll
    for (int rt = 0; rt < 2; ++rt)
        #pragma unroll
        for (int tt = 0; tt < 4; ++tt) acc[rt][tt] = (f32x4){0.f, 0.f, 0.f, 0.f};
    for (int ci = 0; ci < cnt; ++ci) {
        int c = c0 + ci;
        size_t oa0 = paddr(ta, NC, c, L, 0), oa1 = paddr(ta + 1, NC, c, L, 0);
        half8 A0h = *(const half8*)(As + oa0);
        half8 A0l = *(const half8*)(Al + oa0);
        half8 A1h = *(const half8*)(As + oa1);
        half8 A1l = *(const half8*)(Al + oa1);
        #pragma unroll
        for (int tt = 0; tt < 4; ++tt) {
            size_t ob = paddr(tb + tt, NC, c, L, 0);
            half8 Bh = *(const half8*)(Bs + ob);
            half8 Bl8 = *(const half8*)(Bl + ob);
            acc[0][tt] = MFMA16(A0h, Bl8, MFMA16(A0l, Bh, MFMA16(A0h, Bh, acc[0][tt])));
            acc[1][tt] = MFMA16(A1h, Bl8, MFMA16(A1l, Bh, MFMA16(A1h, Bh, acc[1][tt])));
        }
    }
    float* C = Cp + (size_t)z * KN * KN;
    #pragma unroll
    for (int rt = 0; rt < 2; ++rt)
        #pragma unroll
        for (int tt = 0; tt < 4; ++tt)
            #pragma unroll
            for (int r = 0; r < 4; ++r)
                C[(size_t)(m0 + rt * 16 + quad * 4 + r) * KN
                  + n0 + tt * 16 + lane16] = acc[rt][tt][r];
}

// 1-pass variant -> per-z partial C (for G)
__global__ __launch_bounds__(512) void mfma1_kernel(const _Float16* __restrict__ As,
                                                    const _Float16* __restrict__ Bs,
                                                    float* __restrict__ Cp, int NC) {
    int t = threadIdx.x;
    int w = t >> 6, L = t & 63;
    int lane16 = L & 15, quad = L >> 4;
    int m0 = blockIdx.x * 128 + (w & 3) * 32;
    int n0 = blockIdx.y * 128 + (w >> 2) * 64;
    int ta = m0 >> 4, tb = n0 >> 4;
    int z = blockIdx.z;
    int base = NC / 16, rem = NC % 16;
    int c0 = z * base + (z < rem ? z : rem);
    int cnt = base + (z < rem ? 1 : 0);
    f32x4 acc[2][4];
    #pragma unroll
    for (int rt = 0; rt < 2; ++rt)
        #pragma unroll
        for (int tt = 0; tt < 4; ++tt) acc[rt][tt] = (f32x4){0.f, 0.f, 0.f, 0.f};
    for (int ci = 0; ci < cnt; ++ci) {
        int c = c0 + ci;
        half8 A0h = *(const half8*)(As + paddr(ta, NC, c, L, 0));
        half8 A1h = *(const half8*)(As + paddr(ta + 1, NC, c, L, 0));
        #pragma unroll
        for (int tt = 0; tt < 4; ++tt) {
            half8 Bh = *(const half8*)(Bs + paddr(tb + tt, NC, c, L, 0));
            acc[0][tt] = MFMA16(A0h, Bh, acc[0][tt]);
            acc[1][tt] = MFMA16(A1h, Bh, acc[1][tt]);
        }
    }
    float* C = Cp + (size_t)z * KN * KN;
    #pragma unroll
    for (int rt = 0; rt < 2; ++rt)
        #pragma unroll
        for (int tt = 0; tt < 4; ++tt)
            #pragma unroll
            for (int r = 0; r < 4; ++r)
                C[(size_t)(m0 + rt * 16 + quad * 4 + r) * KN
                  + n0 + tt * 16 + lane16] = acc[rt][tt][r];
}

// ---------------------------------------------------------------------------
// Reduce 16 We partials (fixed order — deterministic) + transpose-pack to
// B-side hi/lo frags (NC=16)
// ---------------------------------------------------------------------------
__global__ __launch_bounds__(256) void wepack_kernel(const float* __restrict__ WeP,
                                                     _Float16* __restrict__ WePs,
                                                     _Float16* __restrict__ WePl) {
    int g = blockIdx.x * 256 + threadIdx.x;      // j*512 + k
    int j = g >> 9, k = g & 511;
    float v = 0.f;
    #pragma unroll
    for (int z = 0; z < 16; ++z) v += WeP[(size_t)z * KN * KN + g];
    _Float16 hi = (_Float16)v;
    size_t a = paddr(k >> 4, 16, j >> 5, ((j & 31) >> 3) * 16 + (k & 15), j & 7);
    WePs[a] = hi;
    WePl[a] = (_Float16)(v - (float)hi);
}

// Reduce 16 G partials -> G fp32
__global__ __launch_bounds__(256) void gred_kernel(const float* __restrict__ GP,
                                                   float* __restrict__ G) {
    int g = blockIdx.x * 256 + threadIdx.x;
    float v = 0.f;
    #pragma unroll
    for (int z = 0; z < 16; ++z) v += GP[(size_t)z * KN * KN + g];
    G[g] = v;
}

// ---------------------------------------------------------------------------
// Fused MFMA encoder: grid (BN/32, 2), block 512 (8 waves x 64 cols = 512 cols).
// y=0: h=relu(x@Wf1+bf1) -> packed HPs/HPl (A-side), HTP (hi), colsum.
// y=1: hx=relu(x@Wx1+bx1) staged in LDS -> EX = hx@Wx2+bx2 via 2nd MFMA stage.
// ---------------------------------------------------------------------------
__global__ __launch_bounds__(512) void enc1_kernel(
        const _Float16* __restrict__ XPs, const _Float16* __restrict__ XPl,
        const _Float16* __restrict__ WfxPs, const _Float16* __restrict__ WfxPl,
        const float* __restrict__ bfx,
        const _Float16* __restrict__ Wx2Ps, const _Float16* __restrict__ Wx2Pl,
        const float* __restrict__ bx2,
        _Float16* __restrict__ HPs, _Float16* __restrict__ HPl,
        _Float16* __restrict__ HTP,
        float* __restrict__ colsum, float* __restrict__ EX) {
    __shared__ _Float16 hhi[32][CH];   // 32 KB
    __shared__ _Float16 hlo[32][CH];   // 32 KB
    int t = threadIdx.x;
    int w = t >> 6, L = t & 63;
    int l16 = L & 15, quad = L >> 4;
    int m0 = blockIdx.x * 32;
    int ta = m0 >> 4;
    int enc = blockIdx.y;
    int n0 = enc * 512 + w * 64;
    int tb = n0 >> 4;
    f32x4 acc[2][4];
    #pragma unroll
    for (int rt = 0; rt < 2; ++rt)
        #pragma unroll
        for (int tt = 0; tt < 4; ++tt) acc[rt][tt] = (f32x4){0.f, 0.f, 0.f, 0.f};
    #pragma unroll
    for (int c = 0; c < 4; ++c) {
        size_t oa0 = paddr(ta, 4, c, L, 0), oa1 = paddr(ta + 1, 4, c, L, 0);
        half8 A0h = *(const half8*)(XPs + oa0);
        half8 A0l = *(const half8*)(XPl + oa0);
        half8 A1h = *(const half8*)(XPs + oa1);
        half8 A1l = *(const half8*)(XPl + oa1);
        #pragma unroll
        for (int tt = 0; tt < 4; ++tt) {
            size_t ob = paddr(tb + tt, 4, c, L, 0);
            half8 Bh = *(const half8*)(WfxPs + ob);
            half8 Bl8 = *(const half8*)(WfxPl + ob);
            acc[0][tt] = MFMA16(A0h, Bl8, MFMA16(A0l, Bh, MFMA16(A0h, Bh, acc[0][tt])));
            acc[1][tt] = MFMA16(A1h, Bl8, MFMA16(A1l, Bh, MFMA16(A1h, Bh, acc[1][tt])));
        }
    }
    #pragma unroll
    for (int rt = 0; rt < 2; ++rt)
        #pragma unroll
        for (int tt = 0; tt < 4; ++tt) {
            int col = w * 64 + tt * 16 + l16;
            float bias = bfx[enc * 512 + col];
            #pragma unroll
            for (int r = 0; r < 4; ++r) {
                int row = rt * 16 + quad * 4 + r;
                float v = fmaxf(acc[rt][tt][r] + bias, 0.f);
                _Float16 hi = (_Float16)v;
                hhi[row][col] = hi;
                hlo[row][col] = (_Float16)(v - (float)hi);
            }
        }
    __syncthreads();
    if (enc == 0) {
        float s = 0.f;
        #pragma unroll
        for (int r = 0; r < 32; ++r) s += (float)hhi[r][t] + (float)hlo[r][t];
        atomicAdd(&colsum[t], s);
        #pragma unroll
        for (int i = 0; i < 4; ++i) {
            int idx = t + 512 * i;                // 0..2047
            int tile2 = idx >> 10;
            int c = (idx >> 6) & 15;
            int lane = idx & 63;
            int m = tile2 * 16 + (lane & 15);
            int d0 = c * 32 + ((lane >> 4) << 3);
            *(half8*)(HPs + paddr(ta + tile2, 16, c, lane, 0)) = *(half8*)(&hhi[m][d0]);
            *(half8*)(HPl + paddr(ta + tile2, 16, c, lane, 0)) = *(half8*)(&hlo[m][d0]);
        }
        int cb = blockIdx.x;                      // sample chunk for HTP
        #pragma unroll
        for (int i = 0; i < 4; ++i) {
            int idx = t + 512 * i;
            int chtile = idx >> 6;
            int lane = idx & 63;
            int ch = chtile * 16 + (lane & 15);
            int b0 = (lane >> 4) << 3;
            half8 hh;
            #pragma unroll
            for (int e = 0; e < 8; ++e) hh[e] = hhi[b0 + e][ch];
            *(half8*)(HTP + paddr(chtile, 512, cb, lane, 0)) = hh;
        }
    } else {
        int rt = w & 1, ct = w >> 1;
        f32x4 eacc = (f32x4){0.f, 0.f, 0.f, 0.f};
        for (int c = 0; c < 16; ++c) {
            int d0 = c * 32 + (quad << 3);
            int m = rt * 16 + l16;
            half8 Ah = *(half8*)(&hhi[m][d0]);
            half8 Al = *(half8*)(&hlo[m][d0]);
            size_t ob = paddr(ct, 16, c, L, 0);
            half8 Bh = *(const half8*)(Wx2Ps + ob);
            half8 Bl8 = *(const half8*)(Wx2Pl + ob);
            eacc = MFMA16(Ah, Bl8, MFMA16(Al, Bh, MFMA16(Ah, Bh, eacc)));
        }
        int col = ct * 16 + l16;
        float bias = bx2[col];
        #pragma unroll
        for (int r = 0; r < 4; ++r) {
            int row = m0 + rt * 16 + quad * 4 + r;
            EX[(size_t)row * DIN + col] = eacc[r] + bias;
        }
    }
}

// ---------------------------------------------------------------------------
// Score/argmin: one block (512 thr, 8 waves) covers 32 samples x ALL 512 cols.
// g_k = 0.5*s2[k]-be[k]-h.We[:,k]; 3-pass split; argmin finalized in-block
// (tie -> lowest k, matching np.argmin). Also accumulates sum(2*g_min).
// ---------------------------------------------------------------------------
__global__ __launch_bounds__(512) void score_kernel(
        const _Float16* __restrict__ HPs, const _Float16* __restrict__ HPl,
        const _Float16* __restrict__ WePs, const _Float16* __restrict__ WePl,
        const float* __restrict__ s2, const float* __restrict__ be,
        int* __restrict__ ind, float* __restrict__ out_ind,
        int* __restrict__ counts, float* __restrict__ diffsum) {
    __shared__ float redv[8][32];
    __shared__ int   redi[8][32];
    __shared__ float fin[32];
    int t = threadIdx.x;
    int w = t >> 6, L = t & 63;
    int l16 = L & 15, quad = L >> 4;
    int m0 = blockIdx.x * 32;
    int ta = m0 >> 4;
    int colbase = w * 64;
    int tb = w * 4;
    float cks[4];
    #pragma unroll
    for (int tt = 0; tt < 4; ++tt) {
        int c = colbase + tt * 16 + l16;
        cks[tt] = 0.5f * s2[c] - be[c];
    }
    f32x4 acc[2][4];
    #pragma unroll
    for (int rt = 0; rt < 2; ++rt)
        #pragma unroll
        for (int tt = 0; tt < 4; ++tt) acc[rt][tt] = (f32x4){0.f, 0.f, 0.f, 0.f};
    #pragma unroll
    for (int c = 0; c < 16; ++c) {
        size_t oa0 = paddr(ta, 16, c, L, 0), oa1 = paddr(ta + 1, 16, c, L, 0);
        half8 A0h = *(const half8*)(HPs + oa0);
        half8 A0l = *(const half8*)(HPl + oa0);
        half8 A1h = *(const half8*)(HPs + oa1);
        half8 A1l = *(const half8*)(HPl + oa1);
        #pragma unroll
        for (int tt = 0; tt < 4; ++tt) {
            size_t ob = paddr(tb + tt, 16, c, L, 0);
            half8 Bh = *(const half8*)(WePs + ob);
            half8 Bl8 = *(const half8*)(WePl + ob);
            acc[0][tt] = MFMA16(A0h, Bl8, MFMA16(A0l, Bh, MFMA16(A0h, Bh, acc[0][tt])));
            acc[1][tt] = MFMA16(A1h, Bl8, MFMA16(A1l, Bh, MFMA16(A1h, Bh, acc[1][tt])));
        }
    }
    #pragma unroll
    for (int rt = 0; rt < 2; ++rt) {
        #pragma unroll
        for (int r = 0; r < 4; ++r) {
            float mv = cks[0] - acc[rt][0][r];
            int mi = colbase + l16;
            #pragma unroll
            for (int tt = 1; tt < 4; ++tt) {
                float v = cks[tt] - acc[rt][tt][r];
                int c = colbase + tt * 16 + l16;
                if (v < mv || (v == mv && c < mi)) { mv = v; mi = c; }
            }
            #pragma unroll
            for (int d = 1; d < 16; d <<= 1) {
                float ov = __shfl_xor(mv, d);
                int oi = __shfl_xor(mi, d);
                if (ov < mv || (ov == mv && oi < mi)) { mv = ov; mi = oi; }
            }
            if (l16 == 0) {
                int row = rt * 16 + quad * 4 + r;
                redv[w][row] = mv; redi[w][row] = mi;
            }
        }
    }
    __syncthreads();
    if (t < 32) {
        float mv = redv[0][t]; int mi = redi[0][t];
        #pragma unroll
        for (int w2 = 1; w2 < 8; ++w2) {
            float ov = redv[w2][t]; int oi = redi[w2][t];
            if (ov < mv || (ov == mv && oi < mi)) { mv = ov; mi = oi; }
        }
        int b = m0 + t;
        ind[b] = mi;
        out_ind[b] = (float)mi;
        atomicAdd(&counts[mi], 1);
        fin[t] = 2.f * mv;
    }
    __syncthreads();
    if (t == 0) {
        float s = 0.f;
        #pragma unroll
        for (int i = 0; i < 32; ++i) s += fin[i];
        atomicAdd(diffsum, s);
    }
}

// ---------------------------------------------------------------------------
// diffsum += sum(H^T H o G), tile-wise, no HtH materialization.
// grid (4,4,16), block 512; wave covers 32x64 of the 128x128 tile.
// ---------------------------------------------------------------------------
__global__ __launch_bounds__(512) void hth_kernel(const _Float16* __restrict__ HTP,
                                                  const float* __restrict__ G,
                                                  float* __restrict__ diffsum) {
    __shared__ float sf[512];
    int t = threadIdx.x;
    int w = t >> 6, L = t & 63;
    int lane16 = L & 15, quad = L >> 4;
    int m0 = blockIdx.x * 128 + (w & 3) * 32;
    int n0 = blockIdx.y * 128 + (w >> 2) * 64;
    int ta = m0 >> 4, tb = n0 >> 4;
    int c0 = blockIdx.z * 32;
    f32x4 acc[2][4];
    #pragma unroll
    for (int rt = 0; rt < 2; ++rt)
        #pragma unroll
        for (int tt = 0; tt < 4; ++tt) acc[rt][tt] = (f32x4){0.f, 0.f, 0.f, 0.f};
    for (int ci = 0; ci < 32; ++ci) {
        int c = c0 + ci;
        half8 A0h = *(const half8*)(HTP + paddr(ta, 512, c, L, 0));
        half8 A1h = *(const half8*)(HTP + paddr(ta + 1, 512, c, L, 0));
        #pragma unroll
        for (int tt = 0; tt < 4; ++tt) {
            half8 Bh = *(const half8*)(HTP + paddr(tb + tt, 512, c, L, 0));
            acc[0][tt] = MFMA16(A0h, Bh, acc[0][tt]);
            acc[1][tt] = MFMA16(A1h, Bh, acc[1][tt]);
        }
    }
    float s = 0.f;
    #pragma unroll
    for (int rt = 0; rt < 2; ++rt)
        #pragma unroll
        for (int tt = 0; tt < 4; ++tt)
            #pragma unroll
            for (int r = 0; r < 4; ++r)
                s += acc[rt][tt][r] * G[(size_t)(m0 + rt * 16 + quad * 4 + r) * KN
                                        + n0 + tt * 16 + lane16];
    sf[t] = s;
    __syncthreads();
    for (int st = 256; st > 0; st >>= 1) {
        if (t < st) sf[t] += sf[t + st];
        __syncthreads();
    }
    if (t == 0) atomicAdd(diffsum, sf[0]);
}

// ---------------------------------------------------------------------------
// Finalize: offsets = exclusive scan(counts); perplexity; diff (+ ||bf2||^2).
// ---------------------------------------------------------------------------
__global__ __launch_bounds__(512) void finalize_kernel(const int* __restrict__ counts,
                                                       int* __restrict__ offsets,
                                                       const float* __restrict__ diffsum,
                                                       const float* __restrict__ colsum,
                                                       const float* __restrict__ w0,
                                                       const float* __restrict__ bf2,
                                                       float* __restrict__ out_diff,
                                                       float* __restrict__ out_perp) {
    __shared__ int   sc[512];
    __shared__ float sf[512];
    int t = threadIdx.x;
    int c = counts[t];
    sc[t] = c;
    double p = (double)c / (double)BN;
    double term = -p * log(p + 1e-10);
    float dotp = colsum[t] * w0[t];
    float bbp = 0.f;
    for (int d = t; d < ED; d += 512) { float v = bf2[d]; bbp = fmaf(v, v, bbp); }
    __syncthreads();
    int off = 0;
    for (int k = 0; k < t; ++k) off += sc[k];
    offsets[t] = off;
    sf[t] = dotp; __syncthreads();
    for (int s = 256; s > 0; s >>= 1) { if (t < s) sf[t] += sf[t + s]; __syncthreads(); }
    float dot_all = sf[0];
    __syncthreads();
    sf[t] = bbp; __syncthreads();
    for (int s = 256; s > 0; s >>= 1) { if (t < s) sf[t] += sf[t + s]; __syncthreads(); }
    float bb = sf[0];
    __syncthreads();
    sf[t] = (float)term; __syncthreads();
    for (int s = 256; s > 0; s >>= 1) { if (t < s) sf[t] += sf[t + s]; __syncthreads(); }
    if (t == 0) {
        *out_perp = expf(sf[0]);
        *out_diff = (diffsum[0] + 2.f * dot_all + (float)BN * bb) /
                    ((float)BN * (float)ED);
    }
}

// ---------------------------------------------------------------------------
// Scatter, block-aggregated: one global atomic per (block, expert) instead of
// per sample (hot-expert serialization fix).
// ---------------------------------------------------------------------------
__global__ __launch_bounds__(256) void scatter_kernel(const int* __restrict__ ind,
                                                      const int* __restrict__ offsets,
                                                      int* __restrict__ cursors,
                                                      int* __restrict__ perm) {
    __shared__ int lcount[KN], lbase[KN], lcur[KN];
    int t = threadIdx.x;
    for (int i = t; i < KN; i += 256) { lcount[i] = 0; lcur[i] = 0; }
    __syncthreads();
    int b = blockIdx.x * 256 + t;
    int k = ind[b];
    atomicAdd(&lcount[k], 1);
    __syncthreads();
    for (int i = t; i < KN; i += 256) {
        int c = lcount[i];
        if (c > 0) lbase[i] = atomicAdd(&cursors[i], c);
    }
    __syncthreads();
    int pos = offsets[k] + lbase[k] + atomicAdd(&lcur[k], 1);
    perm[pos] = b;
}

// ---------------------------------------------------------------------------
// Decoder: one wave per sample (load-balanced under histogram skew).
// ---------------------------------------------------------------------------
__global__ __launch_bounds__(256) void decode_kernel(const float* __restrict__ EX,
                                                     const int* __restrict__ perm,
                                                     const int* __restrict__ ind,
                                                     const float* __restrict__ W1,
                                                     const float* __restrict__ b1,
                                                     const float* __restrict__ W2,
                                                     const float* __restrict__ b2,
                                                     float* __restrict__ dec) {
    __shared__ float exs[4][DIN];
    __shared__ float h2s[4][DH];
    int t = threadIdx.x;
    int w = t >> 6, l = t & 63;
    int s = blockIdx.x * 4 + w;
    int b = perm[s];
    int k = ind[b];
    exs[w][l] = EX[(size_t)b * DIN + l];
    __syncthreads();
    const float* w1 = W1 + (size_t)k * (DIN * DH);
    float h = b1[(size_t)k * DH + l];
    #pragma unroll
    for (int j = 0; j < DIN; ++j)
        h = fmaf(exs[w][j], w1[(size_t)j * DH + l], h);
    h2s[w][l] = fmaxf(h, 0.f);
    __syncthreads();
    if (l < DY) {
        const float* w2 = W2 + (size_t)k * (DH * DY);
        float d = b2[(size_t)k * DY + l];
        #pragma unroll
        for (int j = 0; j < DH; ++j)
            d = fmaf(h2s[w][j], w2[(size_t)j * DY + l], d);
        dec[(size_t)b * DY + l] = d;
    }
}

// ---------------------------------------------------------------------------
extern "C" void kernel_launch(void* const* d_in, const int* in_sizes, int n_in,
                              void* d_out, int out_size, void* d_ws, size_t ws_size,
                              hipStream_t stream) {
    const float* x     = (const float*)d_in[0];
    const float* Wf1   = (const float*)d_in[1];
    const float* bf1   = (const float*)d_in[2];
    const float* Wf2   = (const float*)d_in[3];
    const float* bf2   = (const float*)d_in[4];
    const float* Wx1   = (const float*)d_in[5];
    const float* bx1   = (const float*)d_in[6];
    const float* Wx2   = (const float*)d_in[7];
    const float* bx2   = (const float*)d_in[8];
    const float* embed = (const float*)d_in[9];
    const float* W1    = (const float*)d_in[10];
    const float* b1    = (const float*)d_in[11];
    const float* W2    = (const float*)d_in[12];
    const float* b2    = (const float*)d_in[13];
    float* out = (float*)d_out;

    char* ws = (char*)d_ws;
    size_t off = 0;
    auto carve = [&](size_t bytes) -> void* {
        void* p = ws + off;
        off += (bytes + 255) & ~(size_t)255;
        return p;
    };
    _Float16* XPs   = (_Float16*)carve((size_t)BN * INC * 2);    // 4.2 MB
    _Float16* XPl   = (_Float16*)carve((size_t)BN * INC * 2);
    _Float16* WfxPs = (_Float16*)carve((size_t)1024 * INC * 2);
    _Float16* WfxPl = (_Float16*)carve((size_t)1024 * INC * 2);
    float*    bfx   = (float*)carve(1024 * 4);
    _Float16* Wx2Ps = (_Float16*)carve((size_t)DIN * CH * 2);
    _Float16* Wx2Pl = (_Float16*)carve((size_t)DIN * CH * 2);
    _Float16* WfPs  = (_Float16*)carve((size_t)CH * ED * 2);     // 6.4 MB
    _Float16* WfPl  = (_Float16*)carve((size_t)CH * ED * 2);
    _Float16* EmPs  = (_Float16*)carve((size_t)KN * ED * 2);
    _Float16* EmPl  = (_Float16*)carve((size_t)KN * ED * 2);
    // Union region: {WeP[16] + GP[16]} (33.6 MB, dead after gred) overlaps
    // {HPs + HPl + HTP} (50.4 MB, written later by enc1).
    char* un = (char*)carve((size_t)3 * BN * CH * 2);            // 50.4 MB
    float*    WeP = (float*)un;
    float*    GP  = (float*)(un + (size_t)16 * KN * KN * 4);
    _Float16* HPs = (_Float16*)un;
    _Float16* HPl = (_Float16*)(un + (size_t)BN * CH * 2);
    _Float16* HTP = (_Float16*)(un + (size_t)BN * CH * 4);
    _Float16* WePs = (_Float16*)carve((size_t)KN * CH * 2);
    _Float16* WePl = (_Float16*)carve((size_t)KN * CH * 2);
    float*    G    = (float*)carve((size_t)KN * KN * 4);
    float*    EX   = (float*)carve((size_t)BN * DIN * 4);        // 4.2 MB
    float*    s2p  = (float*)carve(8 * KN * 4);
    float*    bep  = (float*)carve(8 * KN * 4);
    float*    s2   = (float*)carve(KN * 4);
    float*    be   = (float*)carve(KN * 4);
    char* zbase = ws + off;                                      // ---- zero region ----
    float* w0    = (float*)carve(CH * 4);
    float* colsum= (float*)carve(CH * 4);
    int*   counts= (int*)carve(KN * 4);
    int*   cursors=(int*)carve(KN * 4);
    float* diffsum=(float*)carve(256);
    size_t zbytes = (size_t)(ws + off - zbase);                  // ---- end zero region ----
    int*   ind     = (int*)carve(BN * 4);
    int*   offsets = (int*)carve(KN * 4);
    int*   perm    = (int*)carve(BN * 4);
    (void)in_sizes; (void)n_in; (void)out_size; (void)ws_size;

    hipMemsetAsync(zbase, 0, zbytes, stream);
    xpack_kernel<<<BN / 32, 256, 0, stream>>>(x, XPs, XPl);
    wfxpack_kernel<<<64, 256, 0, stream>>>(Wf1, Wx1, bf1, bx1, WfxPs, WfxPl, bfx);
    wx2pack_kernel<<<4, 256, 0, stream>>>(Wx2, Wx2Ps, Wx2Pl);
    splitwf2_kernel<<<dim3(NCW, 64), 256, 0, stream>>>(Wf2, bf2, WfPs, WfPl, w0);
    embt_kernel<<<dim3(NCW, 16), 256, 0, stream>>>(embed, EmPs, EmPl);
    s2bep_kernel<<<dim3(16, 8), 256, 0, stream>>>(embed, bf2, s2p, bep);
    sbered_kernel<<<1, 512, 0, stream>>>(s2p, bep, s2, be);
    mfma3_kernel<<<dim3(4, 4, 16), 512, 0, stream>>>(WfPs, WfPl, EmPs, EmPl, WeP, NCW);
    mfma1_kernel<<<dim3(4, 4, 16), 512, 0, stream>>>(WfPs, WfPs, GP, NCW);
    wepack_kernel<<<KN * KN / 256, 256, 0, stream>>>(WeP, WePs, WePl);
    gred_kernel<<<KN * KN / 256, 256, 0, stream>>>(GP, G);
    enc1_kernel<<<dim3(BN / 32, 2), 512, 0, stream>>>(XPs, XPl, WfxPs, WfxPl, bfx,
                                                      Wx2Ps, Wx2Pl, bx2,
                                                      HPs, HPl, HTP, colsum, EX);
    score_kernel<<<BN / 32, 512, 0, stream>>>(HPs, HPl, WePs, WePl, s2, be,
                                              ind, out + OUT_IND, counts, diffsum);
    hth_kernel<<<dim3(4, 4, 16), 512, 0, stream>>>(HTP, G, diffsum);
    finalize_kernel<<<1, 512, 0, stream>>>(counts, offsets, diffsum, colsum, w0, bf2,
                                           out + OUT_DIFF, out + OUT_PERP);
    scatter_kernel<<<BN / 256, 256, 0, stream>>>(ind, offsets, cursors, perm);
    decode_kernel<<<BN / 4, 256, 0, stream>>>(EX, perm, ind, W1, b1, W2, b2,
                                              out + OUT_DEC);
}

// Round 8
// 413.148 us; speedup vs baseline: 5.0139x; 1.0456x over previous
//
#include <hip/hip_runtime.h>
#include <math.h>

// Problem constants
#define BN     16384
#define INC    128
#define CH     512
#define ED     6240
#define KN     512      // NUM_EMB
#define DIN    64
#define DH     64
#define DY     32
#define NCW    195      // ED/32 k-chunks for Wf2/embed packing

// d_out layout (float32): dec[16384*32] | diff[1] | embed_ind[16384] | perplexity[1]
#define OUT_DEC   0
#define OUT_DIFF  (BN*DY)
#define OUT_IND   (BN*DY + 1)
#define OUT_PERP  (BN*DY + 1 + BN)

typedef _Float16 half8 __attribute__((ext_vector_type(8)));
typedef float    f32x4 __attribute__((ext_vector_type(4)));
#define MFMA16(a, b, c) __builtin_amdgcn_mfma_f32_16x16x32_f16(a, b, c, 0, 0, 0)

// Packed fragment-tile layout: element (row r within 16-row tile `tile`,
// k-dim index d) lives at ((tile*NC + d/32)*64 + ((d%32)/8)*16 + (r%16))*8 + d%8.
// One wave-load of half8 at lane L = contiguous 1KB = one full MFMA fragment.
__device__ __forceinline__ size_t paddr(int tile, int NC, int c, int lane, int e) {
    return ((size_t)(tile * NC + c) * 64 + lane) * 8 + e;
}

// ---------------------------------------------------------------------------
// Pack x [BN][128] fp32 -> XPs/XPl packed hi/lo (A-side, NC=4)
// ---------------------------------------------------------------------------
__global__ __launch_bounds__(256) void xpack_kernel(const float* __restrict__ x,
                                                    _Float16* __restrict__ XPs,
                                                    _Float16* __restrict__ XPl) {
    __shared__ float xt[32][INC];
    int t = threadIdx.x;
    int m0 = blockIdx.x * 32;
    for (int i = t; i < 32 * (INC / 4); i += 256) {
        int row = i >> 5, c4 = (i & 31) << 2;
        *(float4*)&xt[row][c4] = *(const float4*)&x[(size_t)(m0 + row) * INC + c4];
    }
    __syncthreads();
    int ta = m0 >> 4;
    #pragma unroll
    for (int i = 0; i < 2; ++i) {
        int idx = t + 256 * i;              // 0..511
        int tile2 = idx >> 8;               // 0..1
        int c = (idx >> 6) & 3;
        int lane = idx & 63;
        int m = tile2 * 16 + (lane & 15);
        int d0 = c * 32 + ((lane >> 4) << 3);
        half8 hh, ll;
        #pragma unroll
        for (int e = 0; e < 8; ++e) {
            float v = xt[m][d0 + e];
            _Float16 hi = (_Float16)v;
            hh[e] = hi;
            ll[e] = (_Float16)(v - (float)hi);
        }
        *(half8*)(XPs + paddr(ta + tile2, 4, c, lane, 0)) = hh;
        *(half8*)(XPl + paddr(ta + tile2, 4, c, lane, 0)) = ll;
    }
}

// ---------------------------------------------------------------------------
// Pack fused Wf1|Wx1 cols (n<512 -> Wf1 col n; else Wx1 col n-512) to B-side
// frag layout (NC=4). Also bfx = concat(bf1, bx1).
// ---------------------------------------------------------------------------
__global__ __launch_bounds__(256) void wfxpack_kernel(const float* __restrict__ Wf1,
                                                      const float* __restrict__ Wx1,
                                                      const float* __restrict__ bf1,
                                                      const float* __restrict__ bx1,
                                                      _Float16* __restrict__ WfxPs,
                                                      _Float16* __restrict__ WfxPl,
                                                      float* __restrict__ bfx) {
    int t = threadIdx.x;
    int tile = blockIdx.x;                  // 0..63
    for (int i = t; i < 2048; i += 256) {
        int c = i >> 9, lane = (i >> 3) & 63, e = i & 7;
        int n = tile * 16 + (lane & 15);
        int d = c * 32 + ((lane >> 4) << 3) + e;
        float v = (n < 512) ? Wf1[(size_t)d * CH + n] : Wx1[(size_t)d * CH + n - 512];
        _Float16 hi = (_Float16)v;
        size_t a = paddr(tile, 4, c, lane, e);
        WfxPs[a] = hi;
        WfxPl[a] = (_Float16)(v - (float)hi);
    }
    if (blockIdx.x == 0)
        for (int j = t; j < 512; j += 256) { bfx[j] = bf1[j]; bfx[512 + j] = bx1[j]; }
}

// ---------------------------------------------------------------------------
// Pack Wx2 [512][64] -> B-side frag layout (4 tiles, NC=16), hi/lo
// ---------------------------------------------------------------------------
__global__ __launch_bounds__(256) void wx2pack_kernel(const float* __restrict__ Wx2,
                                                      _Float16* __restrict__ Ps,
                                                      _Float16* __restrict__ Pl) {
    int t = threadIdx.x;
    int tile = blockIdx.x;                  // 0..3
    for (int i = t; i < 8192; i += 256) {
        int c = i >> 9, lane = (i >> 3) & 63, e = i & 7;
        int n = tile * 16 + (lane & 15);
        int d = c * 32 + ((lane >> 4) << 3) + e;
        float v = Wx2[(size_t)d * DIN + n];
        _Float16 hi = (_Float16)v;
        size_t a = paddr(tile, 16, c, lane, e);
        Ps[a] = hi;
        Pl[a] = (_Float16)(v - (float)hi);
    }
}

// ---------------------------------------------------------------------------
// Split Wf2 [512][6240] fp32 -> packed fp16 hi/lo (frag layout, NC=195).
// Folded: w0[j] += Wf2[j,:].bf2 partials (atomic — feeds only loose-tol diff).
// ---------------------------------------------------------------------------
__global__ __launch_bounds__(256) void splitwf2_kernel(const float* __restrict__ Wf2,
                                                       const float* __restrict__ bf2,
                                                       _Float16* __restrict__ WfPs,
                                                       _Float16* __restrict__ WfPl,
                                                       float* __restrict__ w0) {
    __shared__ float red[8][33];
    int t = threadIdx.x;
    int d = blockIdx.x * 32 + (t & 31);
    int j = blockIdx.y * 8 + (t >> 5);
    float v = Wf2[(size_t)j * ED + d];
    _Float16 hi = (_Float16)v;
    size_t a = paddr(j >> 4, NCW, d >> 5, ((d & 31) >> 3) * 16 + (j & 15), d & 7);
    WfPs[a] = hi;
    WfPl[a] = (_Float16)(v - (float)hi);
    red[t >> 5][t & 31] = v * bf2[d];
    __syncthreads();
    if (t < 8) {
        float s = 0.f;
        #pragma unroll
        for (int i = 0; i < 32; ++i) s += red[t][i];
        atomicAdd(&w0[blockIdx.y * 8 + t], s);
    }
}

// ---------------------------------------------------------------------------
// Transpose+split embed [6240][512] -> packed fp16 hi/lo (rows=codewords).
// Pure pack — s2/be computed deterministically in s2bep/sbered.
// ---------------------------------------------------------------------------
__global__ __launch_bounds__(256) void embt_kernel(const float* __restrict__ embed,
                                                   _Float16* __restrict__ EmPs,
                                                   _Float16* __restrict__ EmPl) {
    __shared__ float tile[32][33];
    int t = threadIdx.x;
    int dl = t >> 5, kl = t & 31;
    #pragma unroll
    for (int r = 0; r < 4; ++r)
        tile[dl + 8 * r][kl] = embed[(size_t)(blockIdx.x * 32 + dl + 8 * r) * KN
                                     + blockIdx.y * 32 + kl];
    __syncthreads();
    int d = blockIdx.x * 32 + kl;
    #pragma unroll
    for (int r = 0; r < 4; ++r) {
        int k = blockIdx.y * 32 + dl + 8 * r;
        float v = tile[kl][dl + 8 * r];
        _Float16 hi = (_Float16)v;
        size_t a = paddr(k >> 4, NCW, d >> 5, ((d & 31) >> 3) * 16 + (k & 15), d & 7);
        EmPs[a] = hi;
        EmPl[a] = (_Float16)(v - (float)hi);
    }
}

// ---------------------------------------------------------------------------
// DETERMINISTIC s2/be partials: grid (16,8). Block = 32 k's x 780 d's.
// Fixed-order in-block reduction, plain stores (no atomics).
// ---------------------------------------------------------------------------
__global__ __launch_bounds__(256) void s2bep_kernel(const float* __restrict__ embed,
                                                    const float* __restrict__ bf2,
                                                    float* __restrict__ s2p,
                                                    float* __restrict__ bep) {
    __shared__ float rs[8][33], rb[8][33];
    int t = threadIdx.x;
    int kl = t & 31, dl = t >> 5;
    int kb = blockIdx.x * 32;
    int d0 = blockIdx.y * 780;
    float s = 0.f, b = 0.f;
    for (int d = d0 + dl; d < d0 + 780; d += 8) {
        float e = embed[(size_t)d * KN + kb + kl];
        s = fmaf(e, e, s);
        b = fmaf(bf2[d], e, b);
    }
    rs[dl][kl] = s; rb[dl][kl] = b;
    __syncthreads();
    if (t < 32) {
        float ss = 0.f, bb = 0.f;
        #pragma unroll
        for (int i = 0; i < 8; ++i) { ss += rs[i][t]; bb += rb[i][t]; }
        s2p[blockIdx.y * KN + kb + t] = ss;
        bep[blockIdx.y * KN + kb + t] = bb;
    }
}

// Deterministic final reduce: s2[k], be[k] from 8 partials in fixed order.
__global__ __launch_bounds__(512) void sbered_kernel(const float* __restrict__ s2p,
                                                     const float* __restrict__ bep,
                                                     float* __restrict__ s2,
                                                     float* __restrict__ be) {
    int k = threadIdx.x;
    float s = 0.f, b = 0.f;
    #pragma unroll
    for (int y = 0; y < 8; ++y) {
        s += s2p[y * KN + k];
        b += bep[y * KN + k];
    }
    s2[k] = s;
    be[k] = b;
}

// ---------------------------------------------------------------------------
// 3-pass split-fp16 MFMA GEMM -> per-z partial C. grid (4,4,16), block 512.
// Block tile 128x128; wave (mi=w&3, ni=w>>2) covers 32 rows x 64 cols.
// ---------------------------------------------------------------------------
__global__ __launch_bounds__(512) void mfma3_kernel(const _Float16* __restrict__ As,
                                                    const _Float16* __restrict__ Al,
                                                    const _Float16* __restrict__ Bs,
                                                    const _Float16* __restrict__ Bl,
                                                    float* __restrict__ Cp, int NC) {
    int t = threadIdx.x;
    int w = t >> 6, L = t & 63;
    int lane16 = L & 15, quad = L >> 4;
    int m0 = blockIdx.x * 128 + (w & 3) * 32;
    int n0 = blockIdx.y * 128 + (w >> 2) * 64;
    int ta = m0 >> 4, tb = n0 >> 4;
    int z = blockIdx.z;
    int base = NC / 16, rem = NC % 16;
    int c0 = z * base + (z < rem ? z : rem);
    int cnt = base + (z < rem ? 1 : 0);
    f32x4 acc[2][4];
    #pragma unroll
    for (int rt = 0; rt < 2; ++rt)
        #pragma unroll
        for (int tt = 0; tt < 4; ++tt) acc[rt][tt] = (f32x4){0.f, 0.f, 0.f, 0.f};
    for (int ci = 0; ci < cnt; ++ci) {
        int c = c0 + ci;
        size_t oa0 = paddr(ta, NC, c, L, 0), oa1 = paddr(ta + 1, NC, c, L, 0);
        half8 A0h = *(const half8*)(As + oa0);
        half8 A0l = *(const half8*)(Al + oa0);
        half8 A1h = *(const half8*)(As + oa1);
        half8 A1l = *(const half8*)(Al + oa1);
        #pragma unroll
        for (int tt = 0; tt < 4; ++tt) {
            size_t ob = paddr(tb + tt, NC, c, L, 0);
            half8 Bh = *(const half8*)(Bs + ob);
            half8 Bl8 = *(const half8*)(Bl + ob);
            acc[0][tt] = MFMA16(A0h, Bl8, MFMA16(A0l, Bh, MFMA16(A0h, Bh, acc[0][tt])));
            acc[1][tt] = MFMA16(A1h, Bl8, MFMA16(A1l, Bh, MFMA16(A1h, Bh, acc[1][tt])));
        }
    }
    float* C = Cp + (size_t)z * KN * KN;
    #pragma unroll
    for (int rt = 0; rt < 2; ++rt)
        #pragma unroll
        for (int tt = 0; tt < 4; ++tt)
            #pragma unroll
            for (int r = 0; r < 4; ++r)
                C[(size_t)(m0 + rt * 16 + quad * 4 + r) * KN
                  + n0 + tt * 16 + lane16] = acc[rt][tt][r];
}

// 1-pass variant -> per-z partial C (for G)
__global__ __launch_bounds__(512) void mfma1_kernel(const _Float16* __restrict__ As,
                                                    const _Float16* __restrict__ Bs,
                                                    float* __restrict__ Cp, int NC) {
    int t = threadIdx.x;
    int w = t >> 6, L = t & 63;
    int lane16 = L & 15, quad = L >> 4;
    int m0 = blockIdx.x * 128 + (w & 3) * 32;
    int n0 = blockIdx.y * 128 + (w >> 2) * 64;
    int ta = m0 >> 4, tb = n0 >> 4;
    int z = blockIdx.z;
    int base = NC / 16, rem = NC % 16;
    int c0 = z * base + (z < rem ? z : rem);
    int cnt = base + (z < rem ? 1 : 0);
    f32x4 acc[2][4];
    #pragma unroll
    for (int rt = 0; rt < 2; ++rt)
        #pragma unroll
        for (int tt = 0; tt < 4; ++tt) acc[rt][tt] = (f32x4){0.f, 0.f, 0.f, 0.f};
    for (int ci = 0; ci < cnt; ++ci) {
        int c = c0 + ci;
        half8 A0h = *(const half8*)(As + paddr(ta, NC, c, L, 0));
        half8 A1h = *(const half8*)(As + paddr(ta + 1, NC, c, L, 0));
        #pragma unroll
        for (int tt = 0; tt < 4; ++tt) {
            half8 Bh = *(const half8*)(Bs + paddr(tb + tt, NC, c, L, 0));
            acc[0][tt] = MFMA16(A0h, Bh, acc[0][tt]);
            acc[1][tt] = MFMA16(A1h, Bh, acc[1][tt]);
        }
    }
    float* C = Cp + (size_t)z * KN * KN;
    #pragma unroll
    for (int rt = 0; rt < 2; ++rt)
        #pragma unroll
        for (int tt = 0; tt < 4; ++tt)
            #pragma unroll
            for (int r = 0; r < 4; ++r)
                C[(size_t)(m0 + rt * 16 + quad * 4 + r) * KN
                  + n0 + tt * 16 + lane16] = acc[rt][tt][r];
}

// ---------------------------------------------------------------------------
// Reduce 16 We partials (fixed order — deterministic) + transpose-pack to
// B-side hi/lo frags (NC=16)
// ---------------------------------------------------------------------------
__global__ __launch_bounds__(256) void wepack_kernel(const float* __restrict__ WeP,
                                                     _Float16* __restrict__ WePs,
                                                     _Float16* __restrict__ WePl) {
    int g = blockIdx.x * 256 + threadIdx.x;      // j*512 + k
    int j = g >> 9, k = g & 511;
    float v = 0.f;
    #pragma unroll
    for (int z = 0; z < 16; ++z) v += WeP[(size_t)z * KN * KN + g];
    _Float16 hi = (_Float16)v;
    size_t a = paddr(k >> 4, 16, j >> 5, ((j & 31) >> 3) * 16 + (k & 15), j & 7);
    WePs[a] = hi;
    WePl[a] = (_Float16)(v - (float)hi);
}

// Reduce 16 G partials -> G fp32
__global__ __launch_bounds__(256) void gred_kernel(const float* __restrict__ GP,
                                                   float* __restrict__ G) {
    int g = blockIdx.x * 256 + threadIdx.x;
    float v = 0.f;
    #pragma unroll
    for (int z = 0; z < 16; ++z) v += GP[(size_t)z * KN * KN + g];
    G[g] = v;
}

// ---------------------------------------------------------------------------
// Fused MFMA encoder: grid (BN/32, 2), block 512 (8 waves x 64 cols = 512 cols).
// y=0: h=relu(x@Wf1+bf1) -> packed HPs/HPl (A-side), HTP (hi), colsum.
// y=1: hx=relu(x@Wx1+bx1) staged in LDS -> EX = hx@Wx2+bx2 via 2nd MFMA stage.
// ---------------------------------------------------------------------------
__global__ __launch_bounds__(512) void enc1_kernel(
        const _Float16* __restrict__ XPs, const _Float16* __restrict__ XPl,
        const _Float16* __restrict__ WfxPs, const _Float16* __restrict__ WfxPl,
        const float* __restrict__ bfx,
        const _Float16* __restrict__ Wx2Ps, const _Float16* __restrict__ Wx2Pl,
        const float* __restrict__ bx2,
        _Float16* __restrict__ HPs, _Float16* __restrict__ HPl,
        _Float16* __restrict__ HTP,
        float* __restrict__ colsum, float* __restrict__ EX) {
    __shared__ _Float16 hhi[32][CH];   // 32 KB
    __shared__ _Float16 hlo[32][CH];   // 32 KB
    int t = threadIdx.x;
    int w = t >> 6, L = t & 63;
    int l16 = L & 15, quad = L >> 4;
    int m0 = blockIdx.x * 32;
    int ta = m0 >> 4;
    int enc = blockIdx.y;
    int n0 = enc * 512 + w * 64;
    int tb = n0 >> 4;
    f32x4 acc[2][4];
    #pragma unroll
    for (int rt = 0; rt < 2; ++rt)
        #pragma unroll
        for (int tt = 0; tt < 4; ++tt) acc[rt][tt] = (f32x4){0.f, 0.f, 0.f, 0.f};
    #pragma unroll
    for (int c = 0; c < 4; ++c) {
        size_t oa0 = paddr(ta, 4, c, L, 0), oa1 = paddr(ta + 1, 4, c, L, 0);
        half8 A0h = *(const half8*)(XPs + oa0);
        half8 A0l = *(const half8*)(XPl + oa0);
        half8 A1h = *(const half8*)(XPs + oa1);
        half8 A1l = *(const half8*)(XPl + oa1);
        #pragma unroll
        for (int tt = 0; tt < 4; ++tt) {
            size_t ob = paddr(tb + tt, 4, c, L, 0);
            half8 Bh = *(const half8*)(WfxPs + ob);
            half8 Bl8 = *(const half8*)(WfxPl + ob);
            acc[0][tt] = MFMA16(A0h, Bl8, MFMA16(A0l, Bh, MFMA16(A0h, Bh, acc[0][tt])));
            acc[1][tt] = MFMA16(A1h, Bl8, MFMA16(A1l, Bh, MFMA16(A1h, Bh, acc[1][tt])));
        }
    }
    #pragma unroll
    for (int rt = 0; rt < 2; ++rt)
        #pragma unroll
        for (int tt = 0; tt < 4; ++tt) {
            int col = w * 64 + tt * 16 + l16;
            float bias = bfx[enc * 512 + col];
            #pragma unroll
            for (int r = 0; r < 4; ++r) {
                int row = rt * 16 + quad * 4 + r;
                float v = fmaxf(acc[rt][tt][r] + bias, 0.f);
                _Float16 hi = (_Float16)v;
                hhi[row][col] = hi;
                hlo[row][col] = (_Float16)(v - (float)hi);
            }
        }
    __syncthreads();
    if (enc == 0) {
        float s = 0.f;
        #pragma unroll
        for (int r = 0; r < 32; ++r) s += (float)hhi[r][t] + (float)hlo[r][t];
        atomicAdd(&colsum[t], s);
        #pragma unroll
        for (int i = 0; i < 4; ++i) {
            int idx = t + 512 * i;                // 0..2047
            int tile2 = idx >> 10;
            int c = (idx >> 6) & 15;
            int lane = idx & 63;
            int m = tile2 * 16 + (lane & 15);
            int d0 = c * 32 + ((lane >> 4) << 3);
            *(half8*)(HPs + paddr(ta + tile2, 16, c, lane, 0)) = *(half8*)(&hhi[m][d0]);
            *(half8*)(HPl + paddr(ta + tile2, 16, c, lane, 0)) = *(half8*)(&hlo[m][d0]);
        }
        int cb = blockIdx.x;                      // sample chunk for HTP
        #pragma unroll
        for (int i = 0; i < 4; ++i) {
            int idx = t + 512 * i;
            int chtile = idx >> 6;
            int lane = idx & 63;
            int ch = chtile * 16 + (lane & 15);
            int b0 = (lane >> 4) << 3;
            half8 hh;
            #pragma unroll
            for (int e = 0; e < 8; ++e) hh[e] = hhi[b0 + e][ch];
            *(half8*)(HTP + paddr(chtile, 512, cb, lane, 0)) = hh;
        }
    } else {
        int rt = w & 1, ct = w >> 1;
        f32x4 eacc = (f32x4){0.f, 0.f, 0.f, 0.f};
        for (int c = 0; c < 16; ++c) {
            int d0 = c * 32 + (quad << 3);
            int m = rt * 16 + l16;
            half8 Ah = *(half8*)(&hhi[m][d0]);
            half8 Al = *(half8*)(&hlo[m][d0]);
            size_t ob = paddr(ct, 16, c, L, 0);
            half8 Bh = *(const half8*)(Wx2Ps + ob);
            half8 Bl8 = *(const half8*)(Wx2Pl + ob);
            eacc = MFMA16(Ah, Bl8, MFMA16(Al, Bh, MFMA16(Ah, Bh, eacc)));
        }
        int col = ct * 16 + l16;
        float bias = bx2[col];
        #pragma unroll
        for (int r = 0; r < 4; ++r) {
            int row = m0 + rt * 16 + quad * 4 + r;
            EX[(size_t)row * DIN + col] = eacc[r] + bias;
        }
    }
}

// ---------------------------------------------------------------------------
// Score/argmin v3 (R8): one block (512 thr, 8 waves) covers 64 samples x ALL
// 512 cols; wave = 4 A-tiles x 4 B-tiles (48 MFMA / 16 loads per chunk —
// R7's 32-row version was 24/12 and 89% stalled at MfmaUtil 11%).
// g_k = 0.5*s2[k]-be[k]-h.We[:,k]; 3-pass split; argmin in-block
// (tie -> lowest k, matching np.argmin). Also accumulates sum(2*g_min).
// ---------------------------------------------------------------------------
__global__ __launch_bounds__(512) void score_kernel(
        const _Float16* __restrict__ HPs, const _Float16* __restrict__ HPl,
        const _Float16* __restrict__ WePs, const _Float16* __restrict__ WePl,
        const float* __restrict__ s2, const float* __restrict__ be,
        int* __restrict__ ind, float* __restrict__ out_ind,
        int* __restrict__ counts, float* __restrict__ diffsum) {
    __shared__ float redv[8][64];
    __shared__ int   redi[8][64];
    __shared__ float fin[64];
    int t = threadIdx.x;
    int w = t >> 6, L = t & 63;
    int l16 = L & 15, quad = L >> 4;
    int m0 = blockIdx.x * 64;
    int ta = m0 >> 4;                 // 4 A tiles: ta..ta+3
    int colbase = w * 64;
    int tb = w * 4;
    float cks[4];
    #pragma unroll
    for (int tt = 0; tt < 4; ++tt) {
        int c = colbase + tt * 16 + l16;
        cks[tt] = 0.5f * s2[c] - be[c];
    }
    f32x4 acc[4][4];
    #pragma unroll
    for (int at = 0; at < 4; ++at)
        #pragma unroll
        for (int tt = 0; tt < 4; ++tt) acc[at][tt] = (f32x4){0.f, 0.f, 0.f, 0.f};
    for (int c = 0; c < 16; ++c) {
        half8 Ah[4], Al[4], Bh[4], Bl[4];
        #pragma unroll
        for (int at = 0; at < 4; ++at) {
            size_t oa = paddr(ta + at, 16, c, L, 0);
            Ah[at] = *(const half8*)(HPs + oa);
            Al[at] = *(const half8*)(HPl + oa);
        }
        #pragma unroll
        for (int tt = 0; tt < 4; ++tt) {
            size_t ob = paddr(tb + tt, 16, c, L, 0);
            Bh[tt] = *(const half8*)(WePs + ob);
            Bl[tt] = *(const half8*)(WePl + ob);
        }
        #pragma unroll
        for (int at = 0; at < 4; ++at)
            #pragma unroll
            for (int tt = 0; tt < 4; ++tt)
                acc[at][tt] = MFMA16(Ah[at], Bl[tt],
                              MFMA16(Al[at], Bh[tt],
                              MFMA16(Ah[at], Bh[tt], acc[at][tt])));
    }
    #pragma unroll
    for (int at = 0; at < 4; ++at) {
        #pragma unroll
        for (int r = 0; r < 4; ++r) {
            float mv = cks[0] - acc[at][0][r];
            int mi = colbase + l16;
            #pragma unroll
            for (int tt = 1; tt < 4; ++tt) {
                float v = cks[tt] - acc[at][tt][r];
                int c = colbase + tt * 16 + l16;
                if (v < mv || (v == mv && c < mi)) { mv = v; mi = c; }
            }
            #pragma unroll
            for (int d = 1; d < 16; d <<= 1) {
                float ov = __shfl_xor(mv, d);
                int oi = __shfl_xor(mi, d);
                if (ov < mv || (ov == mv && oi < mi)) { mv = ov; mi = oi; }
            }
            if (l16 == 0) {
                int row = at * 16 + quad * 4 + r;
                redv[w][row] = mv; redi[w][row] = mi;
            }
        }
    }
    __syncthreads();
    if (t < 64) {
        float mv = redv[0][t]; int mi = redi[0][t];
        #pragma unroll
        for (int w2 = 1; w2 < 8; ++w2) {
            float ov = redv[w2][t]; int oi = redi[w2][t];
            if (ov < mv || (ov == mv && oi < mi)) { mv = ov; mi = oi; }
        }
        int b = m0 + t;
        ind[b] = mi;
        out_ind[b] = (float)mi;
        atomicAdd(&counts[mi], 1);
        fin[t] = 2.f * mv;
    }
    __syncthreads();
    if (t == 0) {
        float s = 0.f;
        #pragma unroll
        for (int i = 0; i < 64; ++i) s += fin[i];
        atomicAdd(diffsum, s);
    }
}

// ---------------------------------------------------------------------------
// diffsum += sum(H^T H o G), tile-wise, no HtH materialization.
// grid (4,4,32), block 512; wave covers 32x64 of the 128x128 tile.
// (R8: z 16->32 — 512 blocks for latency hiding on the K=16384 stream.)
// ---------------------------------------------------------------------------
__global__ __launch_bounds__(512) void hth_kernel(const _Float16* __restrict__ HTP,
                                                  const float* __restrict__ G,
                                                  float* __restrict__ diffsum) {
    __shared__ float sf[512];
    int t = threadIdx.x;
    int w = t >> 6, L = t & 63;
    int lane16 = L & 15, quad = L >> 4;
    int m0 = blockIdx.x * 128 + (w & 3) * 32;
    int n0 = blockIdx.y * 128 + (w >> 2) * 64;
    int ta = m0 >> 4, tb = n0 >> 4;
    int c0 = blockIdx.z * 16;
    f32x4 acc[2][4];
    #pragma unroll
    for (int rt = 0; rt < 2; ++rt)
        #pragma unroll
        for (int tt = 0; tt < 4; ++tt) acc[rt][tt] = (f32x4){0.f, 0.f, 0.f, 0.f};
    for (int ci = 0; ci < 16; ++ci) {
        int c = c0 + ci;
        half8 A0h = *(const half8*)(HTP + paddr(ta, 512, c, L, 0));
        half8 A1h = *(const half8*)(HTP + paddr(ta + 1, 512, c, L, 0));
        #pragma unroll
        for (int tt = 0; tt < 4; ++tt) {
            half8 Bh = *(const half8*)(HTP + paddr(tb + tt, 512, c, L, 0));
            acc[0][tt] = MFMA16(A0h, Bh, acc[0][tt]);
            acc[1][tt] = MFMA16(A1h, Bh, acc[1][tt]);
        }
    }
    float s = 0.f;
    #pragma unroll
    for (int rt = 0; rt < 2; ++rt)
        #pragma unroll
        for (int tt = 0; tt < 4; ++tt)
            #pragma unroll
            for (int r = 0; r < 4; ++r)
                s += acc[rt][tt][r] * G[(size_t)(m0 + rt * 16 + quad * 4 + r) * KN
                                        + n0 + tt * 16 + lane16];
    sf[t] = s;
    __syncthreads();
    for (int st = 256; st > 0; st >>= 1) {
        if (t < st) sf[t] += sf[t + st];
        __syncthreads();
    }
    if (t == 0) atomicAdd(diffsum, sf[0]);
}

// ---------------------------------------------------------------------------
// Finalize: offsets = exclusive scan(counts); perplexity; diff (+ ||bf2||^2).
// ---------------------------------------------------------------------------
__global__ __launch_bounds__(512) void finalize_kernel(const int* __restrict__ counts,
                                                       int* __restrict__ offsets,
                                                       const float* __restrict__ diffsum,
                                                       const float* __restrict__ colsum,
                                                       const float* __restrict__ w0,
                                                       const float* __restrict__ bf2,
                                                       float* __restrict__ out_diff,
                                                       float* __restrict__ out_perp) {
    __shared__ int   sc[512];
    __shared__ float sf[512];
    int t = threadIdx.x;
    int c = counts[t];
    sc[t] = c;
    double p = (double)c / (double)BN;
    double term = -p * log(p + 1e-10);
    float dotp = colsum[t] * w0[t];
    float bbp = 0.f;
    for (int d = t; d < ED; d += 512) { float v = bf2[d]; bbp = fmaf(v, v, bbp); }
    __syncthreads();
    int off = 0;
    for (int k = 0; k < t; ++k) off += sc[k];
    offsets[t] = off;
    sf[t] = dotp; __syncthreads();
    for (int s = 256; s > 0; s >>= 1) { if (t < s) sf[t] += sf[t + s]; __syncthreads(); }
    float dot_all = sf[0];
    __syncthreads();
    sf[t] = bbp; __syncthreads();
    for (int s = 256; s > 0; s >>= 1) { if (t < s) sf[t] += sf[t + s]; __syncthreads(); }
    float bb = sf[0];
    __syncthreads();
    sf[t] = (float)term; __syncthreads();
    for (int s = 256; s > 0; s >>= 1) { if (t < s) sf[t] += sf[t + s]; __syncthreads(); }
    if (t == 0) {
        *out_perp = expf(sf[0]);
        *out_diff = (diffsum[0] + 2.f * dot_all + (float)BN * bb) /
                    ((float)BN * (float)ED);
    }
}

// ---------------------------------------------------------------------------
// Scatter, block-aggregated: one global atomic per (block, expert) instead of
// per sample (hot-expert serialization fix).
// ---------------------------------------------------------------------------
__global__ __launch_bounds__(256) void scatter_kernel(const int* __restrict__ ind,
                                                      const int* __restrict__ offsets,
                                                      int* __restrict__ cursors,
                                                      int* __restrict__ perm) {
    __shared__ int lcount[KN], lbase[KN], lcur[KN];
    int t = threadIdx.x;
    for (int i = t; i < KN; i += 256) { lcount[i] = 0; lcur[i] = 0; }
    __syncthreads();
    int b = blockIdx.x * 256 + t;
    int k = ind[b];
    atomicAdd(&lcount[k], 1);
    __syncthreads();
    for (int i = t; i < KN; i += 256) {
        int c = lcount[i];
        if (c > 0) lbase[i] = atomicAdd(&cursors[i], c);
    }
    __syncthreads();
    int pos = offsets[k] + lbase[k] + atomicAdd(&lcur[k], 1);
    perm[pos] = b;
}

// ---------------------------------------------------------------------------
// Decoder: one wave per sample (load-balanced under histogram skew).
// ---------------------------------------------------------------------------
__global__ __launch_bounds__(256) void decode_kernel(const float* __restrict__ EX,
                                                     const int* __restrict__ perm,
                                                     const int* __restrict__ ind,
                                                     const float* __restrict__ W1,
                                                     const float* __restrict__ b1,
                                                     const float* __restrict__ W2,
                                                     const float* __restrict__ b2,
                                                     float* __restrict__ dec) {
    __shared__ float exs[4][DIN];
    __shared__ float h2s[4][DH];
    int t = threadIdx.x;
    int w = t >> 6, l = t & 63;
    int s = blockIdx.x * 4 + w;
    int b = perm[s];
    int k = ind[b];
    exs[w][l] = EX[(size_t)b * DIN + l];
    __syncthreads();
    const float* w1 = W1 + (size_t)k * (DIN * DH);
    float h = b1[(size_t)k * DH + l];
    #pragma unroll
    for (int j = 0; j < DIN; ++j)
        h = fmaf(exs[w][j], w1[(size_t)j * DH + l], h);
    h2s[w][l] = fmaxf(h, 0.f);
    __syncthreads();
    if (l < DY) {
        const float* w2 = W2 + (size_t)k * (DH * DY);
        float d = b2[(size_t)k * DY + l];
        #pragma unroll
        for (int j = 0; j < DH; ++j)
            d = fmaf(h2s[w][j], w2[(size_t)j * DY + l], d);
        dec[(size_t)b * DY + l] = d;
    }
}

// ---------------------------------------------------------------------------
extern "C" void kernel_launch(void* const* d_in, const int* in_sizes, int n_in,
                              void* d_out, int out_size, void* d_ws, size_t ws_size,
                              hipStream_t stream) {
    const float* x     = (const float*)d_in[0];
    const float* Wf1   = (const float*)d_in[1];
    const float* bf1   = (const float*)d_in[2];
    const float* Wf2   = (const float*)d_in[3];
    const float* bf2   = (const float*)d_in[4];
    const float* Wx1   = (const float*)d_in[5];
    const float* bx1   = (const float*)d_in[6];
    const float* Wx2   = (const float*)d_in[7];
    const float* bx2   = (const float*)d_in[8];
    const float* embed = (const float*)d_in[9];
    const float* W1    = (const float*)d_in[10];
    const float* b1    = (const float*)d_in[11];
    const float* W2    = (const float*)d_in[12];
    const float* b2    = (const float*)d_in[13];
    float* out = (float*)d_out;

    char* ws = (char*)d_ws;
    size_t off = 0;
    auto carve = [&](size_t bytes) -> void* {
        void* p = ws + off;
        off += (bytes + 255) & ~(size_t)255;
        return p;
    };
    _Float16* XPs   = (_Float16*)carve((size_t)BN * INC * 2);    // 4.2 MB
    _Float16* XPl   = (_Float16*)carve((size_t)BN * INC * 2);
    _Float16* WfxPs = (_Float16*)carve((size_t)1024 * INC * 2);
    _Float16* WfxPl = (_Float16*)carve((size_t)1024 * INC * 2);
    float*    bfx   = (float*)carve(1024 * 4);
    _Float16* Wx2Ps = (_Float16*)carve((size_t)DIN * CH * 2);
    _Float16* Wx2Pl = (_Float16*)carve((size_t)DIN * CH * 2);
    _Float16* WfPs  = (_Float16*)carve((size_t)CH * ED * 2);     // 6.4 MB
    _Float16* WfPl  = (_Float16*)carve((size_t)CH * ED * 2);
    _Float16* EmPs  = (_Float16*)carve((size_t)KN * ED * 2);
    _Float16* EmPl  = (_Float16*)carve((size_t)KN * ED * 2);
    // Union region: {WeP[16] + GP[16]} (33.6 MB, dead after gred) overlaps
    // {HPs + HPl + HTP} (50.4 MB, written later by enc1).
    char* un = (char*)carve((size_t)3 * BN * CH * 2);            // 50.4 MB
    float*    WeP = (float*)un;
    float*    GP  = (float*)(un + (size_t)16 * KN * KN * 4);
    _Float16* HPs = (_Float16*)un;
    _Float16* HPl = (_Float16*)(un + (size_t)BN * CH * 2);
    _Float16* HTP = (_Float16*)(un + (size_t)BN * CH * 4);
    _Float16* WePs = (_Float16*)carve((size_t)KN * CH * 2);
    _Float16* WePl = (_Float16*)carve((size_t)KN * CH * 2);
    float*    G    = (float*)carve((size_t)KN * KN * 4);
    float*    EX   = (float*)carve((size_t)BN * DIN * 4);        // 4.2 MB
    float*    s2p  = (float*)carve(8 * KN * 4);
    float*    bep  = (float*)carve(8 * KN * 4);
    float*    s2   = (float*)carve(KN * 4);
    float*    be   = (float*)carve(KN * 4);
    char* zbase = ws + off;                                      // ---- zero region ----
    float* w0    = (float*)carve(CH * 4);
    float* colsum= (float*)carve(CH * 4);
    int*   counts= (int*)carve(KN * 4);
    int*   cursors=(int*)carve(KN * 4);
    float* diffsum=(float*)carve(256);
    size_t zbytes = (size_t)(ws + off - zbase);                  // ---- end zero region ----
    int*   ind     = (int*)carve(BN * 4);
    int*   offsets = (int*)carve(KN * 4);
    int*   perm    = (int*)carve(BN * 4);
    (void)in_sizes; (void)n_in; (void)out_size; (void)ws_size;

    hipMemsetAsync(zbase, 0, zbytes, stream);
    xpack_kernel<<<BN / 32, 256, 0, stream>>>(x, XPs, XPl);
    wfxpack_kernel<<<64, 256, 0, stream>>>(Wf1, Wx1, bf1, bx1, WfxPs, WfxPl, bfx);
    wx2pack_kernel<<<4, 256, 0, stream>>>(Wx2, Wx2Ps, Wx2Pl);
    splitwf2_kernel<<<dim3(NCW, 64), 256, 0, stream>>>(Wf2, bf2, WfPs, WfPl, w0);
    embt_kernel<<<dim3(NCW, 16), 256, 0, stream>>>(embed, EmPs, EmPl);
    s2bep_kernel<<<dim3(16, 8), 256, 0, stream>>>(embed, bf2, s2p, bep);
    sbered_kernel<<<1, 512, 0, stream>>>(s2p, bep, s2, be);
    mfma3_kernel<<<dim3(4, 4, 16), 512, 0, stream>>>(WfPs, WfPl, EmPs, EmPl, WeP, NCW);
    mfma1_kernel<<<dim3(4, 4, 16), 512, 0, stream>>>(WfPs, WfPs, GP, NCW);
    wepack_kernel<<<KN * KN / 256, 256, 0, stream>>>(WeP, WePs, WePl);
    gred_kernel<<<KN * KN / 256, 256, 0, stream>>>(GP, G);
    enc1_kernel<<<dim3(BN / 32, 2), 512, 0, stream>>>(XPs, XPl, WfxPs, WfxPl, bfx,
                                                      Wx2Ps, Wx2Pl, bx2,
                                                      HPs, HPl, HTP, colsum, EX);
    score_kernel<<<BN / 64, 512, 0, stream>>>(HPs, HPl, WePs, WePl, s2, be,
                                              ind, out + OUT_IND, counts, diffsum);
    hth_kernel<<<dim3(4, 4, 32), 512, 0, stream>>>(HTP, G, diffsum);
    finalize_kernel<<<1, 512, 0, stream>>>(counts, offsets, diffsum, colsum, w0, bf2,
                                           out + OUT_DIFF, out + OUT_PERP);
    scatter_kernel<<<BN / 256, 256, 0, stream>>>(ind, offsets, cursors, perm);
    decode_kernel<<<BN / 4, 256, 0, stream>>>(EX, perm, ind, W1, b1, W2, b2,
                                              out + OUT_DEC);
}

// Round 9
// 380.022 us; speedup vs baseline: 5.4510x; 1.0872x over previous
//
#include <hip/hip_runtime.h>
#include <math.h>

// Problem constants
#define BN     16384
#define INC    128
#define CH     512
#define ED     6240
#define KN     512      // NUM_EMB
#define DIN    64
#define DH     64
#define DY     32
#define NCW    195      // ED/32 k-chunks for Wf2/embed packing
#define CHP    (CH + 8) // padded LDS row stride (halves): 16B-aligned, kills
                        // the 16-way bank conflict on row-stride-1024 A reads

// d_out layout (float32): dec[16384*32] | diff[1] | embed_ind[16384] | perplexity[1]
#define OUT_DEC   0
#define OUT_DIFF  (BN*DY)
#define OUT_IND   (BN*DY + 1)
#define OUT_PERP  (BN*DY + 1 + BN)

typedef _Float16 half8 __attribute__((ext_vector_type(8)));
typedef float    f32x4 __attribute__((ext_vector_type(4)));
#define MFMA16(a, b, c) __builtin_amdgcn_mfma_f32_16x16x32_f16(a, b, c, 0, 0, 0)

// Packed fragment-tile layout: element (row r within 16-row tile `tile`,
// k-dim index d) lives at ((tile*NC + d/32)*64 + ((d%32)/8)*16 + (r%16))*8 + d%8.
// One wave-load of half8 at lane L = contiguous 1KB = one full MFMA fragment.
__device__ __forceinline__ size_t paddr(int tile, int NC, int c, int lane, int e) {
    return ((size_t)(tile * NC + c) * 64 + lane) * 8 + e;
}

// ---------------------------------------------------------------------------
// Pack x [BN][128] fp32 -> XPs/XPl packed hi/lo (A-side, NC=4)
// ---------------------------------------------------------------------------
__global__ __launch_bounds__(256) void xpack_kernel(const float* __restrict__ x,
                                                    _Float16* __restrict__ XPs,
                                                    _Float16* __restrict__ XPl) {
    __shared__ float xt[32][INC];
    int t = threadIdx.x;
    int m0 = blockIdx.x * 32;
    for (int i = t; i < 32 * (INC / 4); i += 256) {
        int row = i >> 5, c4 = (i & 31) << 2;
        *(float4*)&xt[row][c4] = *(const float4*)&x[(size_t)(m0 + row) * INC + c4];
    }
    __syncthreads();
    int ta = m0 >> 4;
    #pragma unroll
    for (int i = 0; i < 2; ++i) {
        int idx = t + 256 * i;              // 0..511
        int tile2 = idx >> 8;               // 0..1
        int c = (idx >> 6) & 3;
        int lane = idx & 63;
        int m = tile2 * 16 + (lane & 15);
        int d0 = c * 32 + ((lane >> 4) << 3);
        half8 hh, ll;
        #pragma unroll
        for (int e = 0; e < 8; ++e) {
            float v = xt[m][d0 + e];
            _Float16 hi = (_Float16)v;
            hh[e] = hi;
            ll[e] = (_Float16)(v - (float)hi);
        }
        *(half8*)(XPs + paddr(ta + tile2, 4, c, lane, 0)) = hh;
        *(half8*)(XPl + paddr(ta + tile2, 4, c, lane, 0)) = ll;
    }
}

// ---------------------------------------------------------------------------
// Pack fused Wf1|Wx1 cols (n<512 -> Wf1 col n; else Wx1 col n-512) to B-side
// frag layout (NC=4). Also bfx = concat(bf1, bx1).
// ---------------------------------------------------------------------------
__global__ __launch_bounds__(256) void wfxpack_kernel(const float* __restrict__ Wf1,
                                                      const float* __restrict__ Wx1,
                                                      const float* __restrict__ bf1,
                                                      const float* __restrict__ bx1,
                                                      _Float16* __restrict__ WfxPs,
                                                      _Float16* __restrict__ WfxPl,
                                                      float* __restrict__ bfx) {
    int t = threadIdx.x;
    int tile = blockIdx.x;                  // 0..63
    for (int i = t; i < 2048; i += 256) {
        int c = i >> 9, lane = (i >> 3) & 63, e = i & 7;
        int n = tile * 16 + (lane & 15);
        int d = c * 32 + ((lane >> 4) << 3) + e;
        float v = (n < 512) ? Wf1[(size_t)d * CH + n] : Wx1[(size_t)d * CH + n - 512];
        _Float16 hi = (_Float16)v;
        size_t a = paddr(tile, 4, c, lane, e);
        WfxPs[a] = hi;
        WfxPl[a] = (_Float16)(v - (float)hi);
    }
    if (blockIdx.x == 0)
        for (int j = t; j < 512; j += 256) { bfx[j] = bf1[j]; bfx[512 + j] = bx1[j]; }
}

// ---------------------------------------------------------------------------
// Pack Wx2 [512][64] -> B-side frag layout (4 tiles, NC=16), hi/lo
// ---------------------------------------------------------------------------
__global__ __launch_bounds__(256) void wx2pack_kernel(const float* __restrict__ Wx2,
                                                      _Float16* __restrict__ Ps,
                                                      _Float16* __restrict__ Pl) {
    int t = threadIdx.x;
    int tile = blockIdx.x;                  // 0..3
    for (int i = t; i < 8192; i += 256) {
        int c = i >> 9, lane = (i >> 3) & 63, e = i & 7;
        int n = tile * 16 + (lane & 15);
        int d = c * 32 + ((lane >> 4) << 3) + e;
        float v = Wx2[(size_t)d * DIN + n];
        _Float16 hi = (_Float16)v;
        size_t a = paddr(tile, 16, c, lane, e);
        Ps[a] = hi;
        Pl[a] = (_Float16)(v - (float)hi);
    }
}

// ---------------------------------------------------------------------------
// Split Wf2 [512][6240] fp32 -> packed fp16 hi/lo (frag layout, NC=195).
// Folded: w0[j] += Wf2[j,:].bf2 partials (atomic — feeds only loose-tol diff).
// ---------------------------------------------------------------------------
__global__ __launch_bounds__(256) void splitwf2_kernel(const float* __restrict__ Wf2,
                                                       const float* __restrict__ bf2,
                                                       _Float16* __restrict__ WfPs,
                                                       _Float16* __restrict__ WfPl,
                                                       float* __restrict__ w0) {
    __shared__ float red[8][33];
    int t = threadIdx.x;
    int d = blockIdx.x * 32 + (t & 31);
    int j = blockIdx.y * 8 + (t >> 5);
    float v = Wf2[(size_t)j * ED + d];
    _Float16 hi = (_Float16)v;
    size_t a = paddr(j >> 4, NCW, d >> 5, ((d & 31) >> 3) * 16 + (j & 15), d & 7);
    WfPs[a] = hi;
    WfPl[a] = (_Float16)(v - (float)hi);
    red[t >> 5][t & 31] = v * bf2[d];
    __syncthreads();
    if (t < 8) {
        float s = 0.f;
        #pragma unroll
        for (int i = 0; i < 32; ++i) s += red[t][i];
        atomicAdd(&w0[blockIdx.y * 8 + t], s);
    }
}

// ---------------------------------------------------------------------------
// Transpose+split embed [6240][512] -> packed fp16 hi/lo (rows=codewords).
// Pure pack — s2/be computed deterministically in s2bep/sbered.
// ---------------------------------------------------------------------------
__global__ __launch_bounds__(256) void embt_kernel(const float* __restrict__ embed,
                                                   _Float16* __restrict__ EmPs,
                                                   _Float16* __restrict__ EmPl) {
    __shared__ float tile[32][33];
    int t = threadIdx.x;
    int dl = t >> 5, kl = t & 31;
    #pragma unroll
    for (int r = 0; r < 4; ++r)
        tile[dl + 8 * r][kl] = embed[(size_t)(blockIdx.x * 32 + dl + 8 * r) * KN
                                     + blockIdx.y * 32 + kl];
    __syncthreads();
    int d = blockIdx.x * 32 + kl;
    #pragma unroll
    for (int r = 0; r < 4; ++r) {
        int k = blockIdx.y * 32 + dl + 8 * r;
        float v = tile[kl][dl + 8 * r];
        _Float16 hi = (_Float16)v;
        size_t a = paddr(k >> 4, NCW, d >> 5, ((d & 31) >> 3) * 16 + (k & 15), d & 7);
        EmPs[a] = hi;
        EmPl[a] = (_Float16)(v - (float)hi);
    }
}

// ---------------------------------------------------------------------------
// DETERMINISTIC s2/be partials: grid (16,8). Block = 32 k's x 780 d's.
// Fixed-order in-block reduction, plain stores (no atomics).
// ---------------------------------------------------------------------------
__global__ __launch_bounds__(256) void s2bep_kernel(const float* __restrict__ embed,
                                                    const float* __restrict__ bf2,
                                                    float* __restrict__ s2p,
                                                    float* __restrict__ bep) {
    __shared__ float rs[8][33], rb[8][33];
    int t = threadIdx.x;
    int kl = t & 31, dl = t >> 5;
    int kb = blockIdx.x * 32;
    int d0 = blockIdx.y * 780;
    float s = 0.f, b = 0.f;
    for (int d = d0 + dl; d < d0 + 780; d += 8) {
        float e = embed[(size_t)d * KN + kb + kl];
        s = fmaf(e, e, s);
        b = fmaf(bf2[d], e, b);
    }
    rs[dl][kl] = s; rb[dl][kl] = b;
    __syncthreads();
    if (t < 32) {
        float ss = 0.f, bb = 0.f;
        #pragma unroll
        for (int i = 0; i < 8; ++i) { ss += rs[i][t]; bb += rb[i][t]; }
        s2p[blockIdx.y * KN + kb + t] = ss;
        bep[blockIdx.y * KN + kb + t] = bb;
    }
}

// Deterministic final reduce: s2[k], be[k] from 8 partials in fixed order.
__global__ __launch_bounds__(512) void sbered_kernel(const float* __restrict__ s2p,
                                                     const float* __restrict__ bep,
                                                     float* __restrict__ s2,
                                                     float* __restrict__ be) {
    int k = threadIdx.x;
    float s = 0.f, b = 0.f;
    #pragma unroll
    for (int y = 0; y < 8; ++y) {
        s += s2p[y * KN + k];
        b += bep[y * KN + k];
    }
    s2[k] = s;
    be[k] = b;
}

// ---------------------------------------------------------------------------
// 3-pass split-fp16 MFMA GEMM -> per-z partial C. grid (4,4,16), block 512.
// Block tile 128x128; wave (mi=w&3, ni=w>>2) covers 32 rows x 64 cols.
// ---------------------------------------------------------------------------
__global__ __launch_bounds__(512) void mfma3_kernel(const _Float16* __restrict__ As,
                                                    const _Float16* __restrict__ Al,
                                                    const _Float16* __restrict__ Bs,
                                                    const _Float16* __restrict__ Bl,
                                                    float* __restrict__ Cp, int NC) {
    int t = threadIdx.x;
    int w = t >> 6, L = t & 63;
    int lane16 = L & 15, quad = L >> 4;
    int m0 = blockIdx.x * 128 + (w & 3) * 32;
    int n0 = blockIdx.y * 128 + (w >> 2) * 64;
    int ta = m0 >> 4, tb = n0 >> 4;
    int z = blockIdx.z;
    int base = NC / 16, rem = NC % 16;
    int c0 = z * base + (z < rem ? z : rem);
    int cnt = base + (z < rem ? 1 : 0);
    f32x4 acc[2][4];
    #pragma unroll
    for (int rt = 0; rt < 2; ++rt)
        #pragma unroll
        for (int tt = 0; tt < 4; ++tt) acc[rt][tt] = (f32x4){0.f, 0.f, 0.f, 0.f};
    for (int ci = 0; ci < cnt; ++ci) {
        int c = c0 + ci;
        size_t oa0 = paddr(ta, NC, c, L, 0), oa1 = paddr(ta + 1, NC, c, L, 0);
        half8 A0h = *(const half8*)(As + oa0);
        half8 A0l = *(const half8*)(Al + oa0);
        half8 A1h = *(const half8*)(As + oa1);
        half8 A1l = *(const half8*)(Al + oa1);
        #pragma unroll
        for (int tt = 0; tt < 4; ++tt) {
            size_t ob = paddr(tb + tt, NC, c, L, 0);
            half8 Bh = *(const half8*)(Bs + ob);
            half8 Bl8 = *(const half8*)(Bl + ob);
            acc[0][tt] = MFMA16(A0h, Bl8, MFMA16(A0l, Bh, MFMA16(A0h, Bh, acc[0][tt])));
            acc[1][tt] = MFMA16(A1h, Bl8, MFMA16(A1l, Bh, MFMA16(A1h, Bh, acc[1][tt])));
        }
    }
    float* C = Cp + (size_t)z * KN * KN;
    #pragma unroll
    for (int rt = 0; rt < 2; ++rt)
        #pragma unroll
        for (int tt = 0; tt < 4; ++tt)
            #pragma unroll
            for (int r = 0; r < 4; ++r)
                C[(size_t)(m0 + rt * 16 + quad * 4 + r) * KN
                  + n0 + tt * 16 + lane16] = acc[rt][tt][r];
}

// 1-pass variant -> per-z partial C (for G)
__global__ __launch_bounds__(512) void mfma1_kernel(const _Float16* __restrict__ As,
                                                    const _Float16* __restrict__ Bs,
                                                    float* __restrict__ Cp, int NC) {
    int t = threadIdx.x;
    int w = t >> 6, L = t & 63;
    int lane16 = L & 15, quad = L >> 4;
    int m0 = blockIdx.x * 128 + (w & 3) * 32;
    int n0 = blockIdx.y * 128 + (w >> 2) * 64;
    int ta = m0 >> 4, tb = n0 >> 4;
    int z = blockIdx.z;
    int base = NC / 16, rem = NC % 16;
    int c0 = z * base + (z < rem ? z : rem);
    int cnt = base + (z < rem ? 1 : 0);
    f32x4 acc[2][4];
    #pragma unroll
    for (int rt = 0; rt < 2; ++rt)
        #pragma unroll
        for (int tt = 0; tt < 4; ++tt) acc[rt][tt] = (f32x4){0.f, 0.f, 0.f, 0.f};
    for (int ci = 0; ci < cnt; ++ci) {
        int c = c0 + ci;
        half8 A0h = *(const half8*)(As + paddr(ta, NC, c, L, 0));
        half8 A1h = *(const half8*)(As + paddr(ta + 1, NC, c, L, 0));
        #pragma unroll
        for (int tt = 0; tt < 4; ++tt) {
            half8 Bh = *(const half8*)(Bs + paddr(tb + tt, NC, c, L, 0));
            acc[0][tt] = MFMA16(A0h, Bh, acc[0][tt]);
            acc[1][tt] = MFMA16(A1h, Bh, acc[1][tt]);
        }
    }
    float* C = Cp + (size_t)z * KN * KN;
    #pragma unroll
    for (int rt = 0; rt < 2; ++rt)
        #pragma unroll
        for (int tt = 0; tt < 4; ++tt)
            #pragma unroll
            for (int r = 0; r < 4; ++r)
                C[(size_t)(m0 + rt * 16 + quad * 4 + r) * KN
                  + n0 + tt * 16 + lane16] = acc[rt][tt][r];
}

// ---------------------------------------------------------------------------
// Reduce 16 We partials (fixed order — deterministic) + transpose-pack to
// B-side hi/lo frags (NC=16)
// ---------------------------------------------------------------------------
__global__ __launch_bounds__(256) void wepack_kernel(const float* __restrict__ WeP,
                                                     _Float16* __restrict__ WePs,
                                                     _Float16* __restrict__ WePl) {
    int g = blockIdx.x * 256 + threadIdx.x;      // j*512 + k
    int j = g >> 9, k = g & 511;
    float v = 0.f;
    #pragma unroll
    for (int z = 0; z < 16; ++z) v += WeP[(size_t)z * KN * KN + g];
    _Float16 hi = (_Float16)v;
    size_t a = paddr(k >> 4, 16, j >> 5, ((j & 31) >> 3) * 16 + (k & 15), j & 7);
    WePs[a] = hi;
    WePl[a] = (_Float16)(v - (float)hi);
}

// Reduce 16 G partials -> G fp32
__global__ __launch_bounds__(256) void gred_kernel(const float* __restrict__ GP,
                                                   float* __restrict__ G) {
    int g = blockIdx.x * 256 + threadIdx.x;
    float v = 0.f;
    #pragma unroll
    for (int z = 0; z < 16; ++z) v += GP[(size_t)z * KN * KN + g];
    G[g] = v;
}

// ---------------------------------------------------------------------------
// Fused MFMA encoder + SCORE (R9): grid (BN/32, 2), block 512.
// y=0: h=relu(x@Wf1+bf1) -> LDS (hi/lo, padded) -> colsum, HTP pack, then the
//      score GEMM h.We straight from LDS (A via ds_read_b128, B=WePs/WePl from
//      L2) + in-block argmin over all 512 cols. H never round-trips HBM —
//      R8's score read 21 MB of evicted H at 259 GB/s = its entire 84 us.
// y=1: hx=relu(x@Wx1+bx1) -> LDS -> EX = hx@Wx2+bx2 via 2nd MFMA stage.
// ---------------------------------------------------------------------------
__global__ __launch_bounds__(512) void enc1_kernel(
        const _Float16* __restrict__ XPs, const _Float16* __restrict__ XPl,
        const _Float16* __restrict__ WfxPs, const _Float16* __restrict__ WfxPl,
        const float* __restrict__ bfx,
        const _Float16* __restrict__ Wx2Ps, const _Float16* __restrict__ Wx2Pl,
        const float* __restrict__ bx2,
        const _Float16* __restrict__ WePs, const _Float16* __restrict__ WePl,
        const float* __restrict__ s2, const float* __restrict__ be,
        _Float16* __restrict__ HTP, float* __restrict__ colsum,
        float* __restrict__ EX,
        int* __restrict__ ind, float* __restrict__ out_ind,
        int* __restrict__ counts, float* __restrict__ diffsum) {
    __shared__ _Float16 hhi[32][CHP];   // 33.3 KB (padded: A-frag ds_read 2-way)
    __shared__ _Float16 hlo[32][CHP];
    __shared__ float redv[8][32];
    __shared__ int   redi[8][32];
    __shared__ float fin[32];
    int t = threadIdx.x;
    int w = t >> 6, L = t & 63;
    int l16 = L & 15, quad = L >> 4;
    int m0 = blockIdx.x * 32;
    int ta = m0 >> 4;
    int enc = blockIdx.y;
    int n0 = enc * 512 + w * 64;
    int tb = n0 >> 4;
    f32x4 acc[2][4];
    #pragma unroll
    for (int rt = 0; rt < 2; ++rt)
        #pragma unroll
        for (int tt = 0; tt < 4; ++tt) acc[rt][tt] = (f32x4){0.f, 0.f, 0.f, 0.f};
    #pragma unroll
    for (int c = 0; c < 4; ++c) {
        size_t oa0 = paddr(ta, 4, c, L, 0), oa1 = paddr(ta + 1, 4, c, L, 0);
        half8 A0h = *(const half8*)(XPs + oa0);
        half8 A0l = *(const half8*)(XPl + oa0);
        half8 A1h = *(const half8*)(XPs + oa1);
        half8 A1l = *(const half8*)(XPl + oa1);
        #pragma unroll
        for (int tt = 0; tt < 4; ++tt) {
            size_t ob = paddr(tb + tt, 4, c, L, 0);
            half8 Bh = *(const half8*)(WfxPs + ob);
            half8 Bl8 = *(const half8*)(WfxPl + ob);
            acc[0][tt] = MFMA16(A0h, Bl8, MFMA16(A0l, Bh, MFMA16(A0h, Bh, acc[0][tt])));
            acc[1][tt] = MFMA16(A1h, Bl8, MFMA16(A1l, Bh, MFMA16(A1h, Bh, acc[1][tt])));
        }
    }
    #pragma unroll
    for (int rt = 0; rt < 2; ++rt)
        #pragma unroll
        for (int tt = 0; tt < 4; ++tt) {
            int col = w * 64 + tt * 16 + l16;
            float bias = bfx[enc * 512 + col];
            #pragma unroll
            for (int r = 0; r < 4; ++r) {
                int row = rt * 16 + quad * 4 + r;
                float v = fmaxf(acc[rt][tt][r] + bias, 0.f);
                _Float16 hi = (_Float16)v;
                hhi[row][col] = hi;
                hlo[row][col] = (_Float16)(v - (float)hi);
            }
        }
    __syncthreads();
    if (enc == 0) {
        float s = 0.f;
        #pragma unroll
        for (int r = 0; r < 32; ++r) s += (float)hhi[r][t] + (float)hlo[r][t];
        atomicAdd(&colsum[t], s);
        int cb = blockIdx.x;                      // sample chunk for HTP
        #pragma unroll
        for (int i = 0; i < 4; ++i) {
            int idx = t + 512 * i;
            int chtile = idx >> 6;
            int lane = idx & 63;
            int ch = chtile * 16 + (lane & 15);
            int b0 = (lane >> 4) << 3;
            half8 hh;
            #pragma unroll
            for (int e = 0; e < 8; ++e) hh[e] = hhi[b0 + e][ch];
            *(half8*)(HTP + paddr(chtile, 512, cb, lane, 0)) = hh;
        }
        // ---- fused score: g_k = 0.5*s2[k]-be[k]-h.We[:,k], wave w owns
        // cols [64w,64w+64); A frags from LDS, 3-pass split ----
        int colbase = w * 64;
        int tbs = w * 4;
        float cks[4];
        #pragma unroll
        for (int tt = 0; tt < 4; ++tt) {
            int c = colbase + tt * 16 + l16;
            cks[tt] = 0.5f * s2[c] - be[c];
        }
        #pragma unroll
        for (int rt = 0; rt < 2; ++rt)
            #pragma unroll
            for (int tt = 0; tt < 4; ++tt) acc[rt][tt] = (f32x4){0.f, 0.f, 0.f, 0.f};
        for (int c = 0; c < 16; ++c) {
            int d0 = c * 32 + (quad << 3);
            int mA0 = l16, mA1 = 16 + l16;
            half8 A0h = *(const half8*)(&hhi[mA0][d0]);
            half8 A0l = *(const half8*)(&hlo[mA0][d0]);
            half8 A1h = *(const half8*)(&hhi[mA1][d0]);
            half8 A1l = *(const half8*)(&hlo[mA1][d0]);
            #pragma unroll
            for (int tt = 0; tt < 4; ++tt) {
                size_t ob = paddr(tbs + tt, 16, c, L, 0);
                half8 Bh = *(const half8*)(WePs + ob);
                half8 Bl8 = *(const half8*)(WePl + ob);
                acc[0][tt] = MFMA16(A0h, Bl8, MFMA16(A0l, Bh, MFMA16(A0h, Bh, acc[0][tt])));
                acc[1][tt] = MFMA16(A1h, Bl8, MFMA16(A1l, Bh, MFMA16(A1h, Bh, acc[1][tt])));
            }
        }
        #pragma unroll
        for (int rt = 0; rt < 2; ++rt) {
            #pragma unroll
            for (int r = 0; r < 4; ++r) {
                float mv = cks[0] - acc[rt][0][r];
                int mi = colbase + l16;
                #pragma unroll
                for (int tt = 1; tt < 4; ++tt) {
                    float v = cks[tt] - acc[rt][tt][r];
                    int c = colbase + tt * 16 + l16;
                    if (v < mv || (v == mv && c < mi)) { mv = v; mi = c; }
                }
                #pragma unroll
                for (int d = 1; d < 16; d <<= 1) {
                    float ov = __shfl_xor(mv, d);
                    int oi = __shfl_xor(mi, d);
                    if (ov < mv || (ov == mv && oi < mi)) { mv = ov; mi = oi; }
                }
                if (l16 == 0) {
                    int row = rt * 16 + quad * 4 + r;
                    redv[w][row] = mv; redi[w][row] = mi;
                }
            }
        }
        __syncthreads();
        if (t < 32) {
            float mv = redv[0][t]; int mi = redi[0][t];
            #pragma unroll
            for (int w2 = 1; w2 < 8; ++w2) {
                float ov = redv[w2][t]; int oi = redi[w2][t];
                if (ov < mv || (ov == mv && oi < mi)) { mv = ov; mi = oi; }
            }
            int b = m0 + t;
            ind[b] = mi;
            out_ind[b] = (float)mi;
            atomicAdd(&counts[mi], 1);
            fin[t] = 2.f * mv;
        }
        __syncthreads();
        if (t == 0) {
            float s = 0.f;
            #pragma unroll
            for (int i = 0; i < 32; ++i) s += fin[i];
            atomicAdd(diffsum, s);
        }
    } else {
        int rt = w & 1, ct = w >> 1;
        f32x4 eacc = (f32x4){0.f, 0.f, 0.f, 0.f};
        for (int c = 0; c < 16; ++c) {
            int d0 = c * 32 + (quad << 3);
            int m = rt * 16 + l16;
            half8 Ah = *(half8*)(&hhi[m][d0]);
            half8 Al = *(half8*)(&hlo[m][d0]);
            size_t ob = paddr(ct, 16, c, L, 0);
            half8 Bh = *(const half8*)(Wx2Ps + ob);
            half8 Bl8 = *(const half8*)(Wx2Pl + ob);
            eacc = MFMA16(Ah, Bl8, MFMA16(Al, Bh, MFMA16(Ah, Bh, eacc)));
        }
        int col = ct * 16 + l16;
        float bias = bx2[col];
        #pragma unroll
        for (int r = 0; r < 4; ++r) {
            int row = m0 + rt * 16 + quad * 4 + r;
            EX[(size_t)row * DIN + col] = eacc[r] + bias;
        }
    }
}

// ---------------------------------------------------------------------------
// diffsum += sum(H^T H o G), tile-wise, no HtH materialization.
// grid (4,4,32), block 512; wave covers 32x64 of the 128x128 tile.
// ---------------------------------------------------------------------------
__global__ __launch_bounds__(512) void hth_kernel(const _Float16* __restrict__ HTP,
                                                  const float* __restrict__ G,
                                                  float* __restrict__ diffsum) {
    __shared__ float sf[512];
    int t = threadIdx.x;
    int w = t >> 6, L = t & 63;
    int lane16 = L & 15, quad = L >> 4;
    int m0 = blockIdx.x * 128 + (w & 3) * 32;
    int n0 = blockIdx.y * 128 + (w >> 2) * 64;
    int ta = m0 >> 4, tb = n0 >> 4;
    int c0 = blockIdx.z * 16;
    f32x4 acc[2][4];
    #pragma unroll
    for (int rt = 0; rt < 2; ++rt)
        #pragma unroll
        for (int tt = 0; tt < 4; ++tt) acc[rt][tt] = (f32x4){0.f, 0.f, 0.f, 0.f};
    for (int ci = 0; ci < 16; ++ci) {
        int c = c0 + ci;
        half8 A0h = *(const half8*)(HTP + paddr(ta, 512, c, L, 0));
        half8 A1h = *(const half8*)(HTP + paddr(ta + 1, 512, c, L, 0));
        #pragma unroll
        for (int tt = 0; tt < 4; ++tt) {
            half8 Bh = *(const half8*)(HTP + paddr(tb + tt, 512, c, L, 0));
            acc[0][tt] = MFMA16(A0h, Bh, acc[0][tt]);
            acc[1][tt] = MFMA16(A1h, Bh, acc[1][tt]);
        }
    }
    float s = 0.f;
    #pragma unroll
    for (int rt = 0; rt < 2; ++rt)
        #pragma unroll
        for (int tt = 0; tt < 4; ++tt)
            #pragma unroll
            for (int r = 0; r < 4; ++r)
                s += acc[rt][tt][r] * G[(size_t)(m0 + rt * 16 + quad * 4 + r) * KN
                                        + n0 + tt * 16 + lane16];
    sf[t] = s;
    __syncthreads();
    for (int st = 256; st > 0; st >>= 1) {
        if (t < st) sf[t] += sf[t + st];
        __syncthreads();
    }
    if (t == 0) atomicAdd(diffsum, sf[0]);
}

// ---------------------------------------------------------------------------
// Finalize: offsets = exclusive scan(counts); perplexity; diff (+ ||bf2||^2).
// ---------------------------------------------------------------------------
__global__ __launch_bounds__(512) void finalize_kernel(const int* __restrict__ counts,
                                                       int* __restrict__ offsets,
                                                       const float* __restrict__ diffsum,
                                                       const float* __restrict__ colsum,
                                                       const float* __restrict__ w0,
                                                       const float* __restrict__ bf2,
                                                       float* __restrict__ out_diff,
                                                       float* __restrict__ out_perp) {
    __shared__ int   sc[512];
    __shared__ float sf[512];
    int t = threadIdx.x;
    int c = counts[t];
    sc[t] = c;
    double p = (double)c / (double)BN;
    double term = -p * log(p + 1e-10);
    float dotp = colsum[t] * w0[t];
    float bbp = 0.f;
    for (int d = t; d < ED; d += 512) { float v = bf2[d]; bbp = fmaf(v, v, bbp); }
    __syncthreads();
    int off = 0;
    for (int k = 0; k < t; ++k) off += sc[k];
    offsets[t] = off;
    sf[t] = dotp; __syncthreads();
    for (int s = 256; s > 0; s >>= 1) { if (t < s) sf[t] += sf[t + s]; __syncthreads(); }
    float dot_all = sf[0];
    __syncthreads();
    sf[t] = bbp; __syncthreads();
    for (int s = 256; s > 0; s >>= 1) { if (t < s) sf[t] += sf[t + s]; __syncthreads(); }
    float bb = sf[0];
    __syncthreads();
    sf[t] = (float)term; __syncthreads();
    for (int s = 256; s > 0; s >>= 1) { if (t < s) sf[t] += sf[t + s]; __syncthreads(); }
    if (t == 0) {
        *out_perp = expf(sf[0]);
        *out_diff = (diffsum[0] + 2.f * dot_all + (float)BN * bb) /
                    ((float)BN * (float)ED);
    }
}

// ---------------------------------------------------------------------------
// Scatter, block-aggregated: one global atomic per (block, expert) instead of
// per sample (hot-expert serialization fix).
// ---------------------------------------------------------------------------
__global__ __launch_bounds__(256) void scatter_kernel(const int* __restrict__ ind,
                                                      const int* __restrict__ offsets,
                                                      int* __restrict__ cursors,
                                                      int* __restrict__ perm) {
    __shared__ int lcount[KN], lbase[KN], lcur[KN];
    int t = threadIdx.x;
    for (int i = t; i < KN; i += 256) { lcount[i] = 0; lcur[i] = 0; }
    __syncthreads();
    int b = blockIdx.x * 256 + t;
    int k = ind[b];
    atomicAdd(&lcount[k], 1);
    __syncthreads();
    for (int i = t; i < KN; i += 256) {
        int c = lcount[i];
        if (c > 0) lbase[i] = atomicAdd(&cursors[i], c);
    }
    __syncthreads();
    int pos = offsets[k] + lbase[k] + atomicAdd(&lcur[k], 1);
    perm[pos] = b;
}

// ---------------------------------------------------------------------------
// Decoder: one wave per sample (load-balanced under histogram skew).
// ---------------------------------------------------------------------------
__global__ __launch_bounds__(256) void decode_kernel(const float* __restrict__ EX,
                                                     const int* __restrict__ perm,
                                                     const int* __restrict__ ind,
                                                     const float* __restrict__ W1,
                                                     const float* __restrict__ b1,
                                                     const float* __restrict__ W2,
                                                     const float* __restrict__ b2,
                                                     float* __restrict__ dec) {
    __shared__ float exs[4][DIN];
    __shared__ float h2s[4][DH];
    int t = threadIdx.x;
    int w = t >> 6, l = t & 63;
    int s = blockIdx.x * 4 + w;
    int b = perm[s];
    int k = ind[b];
    exs[w][l] = EX[(size_t)b * DIN + l];
    __syncthreads();
    const float* w1 = W1 + (size_t)k * (DIN * DH);
    float h = b1[(size_t)k * DH + l];
    #pragma unroll
    for (int j = 0; j < DIN; ++j)
        h = fmaf(exs[w][j], w1[(size_t)j * DH + l], h);
    h2s[w][l] = fmaxf(h, 0.f);
    __syncthreads();
    if (l < DY) {
        const float* w2 = W2 + (size_t)k * (DH * DY);
        float d = b2[(size_t)k * DY + l];
        #pragma unroll
        for (int j = 0; j < DH; ++j)
            d = fmaf(h2s[w][j], w2[(size_t)j * DY + l], d);
        dec[(size_t)b * DY + l] = d;
    }
}

// ---------------------------------------------------------------------------
extern "C" void kernel_launch(void* const* d_in, const int* in_sizes, int n_in,
                              void* d_out, int out_size, void* d_ws, size_t ws_size,
                              hipStream_t stream) {
    const float* x     = (const float*)d_in[0];
    const float* Wf1   = (const float*)d_in[1];
    const float* bf1   = (const float*)d_in[2];
    const float* Wf2   = (const float*)d_in[3];
    const float* bf2   = (const float*)d_in[4];
    const float* Wx1   = (const float*)d_in[5];
    const float* bx1   = (const float*)d_in[6];
    const float* Wx2   = (const float*)d_in[7];
    const float* bx2   = (const float*)d_in[8];
    const float* embed = (const float*)d_in[9];
    const float* W1    = (const float*)d_in[10];
    const float* b1    = (const float*)d_in[11];
    const float* W2    = (const float*)d_in[12];
    const float* b2    = (const float*)d_in[13];
    float* out = (float*)d_out;

    char* ws = (char*)d_ws;
    size_t off = 0;
    auto carve = [&](size_t bytes) -> void* {
        void* p = ws + off;
        off += (bytes + 255) & ~(size_t)255;
        return p;
    };
    _Float16* XPs   = (_Float16*)carve((size_t)BN * INC * 2);    // 4.2 MB
    _Float16* XPl   = (_Float16*)carve((size_t)BN * INC * 2);
    _Float16* WfxPs = (_Float16*)carve((size_t)1024 * INC * 2);
    _Float16* WfxPl = (_Float16*)carve((size_t)1024 * INC * 2);
    float*    bfx   = (float*)carve(1024 * 4);
    _Float16* Wx2Ps = (_Float16*)carve((size_t)DIN * CH * 2);
    _Float16* Wx2Pl = (_Float16*)carve((size_t)DIN * CH * 2);
    _Float16* WfPs  = (_Float16*)carve((size_t)CH * ED * 2);     // 6.4 MB
    _Float16* WfPl  = (_Float16*)carve((size_t)CH * ED * 2);
    _Float16* EmPs  = (_Float16*)carve((size_t)KN * ED * 2);
    _Float16* EmPl  = (_Float16*)carve((size_t)KN * ED * 2);
    // Union region: {WeP[16] + GP[16]} (32 MB, dead after wepack/gred)
    // overlaps {HTP} (16.8 MB, written later by enc1).
    char* un = (char*)carve((size_t)32 * KN * KN * 4);           // 32 MB
    float*    WeP = (float*)un;
    float*    GP  = (float*)(un + (size_t)16 * KN * KN * 4);
    _Float16* HTP = (_Float16*)un;
    _Float16* WePs = (_Float16*)carve((size_t)KN * CH * 2);
    _Float16* WePl = (_Float16*)carve((size_t)KN * CH * 2);
    float*    G    = (float*)carve((size_t)KN * KN * 4);
    float*    EX   = (float*)carve((size_t)BN * DIN * 4);        // 4.2 MB
    float*    s2p  = (float*)carve(8 * KN * 4);
    float*    bep  = (float*)carve(8 * KN * 4);
    float*    s2   = (float*)carve(KN * 4);
    float*    be   = (float*)carve(KN * 4);
    char* zbase = ws + off;                                      // ---- zero region ----
    float* w0    = (float*)carve(CH * 4);
    float* colsum= (float*)carve(CH * 4);
    int*   counts= (int*)carve(KN * 4);
    int*   cursors=(int*)carve(KN * 4);
    float* diffsum=(float*)carve(256);
    size_t zbytes = (size_t)(ws + off - zbase);                  // ---- end zero region ----
    int*   ind     = (int*)carve(BN * 4);
    int*   offsets = (int*)carve(KN * 4);
    int*   perm    = (int*)carve(BN * 4);
    (void)in_sizes; (void)n_in; (void)out_size; (void)ws_size;

    hipMemsetAsync(zbase, 0, zbytes, stream);
    xpack_kernel<<<BN / 32, 256, 0, stream>>>(x, XPs, XPl);
    wfxpack_kernel<<<64, 256, 0, stream>>>(Wf1, Wx1, bf1, bx1, WfxPs, WfxPl, bfx);
    wx2pack_kernel<<<4, 256, 0, stream>>>(Wx2, Wx2Ps, Wx2Pl);
    splitwf2_kernel<<<dim3(NCW, 64), 256, 0, stream>>>(Wf2, bf2, WfPs, WfPl, w0);
    embt_kernel<<<dim3(NCW, 16), 256, 0, stream>>>(embed, EmPs, EmPl);
    s2bep_kernel<<<dim3(16, 8), 256, 0, stream>>>(embed, bf2, s2p, bep);
    sbered_kernel<<<1, 512, 0, stream>>>(s2p, bep, s2, be);
    mfma3_kernel<<<dim3(4, 4, 16), 512, 0, stream>>>(WfPs, WfPl, EmPs, EmPl, WeP, NCW);
    mfma1_kernel<<<dim3(4, 4, 16), 512, 0, stream>>>(WfPs, WfPs, GP, NCW);
    wepack_kernel<<<KN * KN / 256, 256, 0, stream>>>(WeP, WePs, WePl);
    gred_kernel<<<KN * KN / 256, 256, 0, stream>>>(GP, G);
    enc1_kernel<<<dim3(BN / 32, 2), 512, 0, stream>>>(XPs, XPl, WfxPs, WfxPl, bfx,
                                                      Wx2Ps, Wx2Pl, bx2,
                                                      WePs, WePl, s2, be,
                                                      HTP, colsum, EX,
                                                      ind, out + OUT_IND, counts,
                                                      diffsum);
    hth_kernel<<<dim3(4, 4, 32), 512, 0, stream>>>(HTP, G, diffsum);
    finalize_kernel<<<1, 512, 0, stream>>>(counts, offsets, diffsum, colsum, w0, bf2,
                                           out + OUT_DIFF, out + OUT_PERP);
    scatter_kernel<<<BN / 256, 256, 0, stream>>>(ind, offsets, cursors, perm);
    decode_kernel<<<BN / 4, 256, 0, stream>>>(EX, perm, ind, W1, b1, W2, b2,
                                              out + OUT_DEC);
}

// Round 10
// 352.910 us; speedup vs baseline: 5.8697x; 1.0768x over previous
//
#include <hip/hip_runtime.h>
#include <math.h>

// Problem constants
#define BN     16384
#define INC    128
#define CH     512
#define ED     6240
#define KN     512      // NUM_EMB
#define DIN    64
#define DH     64
#define DY     32
#define NCW    195      // ED/32 k-chunks for Wf2/embed packing
#define CHP    (CH + 8) // padded LDS row stride (halves)

// d_out layout (float32): dec[16384*32] | diff[1] | embed_ind[16384] | perplexity[1]
#define OUT_DEC   0
#define OUT_DIFF  (BN*DY)
#define OUT_IND   (BN*DY + 1)
#define OUT_PERP  (BN*DY + 1 + BN)

typedef _Float16 half8 __attribute__((ext_vector_type(8)));
typedef float    f32x4 __attribute__((ext_vector_type(4)));
#define MFMA16(a, b, c) __builtin_amdgcn_mfma_f32_16x16x32_f16(a, b, c, 0, 0, 0)

// Packed fragment-tile layout: element (row r within 16-row tile `tile`,
// k-dim index d) lives at ((tile*NC + d/32)*64 + ((d%32)/8)*16 + (r%16))*8 + d%8.
__device__ __forceinline__ size_t paddr(int tile, int NC, int c, int lane, int e) {
    return ((size_t)(tile * NC + c) * 64 + lane) * 8 + e;
}

// ---------------------------------------------------------------------------
// packall (R10): all input packers + s2/be partials in ONE launch.
// Block ranges: [0,12480) splitwf2 | [..,15600) embt | [..,15728) s2bep |
// [..,16240) xpack | [..,16304) wfxpack | [..,16308) wx2pack.
// (R9 ran these as 6 serial launches; the small grids ran at <2% fill.)
// ---------------------------------------------------------------------------
__global__ __launch_bounds__(256) void packall_kernel(
        const float* __restrict__ x,
        const float* __restrict__ Wf1, const float* __restrict__ Wx1,
        const float* __restrict__ bf1, const float* __restrict__ bx1,
        const float* __restrict__ Wx2,
        const float* __restrict__ Wf2, const float* __restrict__ bf2,
        const float* __restrict__ embed,
        _Float16* __restrict__ XPs, _Float16* __restrict__ XPl,
        _Float16* __restrict__ WfxPs, _Float16* __restrict__ WfxPl,
        float* __restrict__ bfx,
        _Float16* __restrict__ Wx2Ps, _Float16* __restrict__ Wx2Pl,
        _Float16* __restrict__ WfPs, _Float16* __restrict__ WfPl,
        _Float16* __restrict__ EmPs, _Float16* __restrict__ EmPl,
        float* __restrict__ s2p, float* __restrict__ bep,
        float* __restrict__ w0) {
    __shared__ __align__(16) char smem[16384];
    int id = blockIdx.x;
    int t = threadIdx.x;
    if (id < 12480) {
        // ---- splitwf2: Wf2 -> packed hi/lo + w0 partials ----
        float (*red)[33] = (float(*)[33])smem;
        int bx = id % NCW, by = id / NCW;
        int d = bx * 32 + (t & 31);
        int j = by * 8 + (t >> 5);
        float v = Wf2[(size_t)j * ED + d];
        _Float16 hi = (_Float16)v;
        size_t a = paddr(j >> 4, NCW, d >> 5, ((d & 31) >> 3) * 16 + (j & 15), d & 7);
        WfPs[a] = hi;
        WfPl[a] = (_Float16)(v - (float)hi);
        red[t >> 5][t & 31] = v * bf2[d];
        __syncthreads();
        if (t < 8) {
            float s = 0.f;
            #pragma unroll
            for (int i = 0; i < 32; ++i) s += red[t][i];
            atomicAdd(&w0[by * 8 + t], s);
        }
    } else if (id < 15600) {
        // ---- embt: embed transpose+split ----
        float (*tile)[33] = (float(*)[33])smem;
        int sub = id - 12480;
        int bx = sub % NCW, by = sub / NCW;
        int dl = t >> 5, kl = t & 31;
        #pragma unroll
        for (int r = 0; r < 4; ++r)
            tile[dl + 8 * r][kl] = embed[(size_t)(bx * 32 + dl + 8 * r) * KN
                                         + by * 32 + kl];
        __syncthreads();
        int d = bx * 32 + kl;
        #pragma unroll
        for (int r = 0; r < 4; ++r) {
            int k = by * 32 + dl + 8 * r;
            float v = tile[kl][dl + 8 * r];
            _Float16 hi = (_Float16)v;
            size_t a = paddr(k >> 4, NCW, d >> 5, ((d & 31) >> 3) * 16 + (k & 15), d & 7);
            EmPs[a] = hi;
            EmPl[a] = (_Float16)(v - (float)hi);
        }
    } else if (id < 15728) {
        // ---- s2bep: deterministic s2/be partials (fixed-order, no atomics) ----
        float (*rs)[33] = (float(*)[33])smem;
        float (*rb)[33] = (float(*)[33])(smem + 8 * 33 * 4);
        int sub = id - 15600;
        int bx = sub % 16, by = sub / 16;
        int kl = t & 31, dl = t >> 5;
        int kb = bx * 32;
        int d0 = by * 780;
        float s = 0.f, b = 0.f;
        for (int d = d0 + dl; d < d0 + 780; d += 8) {
            float e = embed[(size_t)d * KN + kb + kl];
            s = fmaf(e, e, s);
            b = fmaf(bf2[d], e, b);
        }
        rs[dl][kl] = s; rb[dl][kl] = b;
        __syncthreads();
        if (t < 32) {
            float ss = 0.f, bb = 0.f;
            #pragma unroll
            for (int i = 0; i < 8; ++i) { ss += rs[i][t]; bb += rb[i][t]; }
            s2p[by * KN + kb + t] = ss;
            bep[by * KN + kb + t] = bb;
        }
    } else if (id < 16240) {
        // ---- xpack: x -> XPs/XPl ----
        float (*xt)[INC] = (float(*)[INC])smem;
        int m0 = (id - 15728) * 32;
        for (int i = t; i < 32 * (INC / 4); i += 256) {
            int row = i >> 5, c4 = (i & 31) << 2;
            *(float4*)&xt[row][c4] = *(const float4*)&x[(size_t)(m0 + row) * INC + c4];
        }
        __syncthreads();
        int ta = m0 >> 4;
        #pragma unroll
        for (int i = 0; i < 2; ++i) {
            int idx = t + 256 * i;
            int tile2 = idx >> 8;
            int c = (idx >> 6) & 3;
            int lane = idx & 63;
            int m = tile2 * 16 + (lane & 15);
            int d0 = c * 32 + ((lane >> 4) << 3);
            half8 hh, ll;
            #pragma unroll
            for (int e = 0; e < 8; ++e) {
                float v = xt[m][d0 + e];
                _Float16 hi = (_Float16)v;
                hh[e] = hi;
                ll[e] = (_Float16)(v - (float)hi);
            }
            *(half8*)(XPs + paddr(ta + tile2, 4, c, lane, 0)) = hh;
            *(half8*)(XPl + paddr(ta + tile2, 4, c, lane, 0)) = ll;
        }
    } else if (id < 16304) {
        // ---- wfxpack: fused Wf1|Wx1 cols + bfx ----
        int tile = id - 16240;
        for (int i = t; i < 2048; i += 256) {
            int c = i >> 9, lane = (i >> 3) & 63, e = i & 7;
            int n = tile * 16 + (lane & 15);
            int d = c * 32 + ((lane >> 4) << 3) + e;
            float v = (n < 512) ? Wf1[(size_t)d * CH + n] : Wx1[(size_t)d * CH + n - 512];
            _Float16 hi = (_Float16)v;
            size_t a = paddr(tile, 4, c, lane, e);
            WfxPs[a] = hi;
            WfxPl[a] = (_Float16)(v - (float)hi);
        }
        if (tile == 0)
            for (int j = t; j < 512; j += 256) { bfx[j] = bf1[j]; bfx[512 + j] = bx1[j]; }
    } else {
        // ---- wx2pack ----
        int tile = id - 16304;
        for (int i = t; i < 8192; i += 256) {
            int c = i >> 9, lane = (i >> 3) & 63, e = i & 7;
            int n = tile * 16 + (lane & 15);
            int d = c * 32 + ((lane >> 4) << 3) + e;
            float v = Wx2[(size_t)d * DIN + n];
            _Float16 hi = (_Float16)v;
            size_t a = paddr(tile, 16, c, lane, e);
            Wx2Ps[a] = hi;
            Wx2Pl[a] = (_Float16)(v - (float)hi);
        }
    }
}

// ---------------------------------------------------------------------------
// Merged precompute GEMMs (R10): grid (4,4,16), block 512.
// z<8: We partial (3-pass split, A=WfP, B=EmP); z>=8: G partial (1-pass,
// A=B=WfPs). z-split 8 (was 16) halves partial-buffer traffic.
// ---------------------------------------------------------------------------
__global__ __launch_bounds__(512) void mfma_weg_kernel(
        const _Float16* __restrict__ WfPs, const _Float16* __restrict__ WfPl,
        const _Float16* __restrict__ EmPs, const _Float16* __restrict__ EmPl,
        float* __restrict__ WeP, float* __restrict__ GP) {
    int t = threadIdx.x;
    int w = t >> 6, L = t & 63;
    int lane16 = L & 15, quad = L >> 4;
    int m0 = blockIdx.x * 128 + (w & 3) * 32;
    int n0 = blockIdx.y * 128 + (w >> 2) * 64;
    int ta = m0 >> 4, tb = n0 >> 4;
    int zraw = blockIdx.z;
    bool isWe = zraw < 8;
    int z = isWe ? zraw : zraw - 8;
    int base = NCW / 8, rem = NCW % 8;          // 24, 3
    int c0 = z * base + (z < rem ? z : rem);
    int cnt = base + (z < rem ? 1 : 0);
    f32x4 acc[2][4];
    #pragma unroll
    for (int rt = 0; rt < 2; ++rt)
        #pragma unroll
        for (int tt = 0; tt < 4; ++tt) acc[rt][tt] = (f32x4){0.f, 0.f, 0.f, 0.f};
    if (isWe) {
        for (int ci = 0; ci < cnt; ++ci) {
            int c = c0 + ci;
            size_t oa0 = paddr(ta, NCW, c, L, 0), oa1 = paddr(ta + 1, NCW, c, L, 0);
            half8 A0h = *(const half8*)(WfPs + oa0);
            half8 A0l = *(const half8*)(WfPl + oa0);
            half8 A1h = *(const half8*)(WfPs + oa1);
            half8 A1l = *(const half8*)(WfPl + oa1);
            #pragma unroll
            for (int tt = 0; tt < 4; ++tt) {
                size_t ob = paddr(tb + tt, NCW, c, L, 0);
                half8 Bh = *(const half8*)(EmPs + ob);
                half8 Bl8 = *(const half8*)(EmPl + ob);
                acc[0][tt] = MFMA16(A0h, Bl8, MFMA16(A0l, Bh, MFMA16(A0h, Bh, acc[0][tt])));
                acc[1][tt] = MFMA16(A1h, Bl8, MFMA16(A1l, Bh, MFMA16(A1h, Bh, acc[1][tt])));
            }
        }
    } else {
        for (int ci = 0; ci < cnt; ++ci) {
            int c = c0 + ci;
            half8 A0h = *(const half8*)(WfPs + paddr(ta, NCW, c, L, 0));
            half8 A1h = *(const half8*)(WfPs + paddr(ta + 1, NCW, c, L, 0));
            #pragma unroll
            for (int tt = 0; tt < 4; ++tt) {
                half8 Bh = *(const half8*)(WfPs + paddr(tb + tt, NCW, c, L, 0));
                acc[0][tt] = MFMA16(A0h, Bh, acc[0][tt]);
                acc[1][tt] = MFMA16(A1h, Bh, acc[1][tt]);
            }
        }
    }
    float* C = (isWe ? WeP : GP) + (size_t)z * KN * KN;
    #pragma unroll
    for (int rt = 0; rt < 2; ++rt)
        #pragma unroll
        for (int tt = 0; tt < 4; ++tt)
            #pragma unroll
            for (int r = 0; r < 4; ++r)
                C[(size_t)(m0 + rt * 16 + quad * 4 + r) * KN
                  + n0 + tt * 16 + lane16] = acc[rt][tt][r];
}

// ---------------------------------------------------------------------------
// Merged reducers (R10): blocks [0,1024) wepack (8 partials, fixed order ->
// deterministic, transpose-pack to B-frags); [1024,2048) gred; block 2048
// sbered (s2/be final fixed-order reduce).
// ---------------------------------------------------------------------------
__global__ __launch_bounds__(256) void wepackgred_kernel(
        const float* __restrict__ WeP, const float* __restrict__ GP,
        const float* __restrict__ s2p, const float* __restrict__ bep,
        _Float16* __restrict__ WePs, _Float16* __restrict__ WePl,
        float* __restrict__ G, float* __restrict__ s2, float* __restrict__ be) {
    int id = blockIdx.x;
    int t = threadIdx.x;
    if (id < 1024) {
        int g = id * 256 + t;                   // j*512 + k
        int j = g >> 9, k = g & 511;
        float v = 0.f;
        #pragma unroll
        for (int z = 0; z < 8; ++z) v += WeP[(size_t)z * KN * KN + g];
        _Float16 hi = (_Float16)v;
        size_t a = paddr(k >> 4, 16, j >> 5, ((j & 31) >> 3) * 16 + (k & 15), j & 7);
        WePs[a] = hi;
        WePl[a] = (_Float16)(v - (float)hi);
    } else if (id < 2048) {
        int g = (id - 1024) * 256 + t;
        float v = 0.f;
        #pragma unroll
        for (int z = 0; z < 8; ++z) v += GP[(size_t)z * KN * KN + g];
        G[g] = v;
    } else {
        #pragma unroll
        for (int i = 0; i < 2; ++i) {
            int k = t + 256 * i;
            float s = 0.f, b = 0.f;
            #pragma unroll
            for (int y = 0; y < 8; ++y) {
                s += s2p[y * KN + k];
                b += bep[y * KN + k];
            }
            s2[k] = s;
            be[k] = b;
        }
    }
}

// ---------------------------------------------------------------------------
// Fused MFMA encoder + SCORE: grid (BN/32, 2), block 512.  (unchanged R9)
// y=0: h=relu(x@Wf1+bf1) -> LDS -> colsum, HTP pack, score GEMM h.We from LDS
//      (B=WePs/WePl from L2) + in-block argmin (deterministic).
// y=1: hx=relu(x@Wx1+bx1) -> LDS -> EX = hx@Wx2+bx2 via 2nd MFMA stage.
// ---------------------------------------------------------------------------
__global__ __launch_bounds__(512) void enc1_kernel(
        const _Float16* __restrict__ XPs, const _Float16* __restrict__ XPl,
        const _Float16* __restrict__ WfxPs, const _Float16* __restrict__ WfxPl,
        const float* __restrict__ bfx,
        const _Float16* __restrict__ Wx2Ps, const _Float16* __restrict__ Wx2Pl,
        const float* __restrict__ bx2,
        const _Float16* __restrict__ WePs, const _Float16* __restrict__ WePl,
        const float* __restrict__ s2, const float* __restrict__ be,
        _Float16* __restrict__ HTP, float* __restrict__ colsum,
        float* __restrict__ EX,
        int* __restrict__ ind, float* __restrict__ out_ind,
        int* __restrict__ counts, float* __restrict__ diffsum) {
    __shared__ _Float16 hhi[32][CHP];
    __shared__ _Float16 hlo[32][CHP];
    __shared__ float redv[8][32];
    __shared__ int   redi[8][32];
    __shared__ float fin[32];
    int t = threadIdx.x;
    int w = t >> 6, L = t & 63;
    int l16 = L & 15, quad = L >> 4;
    int m0 = blockIdx.x * 32;
    int ta = m0 >> 4;
    int enc = blockIdx.y;
    int n0 = enc * 512 + w * 64;
    int tb = n0 >> 4;
    f32x4 acc[2][4];
    #pragma unroll
    for (int rt = 0; rt < 2; ++rt)
        #pragma unroll
        for (int tt = 0; tt < 4; ++tt) acc[rt][tt] = (f32x4){0.f, 0.f, 0.f, 0.f};
    #pragma unroll
    for (int c = 0; c < 4; ++c) {
        size_t oa0 = paddr(ta, 4, c, L, 0), oa1 = paddr(ta + 1, 4, c, L, 0);
        half8 A0h = *(const half8*)(XPs + oa0);
        half8 A0l = *(const half8*)(XPl + oa0);
        half8 A1h = *(const half8*)(XPs + oa1);
        half8 A1l = *(const half8*)(XPl + oa1);
        #pragma unroll
        for (int tt = 0; tt < 4; ++tt) {
            size_t ob = paddr(tb + tt, 4, c, L, 0);
            half8 Bh = *(const half8*)(WfxPs + ob);
            half8 Bl8 = *(const half8*)(WfxPl + ob);
            acc[0][tt] = MFMA16(A0h, Bl8, MFMA16(A0l, Bh, MFMA16(A0h, Bh, acc[0][tt])));
            acc[1][tt] = MFMA16(A1h, Bl8, MFMA16(A1l, Bh, MFMA16(A1h, Bh, acc[1][tt])));
        }
    }
    #pragma unroll
    for (int rt = 0; rt < 2; ++rt)
        #pragma unroll
        for (int tt = 0; tt < 4; ++tt) {
            int col = w * 64 + tt * 16 + l16;
            float bias = bfx[enc * 512 + col];
            #pragma unroll
            for (int r = 0; r < 4; ++r) {
                int row = rt * 16 + quad * 4 + r;
                float v = fmaxf(acc[rt][tt][r] + bias, 0.f);
                _Float16 hi = (_Float16)v;
                hhi[row][col] = hi;
                hlo[row][col] = (_Float16)(v - (float)hi);
            }
        }
    __syncthreads();
    if (enc == 0) {
        float s = 0.f;
        #pragma unroll
        for (int r = 0; r < 32; ++r) s += (float)hhi[r][t] + (float)hlo[r][t];
        atomicAdd(&colsum[t], s);
        int cb = blockIdx.x;
        #pragma unroll
        for (int i = 0; i < 4; ++i) {
            int idx = t + 512 * i;
            int chtile = idx >> 6;
            int lane = idx & 63;
            int ch = chtile * 16 + (lane & 15);
            int b0 = (lane >> 4) << 3;
            half8 hh;
            #pragma unroll
            for (int e = 0; e < 8; ++e) hh[e] = hhi[b0 + e][ch];
            *(half8*)(HTP + paddr(chtile, 512, cb, lane, 0)) = hh;
        }
        int colbase = w * 64;
        int tbs = w * 4;
        float cks[4];
        #pragma unroll
        for (int tt = 0; tt < 4; ++tt) {
            int c = colbase + tt * 16 + l16;
            cks[tt] = 0.5f * s2[c] - be[c];
        }
        #pragma unroll
        for (int rt = 0; rt < 2; ++rt)
            #pragma unroll
            for (int tt = 0; tt < 4; ++tt) acc[rt][tt] = (f32x4){0.f, 0.f, 0.f, 0.f};
        for (int c = 0; c < 16; ++c) {
            int d0 = c * 32 + (quad << 3);
            int mA0 = l16, mA1 = 16 + l16;
            half8 A0h = *(const half8*)(&hhi[mA0][d0]);
            half8 A0l = *(const half8*)(&hlo[mA0][d0]);
            half8 A1h = *(const half8*)(&hhi[mA1][d0]);
            half8 A1l = *(const half8*)(&hlo[mA1][d0]);
            #pragma unroll
            for (int tt = 0; tt < 4; ++tt) {
                size_t ob = paddr(tbs + tt, 16, c, L, 0);
                half8 Bh = *(const half8*)(WePs + ob);
                half8 Bl8 = *(const half8*)(WePl + ob);
                acc[0][tt] = MFMA16(A0h, Bl8, MFMA16(A0l, Bh, MFMA16(A0h, Bh, acc[0][tt])));
                acc[1][tt] = MFMA16(A1h, Bl8, MFMA16(A1l, Bh, MFMA16(A1h, Bh, acc[1][tt])));
            }
        }
        #pragma unroll
        for (int rt = 0; rt < 2; ++rt) {
            #pragma unroll
            for (int r = 0; r < 4; ++r) {
                float mv = cks[0] - acc[rt][0][r];
                int mi = colbase + l16;
                #pragma unroll
                for (int tt = 1; tt < 4; ++tt) {
                    float v = cks[tt] - acc[rt][tt][r];
                    int c = colbase + tt * 16 + l16;
                    if (v < mv || (v == mv && c < mi)) { mv = v; mi = c; }
                }
                #pragma unroll
                for (int d = 1; d < 16; d <<= 1) {
                    float ov = __shfl_xor(mv, d);
                    int oi = __shfl_xor(mi, d);
                    if (ov < mv || (ov == mv && oi < mi)) { mv = ov; mi = oi; }
                }
                if (l16 == 0) {
                    int row = rt * 16 + quad * 4 + r;
                    redv[w][row] = mv; redi[w][row] = mi;
                }
            }
        }
        __syncthreads();
        if (t < 32) {
            float mv = redv[0][t]; int mi = redi[0][t];
            #pragma unroll
            for (int w2 = 1; w2 < 8; ++w2) {
                float ov = redv[w2][t]; int oi = redi[w2][t];
                if (ov < mv || (ov == mv && oi < mi)) { mv = ov; mi = oi; }
            }
            int b = m0 + t;
            ind[b] = mi;
            out_ind[b] = (float)mi;
            atomicAdd(&counts[mi], 1);
            fin[t] = 2.f * mv;
        }
        __syncthreads();
        if (t == 0) {
            float s = 0.f;
            #pragma unroll
            for (int i = 0; i < 32; ++i) s += fin[i];
            atomicAdd(diffsum, s);
        }
    } else {
        int rt = w & 1, ct = w >> 1;
        f32x4 eacc = (f32x4){0.f, 0.f, 0.f, 0.f};
        for (int c = 0; c < 16; ++c) {
            int d0 = c * 32 + (quad << 3);
            int m = rt * 16 + l16;
            half8 Ah = *(half8*)(&hhi[m][d0]);
            half8 Al = *(half8*)(&hlo[m][d0]);
            size_t ob = paddr(ct, 16, c, L, 0);
            half8 Bh = *(const half8*)(Wx2Ps + ob);
            half8 Bl8 = *(const half8*)(Wx2Pl + ob);
            eacc = MFMA16(Ah, Bl8, MFMA16(Al, Bh, MFMA16(Ah, Bh, eacc)));
        }
        int col = ct * 16 + l16;
        float bias = bx2[col];
        #pragma unroll
        for (int r = 0; r < 4; ++r) {
            int row = m0 + rt * 16 + quad * 4 + r;
            EX[(size_t)row * DIN + col] = eacc[r] + bias;
        }
    }
}

// ---------------------------------------------------------------------------
// diffsum += sum(H^T H o G), tile-wise. grid (4,4,32), block 512.
// ---------------------------------------------------------------------------
__global__ __launch_bounds__(512) void hth_kernel(const _Float16* __restrict__ HTP,
                                                  const float* __restrict__ G,
                                                  float* __restrict__ diffsum) {
    __shared__ float sf[512];
    int t = threadIdx.x;
    int w = t >> 6, L = t & 63;
    int lane16 = L & 15, quad = L >> 4;
    int m0 = blockIdx.x * 128 + (w & 3) * 32;
    int n0 = blockIdx.y * 128 + (w >> 2) * 64;
    int ta = m0 >> 4, tb = n0 >> 4;
    int c0 = blockIdx.z * 16;
    f32x4 acc[2][4];
    #pragma unroll
    for (int rt = 0; rt < 2; ++rt)
        #pragma unroll
        for (int tt = 0; tt < 4; ++tt) acc[rt][tt] = (f32x4){0.f, 0.f, 0.f, 0.f};
    for (int ci = 0; ci < 16; ++ci) {
        int c = c0 + ci;
        half8 A0h = *(const half8*)(HTP + paddr(ta, 512, c, L, 0));
        half8 A1h = *(const half8*)(HTP + paddr(ta + 1, 512, c, L, 0));
        #pragma unroll
        for (int tt = 0; tt < 4; ++tt) {
            half8 Bh = *(const half8*)(HTP + paddr(tb + tt, 512, c, L, 0));
            acc[0][tt] = MFMA16(A0h, Bh, acc[0][tt]);
            acc[1][tt] = MFMA16(A1h, Bh, acc[1][tt]);
        }
    }
    float s = 0.f;
    #pragma unroll
    for (int rt = 0; rt < 2; ++rt)
        #pragma unroll
        for (int tt = 0; tt < 4; ++tt)
            #pragma unroll
            for (int r = 0; r < 4; ++r)
                s += acc[rt][tt][r] * G[(size_t)(m0 + rt * 16 + quad * 4 + r) * KN
                                        + n0 + tt * 16 + lane16];
    sf[t] = s;
    __syncthreads();
    for (int st = 256; st > 0; st >>= 1) {
        if (t < st) sf[t] += sf[t + st];
        __syncthreads();
    }
    if (t == 0) atomicAdd(diffsum, sf[0]);
}

// ---------------------------------------------------------------------------
// Finalize: perplexity + diff only (R10: offsets scan moved into scatter).
// ---------------------------------------------------------------------------
__global__ __launch_bounds__(512) void finalize_kernel(const int* __restrict__ counts,
                                                       const float* __restrict__ diffsum,
                                                       const float* __restrict__ colsum,
                                                       const float* __restrict__ w0,
                                                       const float* __restrict__ bf2,
                                                       float* __restrict__ out_diff,
                                                       float* __restrict__ out_perp) {
    __shared__ float sf[512];
    int t = threadIdx.x;
    int c = counts[t];
    double p = (double)c / (double)BN;
    double term = -p * log(p + 1e-10);
    float dotp = colsum[t] * w0[t];
    float bbp = 0.f;
    for (int d = t; d < ED; d += 512) { float v = bf2[d]; bbp = fmaf(v, v, bbp); }
    sf[t] = dotp; __syncthreads();
    for (int s = 256; s > 0; s >>= 1) { if (t < s) sf[t] += sf[t + s]; __syncthreads(); }
    float dot_all = sf[0];
    __syncthreads();
    sf[t] = bbp; __syncthreads();
    for (int s = 256; s > 0; s >>= 1) { if (t < s) sf[t] += sf[t + s]; __syncthreads(); }
    float bb = sf[0];
    __syncthreads();
    sf[t] = (float)term; __syncthreads();
    for (int s = 256; s > 0; s >>= 1) { if (t < s) sf[t] += sf[t + s]; __syncthreads(); }
    if (t == 0) {
        *out_perp = expf(sf[0]);
        *out_diff = (diffsum[0] + 2.f * dot_all + (float)BN * bb) /
                    ((float)BN * (float)ED);
    }
}

// ---------------------------------------------------------------------------
// Scatter (R10): computes its own offsets scan from counts (deterministic int
// scan) — decode no longer waits behind finalize. Block-aggregated cursors.
// ---------------------------------------------------------------------------
__global__ __launch_bounds__(256) void scatter_kernel(const int* __restrict__ ind,
                                                      const int* __restrict__ counts,
                                                      int* __restrict__ cursors,
                                                      int* __restrict__ perm) {
    __shared__ int sc[KN], soff[KN], lcount[KN], lbase[KN], lcur[KN];
    int t = threadIdx.x;
    for (int i = t; i < KN; i += 256) {
        sc[i] = counts[i];
        lcount[i] = 0; lcur[i] = 0;
    }
    __syncthreads();
    #pragma unroll
    for (int half = 0; half < 2; ++half) {
        int i = t + 256 * half;
        int off = 0;
        for (int k = 0; k < i; ++k) off += sc[k];
        soff[i] = off;
    }
    int b = blockIdx.x * 256 + t;
    int k = ind[b];
    atomicAdd(&lcount[k], 1);
    __syncthreads();
    for (int i = t; i < KN; i += 256) {
        int c = lcount[i];
        if (c > 0) lbase[i] = atomicAdd(&cursors[i], c);
    }
    __syncthreads();
    int pos = soff[k] + lbase[k] + atomicAdd(&lcur[k], 1);
    perm[pos] = b;
}

// ---------------------------------------------------------------------------
// Decoder: one wave per sample (load-balanced under histogram skew).
// ---------------------------------------------------------------------------
__global__ __launch_bounds__(256) void decode_kernel(const float* __restrict__ EX,
                                                     const int* __restrict__ perm,
                                                     const int* __restrict__ ind,
                                                     const float* __restrict__ W1,
                                                     const float* __restrict__ b1,
                                                     const float* __restrict__ W2,
                                                     const float* __restrict__ b2,
                                                     float* __restrict__ dec) {
    __shared__ float exs[4][DIN];
    __shared__ float h2s[4][DH];
    int t = threadIdx.x;
    int w = t >> 6, l = t & 63;
    int s = blockIdx.x * 4 + w;
    int b = perm[s];
    int k = ind[b];
    exs[w][l] = EX[(size_t)b * DIN + l];
    __syncthreads();
    const float* w1 = W1 + (size_t)k * (DIN * DH);
    float h = b1[(size_t)k * DH + l];
    #pragma unroll
    for (int j = 0; j < DIN; ++j)
        h = fmaf(exs[w][j], w1[(size_t)j * DH + l], h);
    h2s[w][l] = fmaxf(h, 0.f);
    __syncthreads();
    if (l < DY) {
        const float* w2 = W2 + (size_t)k * (DH * DY);
        float d = b2[(size_t)k * DY + l];
        #pragma unroll
        for (int j = 0; j < DH; ++j)
            d = fmaf(h2s[w][j], w2[(size_t)j * DY + l], d);
        dec[(size_t)b * DY + l] = d;
    }
}

// ---------------------------------------------------------------------------
extern "C" void kernel_launch(void* const* d_in, const int* in_sizes, int n_in,
                              void* d_out, int out_size, void* d_ws, size_t ws_size,
                              hipStream_t stream) {
    const float* x     = (const float*)d_in[0];
    const float* Wf1   = (const float*)d_in[1];
    const float* bf1   = (const float*)d_in[2];
    const float* Wf2   = (const float*)d_in[3];
    const float* bf2   = (const float*)d_in[4];
    const float* Wx1   = (const float*)d_in[5];
    const float* bx1   = (const float*)d_in[6];
    const float* Wx2   = (const float*)d_in[7];
    const float* bx2   = (const float*)d_in[8];
    const float* embed = (const float*)d_in[9];
    const float* W1    = (const float*)d_in[10];
    const float* b1    = (const float*)d_in[11];
    const float* W2    = (const float*)d_in[12];
    const float* b2    = (const float*)d_in[13];
    float* out = (float*)d_out;

    char* ws = (char*)d_ws;
    size_t off = 0;
    auto carve = [&](size_t bytes) -> void* {
        void* p = ws + off;
        off += (bytes + 255) & ~(size_t)255;
        return p;
    };
    _Float16* XPs   = (_Float16*)carve((size_t)BN * INC * 2);    // 4.2 MB
    _Float16* XPl   = (_Float16*)carve((size_t)BN * INC * 2);
    _Float16* WfxPs = (_Float16*)carve((size_t)1024 * INC * 2);
    _Float16* WfxPl = (_Float16*)carve((size_t)1024 * INC * 2);
    float*    bfx   = (float*)carve(1024 * 4);
    _Float16* Wx2Ps = (_Float16*)carve((size_t)DIN * CH * 2);
    _Float16* Wx2Pl = (_Float16*)carve((size_t)DIN * CH * 2);
    _Float16* WfPs  = (_Float16*)carve((size_t)CH * ED * 2);     // 6.4 MB
    _Float16* WfPl  = (_Float16*)carve((size_t)CH * ED * 2);
    _Float16* EmPs  = (_Float16*)carve((size_t)KN * ED * 2);
    _Float16* EmPl  = (_Float16*)carve((size_t)KN * ED * 2);
    // Union region: {WeP[8] + GP[8]} (16 MB, dead after wepackgred) overlaps
    // {HTP} (16.8 MB, written later by enc1).
    char* un = (char*)carve((size_t)BN * CH * 2);                // 16.8 MB
    float*    WeP = (float*)un;
    float*    GP  = (float*)(un + (size_t)8 * KN * KN * 4);
    _Float16* HTP = (_Float16*)un;
    _Float16* WePs = (_Float16*)carve((size_t)KN * CH * 2);
    _Float16* WePl = (_Float16*)carve((size_t)KN * CH * 2);
    float*    G    = (float*)carve((size_t)KN * KN * 4);
    float*    EX   = (float*)carve((size_t)BN * DIN * 4);        // 4.2 MB
    float*    s2p  = (float*)carve(8 * KN * 4);
    float*    bep  = (float*)carve(8 * KN * 4);
    float*    s2   = (float*)carve(KN * 4);
    float*    be   = (float*)carve(KN * 4);
    char* zbase = ws + off;                                      // ---- zero region ----
    float* w0    = (float*)carve(CH * 4);
    float* colsum= (float*)carve(CH * 4);
    int*   counts= (int*)carve(KN * 4);
    int*   cursors=(int*)carve(KN * 4);
    float* diffsum=(float*)carve(256);
    size_t zbytes = (size_t)(ws + off - zbase);                  // ---- end zero region ----
    int*   ind     = (int*)carve(BN * 4);
    int*   perm    = (int*)carve(BN * 4);
    (void)in_sizes; (void)n_in; (void)out_size; (void)ws_size;

    hipMemsetAsync(zbase, 0, zbytes, stream);
    packall_kernel<<<16308, 256, 0, stream>>>(x, Wf1, Wx1, bf1, bx1, Wx2, Wf2, bf2,
                                              embed, XPs, XPl, WfxPs, WfxPl, bfx,
                                              Wx2Ps, Wx2Pl, WfPs, WfPl, EmPs, EmPl,
                                              s2p, bep, w0);
    mfma_weg_kernel<<<dim3(4, 4, 16), 512, 0, stream>>>(WfPs, WfPl, EmPs, EmPl,
                                                        WeP, GP);
    wepackgred_kernel<<<2049, 256, 0, stream>>>(WeP, GP, s2p, bep,
                                                WePs, WePl, G, s2, be);
    enc1_kernel<<<dim3(BN / 32, 2), 512, 0, stream>>>(XPs, XPl, WfxPs, WfxPl, bfx,
                                                      Wx2Ps, Wx2Pl, bx2,
                                                      WePs, WePl, s2, be,
                                                      HTP, colsum, EX,
                                                      ind, out + OUT_IND, counts,
                                                      diffsum);
    scatter_kernel<<<BN / 256, 256, 0, stream>>>(ind, counts, cursors, perm);
    decode_kernel<<<BN / 4, 256, 0, stream>>>(EX, perm, ind, W1, b1, W2, b2,
                                              out + OUT_DEC);
    hth_kernel<<<dim3(4, 4, 32), 512, 0, stream>>>(HTP, G, diffsum);
    finalize_kernel<<<1, 512, 0, stream>>>(counts, diffsum, colsum, w0, bf2,
                                           out + OUT_DIFF, out + OUT_PERP);
}